// Round 1
// baseline (608.245 us; speedup 1.0000x reference)
//
#include <hip/hip_runtime.h>
#include <hip/hip_bf16.h>

// GraphSAGE 2-layer, mean aggregator, fp32.
//   L1: h  = relu(x @ Wself1 + mean_agg(x) @ Wneigh1 + b1)
//   L2: out = h @ Wself2 + mean_agg(h) @ Wneigh2 + b2
// Transform-first for aggregation (linearity): agg(x)@W == agg(x@W).
// CSR built on device per launch (deterministic set; atomic order only
// perturbs fp sum order, << 0.105 threshold).

#define WAVE 64

// ---------------- CSR build ----------------

__global__ void k_hist(const int* __restrict__ dst, int* __restrict__ cnt, int E) {
    int i = blockIdx.x * blockDim.x + threadIdx.x;
    if (i < E) atomicAdd(&cnt[dst[i]], 1);
}

__global__ void k_scan1(const int* __restrict__ cnt, int* __restrict__ bsum, int n) {
    __shared__ int s[256];
    int i = blockIdx.x * 256 + threadIdx.x;
    int v = (i < n) ? cnt[i] : 0;
    s[threadIdx.x] = v;
    __syncthreads();
    for (int o = 128; o > 0; o >>= 1) {
        if (threadIdx.x < o) s[threadIdx.x] += s[threadIdx.x + o];
        __syncthreads();
    }
    if (threadIdx.x == 0) bsum[blockIdx.x] = s[0];
}

// single block, 512 threads: exclusive scan of nb block sums (nb <= 512)
__global__ void k_scan2(int* __restrict__ bsum, int nb) {
    __shared__ int s[512];
    int t = threadIdx.x;
    int v = (t < nb) ? bsum[t] : 0;
    s[t] = v;
    __syncthreads();
    for (int o = 1; o < 512; o <<= 1) {
        int x = (t >= o) ? s[t - o] : 0;
        __syncthreads();
        s[t] += x;
        __syncthreads();
    }
    if (t < nb) bsum[t] = s[t] - v;  // exclusive
}

__global__ void k_scan3(const int* __restrict__ cnt, const int* __restrict__ bsum,
                        int* __restrict__ row_off, int* __restrict__ cursor,
                        float* __restrict__ inv_deg, int n) {
    __shared__ int s[256];
    int t = threadIdx.x;
    int i = blockIdx.x * 256 + t;
    int v = (i < n) ? cnt[i] : 0;
    s[t] = v;
    __syncthreads();
    for (int o = 1; o < 256; o <<= 1) {
        int x = (t >= o) ? s[t - o] : 0;
        __syncthreads();
        s[t] += x;
        __syncthreads();
    }
    if (i < n) {
        int excl = s[t] - v + bsum[blockIdx.x];
        row_off[i] = excl;
        cursor[i]  = excl;
        inv_deg[i] = 1.0f / fmaxf((float)v, 1.0f);
    }
}

__global__ void k_scatter(const int* __restrict__ src, const int* __restrict__ dst,
                          int* __restrict__ cursor, int* __restrict__ ssorted, int E) {
    int i = blockIdx.x * blockDim.x + threadIdx.x;
    if (i < E) {
        int p = atomicAdd(&cursor[dst[i]], 1);
        ssorted[p] = src[i];
    }
}

// ---------------- dual-output fp32 GEMM ----------------
// O1 = A @ W1            (no bias)
// O2 = A @ W2 + bias
// A: [nrows x 128] row-major; W*: [128 x MOUT] row-major.
// Block: 256 threads, BM=64 rows, register tile 8 rows x (2*MOUT/32) cols.
template <int MOUT>
__global__ __launch_bounds__(256) void k_gemm_dual(
    const float* __restrict__ A, int nrows,
    const float* __restrict__ W1, const float* __restrict__ W2,
    const float* __restrict__ bias,
    float* __restrict__ O1, float* __restrict__ O2) {
    constexpr int K = 128, KC = 32, BM = 64;
    constexpr int NJ = MOUT / 32;   // col-groups per weight matrix
    constexpr int TC = 2 * MOUT;    // combined cols

    __shared__ float At[BM][KC + 1];
    __shared__ float Wt[KC][TC];

    const int tid = threadIdx.x;
    const int tx = tid & 31;   // col lane
    const int ty = tid >> 5;   // 0..7 row group
    const int row0 = blockIdx.x * BM;

    float acc[8][2 * NJ];
#pragma unroll
    for (int i = 0; i < 8; ++i)
#pragma unroll
        for (int j = 0; j < 2 * NJ; ++j) acc[i][j] = 0.f;

    for (int kc = 0; kc < K; kc += KC) {
        // stage A chunk: BM x KC floats (float4 global loads, scalar LDS writes)
#pragma unroll
        for (int i = 0; i < (BM * KC) / (4 * 256); ++i) {
            int q = tid + 256 * i;            // float4 index
            int r = q / (KC / 4);
            int kk = (q % (KC / 4)) * 4;
            float4 v = make_float4(0.f, 0.f, 0.f, 0.f);
            if (row0 + r < nrows)
                v = *reinterpret_cast<const float4*>(A + (size_t)(row0 + r) * K + kc + kk);
            At[r][kk + 0] = v.x; At[r][kk + 1] = v.y;
            At[r][kk + 2] = v.z; At[r][kk + 3] = v.w;
        }
        // stage W chunk: KC x TC floats  ([W1 | W2] side by side)
#pragma unroll
        for (int i = 0; i < (KC * TC) / (4 * 256); ++i) {
            int q = tid + 256 * i;
            int k = q / (TC / 4);
            int c = (q % (TC / 4)) * 4;
            const float* src = (c < MOUT) ? (W1 + (size_t)(kc + k) * MOUT + c)
                                          : (W2 + (size_t)(kc + k) * MOUT + (c - MOUT));
            *reinterpret_cast<float4*>(&Wt[k][c]) =
                *reinterpret_cast<const float4*>(src);
        }
        __syncthreads();
#pragma unroll
        for (int k = 0; k < KC; ++k) {
            float a[8];
#pragma unroll
            for (int i = 0; i < 8; ++i) a[i] = At[ty * 8 + i][k];
            float w[2 * NJ];
#pragma unroll
            for (int j = 0; j < 2 * NJ; ++j) w[j] = Wt[k][tx + 32 * j];
#pragma unroll
            for (int i = 0; i < 8; ++i)
#pragma unroll
                for (int j = 0; j < 2 * NJ; ++j)
                    acc[i][j] = fmaf(a[i], w[j], acc[i][j]);
        }
        __syncthreads();
    }

#pragma unroll
    for (int i = 0; i < 8; ++i) {
        int r = row0 + ty * 8 + i;
        if (r < nrows) {
#pragma unroll
            for (int j = 0; j < NJ; ++j)
                O1[(size_t)r * MOUT + tx + 32 * j] = acc[i][j];
#pragma unroll
            for (int j = 0; j < NJ; ++j)
                O2[(size_t)r * MOUT + tx + 32 * j] = acc[i][NJ + j] + bias[tx + 32 * j];
        }
    }
}

// ---------------- aggregation (CSR gather-sum) ----------------
// one wave per node; 128-dim rows -> float2 per lane. Fuses +agg*inv and relu.
__global__ void k_agg_relu_128(const float* __restrict__ t1, float* __restrict__ h,
                               const int* __restrict__ row_off, const int* __restrict__ cnt,
                               const float* __restrict__ inv_deg,
                               const int* __restrict__ ssorted, int n) {
    int gid = blockIdx.x * blockDim.x + threadIdx.x;
    int node = gid / WAVE;
    int lane = threadIdx.x & (WAVE - 1);
    if (node >= n) return;
    int beg = row_off[node];
    int d = cnt[node];
    float ax = 0.f, ay = 0.f;
    int s_next = (d > 0) ? ssorted[beg] : 0;
    for (int j = 0; j < d; ++j) {
        int s = s_next;
        if (j + 1 < d) s_next = ssorted[beg + j + 1];
        const float2 v = *reinterpret_cast<const float2*>(t1 + (size_t)s * 128 + lane * 2);
        ax += v.x; ay += v.y;
    }
    float inv = inv_deg[node];
    float2 hv = *reinterpret_cast<const float2*>(h + (size_t)node * 128 + lane * 2);
    hv.x = fmaxf(hv.x + ax * inv, 0.f);
    hv.y = fmaxf(hv.y + ay * inv, 0.f);
    *reinterpret_cast<float2*>(h + (size_t)node * 128 + lane * 2) = hv;
}

// one wave per node; 64-dim rows -> 1 float per lane. out += agg*inv.
__global__ void k_agg_add_64(const float* __restrict__ t2, float* __restrict__ out,
                             const int* __restrict__ row_off, const int* __restrict__ cnt,
                             const float* __restrict__ inv_deg,
                             const int* __restrict__ ssorted, int n) {
    int gid = blockIdx.x * blockDim.x + threadIdx.x;
    int node = gid / WAVE;
    int lane = threadIdx.x & (WAVE - 1);
    if (node >= n) return;
    int beg = row_off[node];
    int d = cnt[node];
    float acc = 0.f;
    int s_next = (d > 0) ? ssorted[beg] : 0;
    for (int j = 0; j < d; ++j) {
        int s = s_next;
        if (j + 1 < d) s_next = ssorted[beg + j + 1];
        acc += t2[(size_t)s * 64 + lane];
    }
    size_t o = (size_t)node * 64 + lane;
    out[o] += acc * inv_deg[node];
}

// ---------------- launch ----------------

extern "C" void kernel_launch(void* const* d_in, const int* in_sizes, int n_in,
                              void* d_out, int out_size, void* d_ws, size_t ws_size,
                              hipStream_t stream) {
    const float* x        = (const float*)d_in[0];
    const int*   src      = (const int*)d_in[1];
    const int*   dst      = (const int*)d_in[2];
    const float* W_self1  = (const float*)d_in[3];
    const float* W_neigh1 = (const float*)d_in[4];
    const float* b1       = (const float*)d_in[5];
    const float* W_self2  = (const float*)d_in[6];
    const float* W_neigh2 = (const float*)d_in[7];
    const float* b2       = (const float*)d_in[8];
    float* out = (float*)d_out;

    const int N = in_sizes[0] / 128;
    const int E = in_sizes[1];

    // workspace carve-up (256B aligned)
    char* ws = (char*)d_ws;
    size_t off = 0;
    auto carve = [&](size_t bytes) {
        char* p = ws + off;
        off = (off + bytes + 255) & ~(size_t)255;
        return p;
    };
    int*   cnt      = (int*)carve((size_t)N * 4);
    int*   bsum     = (int*)carve(4096);
    int*   row_off  = (int*)carve((size_t)N * 4);
    int*   cursor   = (int*)carve((size_t)N * 4);
    float* inv_deg  = (float*)carve((size_t)N * 4);
    int*   ssorted  = (int*)carve((size_t)E * 4);
    float* t1       = (float*)carve((size_t)N * 128 * 4);  // layer1 neigh-transform; reused as t2
    float* h        = (float*)carve((size_t)N * 128 * 4);
    float* t2       = t1;  // alias: t1 dead once agg1 done

    const int nb = (N + 255) / 256;       // scan blocks (391)
    const int gE = (E + 255) / 256;       // edge-parallel blocks
    const int gGemm = (N + 63) / 64;
    const int gAgg = (N + 3) / 4;         // 4 waves (nodes) per 256-thread block

    // CSR build
    hipMemsetAsync(cnt, 0, (size_t)N * 4, stream);
    k_hist<<<gE, 256, 0, stream>>>(dst, cnt, E);
    k_scan1<<<nb, 256, 0, stream>>>(cnt, bsum, N);
    k_scan2<<<1, 512, 0, stream>>>(bsum, nb);
    k_scan3<<<nb, 256, 0, stream>>>(cnt, bsum, row_off, cursor, inv_deg, N);
    k_scatter<<<gE, 256, 0, stream>>>(src, dst, cursor, ssorted, E);

    // layer 1: t1 = x@W_neigh1 ; h = x@W_self1 + b1
    k_gemm_dual<128><<<gGemm, 256, 0, stream>>>(x, N, W_neigh1, W_self1, b1, t1, h);
    // h = relu(h + mean_agg(t1))
    k_agg_relu_128<<<gAgg, 256, 0, stream>>>(t1, h, row_off, cnt, inv_deg, ssorted, N);

    // layer 2: t2 = h@W_neigh2 ; out = h@W_self2 + b2
    k_gemm_dual<64><<<gGemm, 256, 0, stream>>>(h, N, W_neigh2, W_self2, b2, t2, out);
    // out += mean_agg(t2)
    k_agg_add_64<<<gAgg, 256, 0, stream>>>(t2, out, row_off, cnt, inv_deg, ssorted, N);
}

// Round 2
// 465.961 us; speedup vs baseline: 1.3054x; 1.3054x over previous
//
#include <hip/hip_runtime.h>
#include <hip/hip_bf16.h>

// GraphSAGE 2-layer, mean aggregator.
//   L1: h  = relu(x @ Wself1 + mean_agg(x) @ Wneigh1 + b1)
//   L2: out = h @ Wself2 + mean_agg(h) @ Wneigh2 + b2
// Transform-first aggregation (linearity). GEMMs in bf16 MFMA (fp32 accum);
// intermediates stored bf16 to halve gather traffic. CSR built on device.

typedef __attribute__((ext_vector_type(8))) short short8;
typedef __attribute__((ext_vector_type(4))) float f32x4;

__device__ __forceinline__ unsigned short f2bf(float f) {
    unsigned int u = __builtin_bit_cast(unsigned int, f);
    u += 0x7fffu + ((u >> 16) & 1u);   // RNE
    return (unsigned short)(u >> 16);
}
__device__ __forceinline__ float bf_lo(unsigned int p) {
    return __builtin_bit_cast(float, p << 16);
}
__device__ __forceinline__ float bf_hi(unsigned int p) {
    return __builtin_bit_cast(float, p & 0xffff0000u);
}

// ---------------- CSR build ----------------

__global__ void k_hist(const int* __restrict__ dst, int* __restrict__ cnt, int E) {
    int i = blockIdx.x * blockDim.x + threadIdx.x;
    if (i < E) atomicAdd(&cnt[dst[i]], 1);
}

__global__ void k_scan1(const int* __restrict__ cnt, int* __restrict__ bsum, int n) {
    __shared__ int s[256];
    int i = blockIdx.x * 256 + threadIdx.x;
    int v = (i < n) ? cnt[i] : 0;
    s[threadIdx.x] = v;
    __syncthreads();
    for (int o = 128; o > 0; o >>= 1) {
        if (threadIdx.x < o) s[threadIdx.x] += s[threadIdx.x + o];
        __syncthreads();
    }
    if (threadIdx.x == 0) bsum[blockIdx.x] = s[0];
}

__global__ void k_scan2(int* __restrict__ bsum, int nb) {
    __shared__ int s[512];
    int t = threadIdx.x;
    int v = (t < nb) ? bsum[t] : 0;
    s[t] = v;
    __syncthreads();
    for (int o = 1; o < 512; o <<= 1) {
        int x = (t >= o) ? s[t - o] : 0;
        __syncthreads();
        s[t] += x;
        __syncthreads();
    }
    if (t < nb) bsum[t] = s[t] - v;  // exclusive
}

__global__ void k_scan3(const int* __restrict__ cnt, const int* __restrict__ bsum,
                        int* __restrict__ row_off, int* __restrict__ cursor,
                        float* __restrict__ inv_deg, int n) {
    __shared__ int s[256];
    int t = threadIdx.x;
    int i = blockIdx.x * 256 + t;
    int v = (i < n) ? cnt[i] : 0;
    s[t] = v;
    __syncthreads();
    for (int o = 1; o < 256; o <<= 1) {
        int x = (t >= o) ? s[t - o] : 0;
        __syncthreads();
        s[t] += x;
        __syncthreads();
    }
    if (i < n) {
        int excl = s[t] - v + bsum[blockIdx.x];
        row_off[i] = excl;
        cursor[i]  = excl;
        inv_deg[i] = 1.0f / fmaxf((float)v, 1.0f);
    }
}

__global__ void k_scatter(const int* __restrict__ src, const int* __restrict__ dst,
                          int* __restrict__ cursor, int* __restrict__ ssorted, int E) {
    int i = blockIdx.x * blockDim.x + threadIdx.x;
    if (i < E) {
        int p = atomicAdd(&cursor[dst[i]], 1);
        ssorted[p] = src[i];
    }
}

// ---------------- weight prep: transpose + bf16 ----------------
// Bt1 [256][128]: cols 0-127 = W_neigh1^T, 128-255 = W_self1^T
// Bt2 [128][128]: cols 0-63  = W_neigh2^T,  64-127 = W_self2^T
__global__ void k_prep(const float* __restrict__ Wn1, const float* __restrict__ Ws1,
                       const float* __restrict__ Wn2, const float* __restrict__ Ws2,
                       unsigned short* __restrict__ Bt1, unsigned short* __restrict__ Bt2) {
    int i = blockIdx.x * 256 + threadIdx.x;
    if (i < 256 * 128) {
        int c = i >> 7, k = i & 127;
        float v = (c < 128) ? Wn1[k * 128 + c] : Ws1[k * 128 + (c - 128)];
        Bt1[i] = f2bf(v);
    } else {
        int j = i - 256 * 128;
        if (j < 128 * 128) {
            int c = j >> 7, k = j & 127;
            float v = (c < 64) ? Wn2[k * 64 + c] : Ws2[k * 64 + (c - 64)];
            Bt2[j] = f2bf(v);
        }
    }
}

// ---------------- bf16 MFMA dual-output GEMM ----------------
// A [nrows x 128] (f32 if AF32, converted on the fly; else bf16 bits).
// Bt [2*MO x 128] bf16, K-contiguous (pre-transposed).
// O1 = A @ B[:, 0:MO]          (bf16)
// O2 = A @ B[:, MO:2MO] + bias (bf16 if !O2F32, else f32)
// Block = 256 thr = 4 waves; wave (wr,wc) owns 64 rows x 64 cols. No LDS.
template <int MO, int NWR, int NWC, bool AF32, bool O2F32>
__global__ __launch_bounds__(256, 2) void k_gemm(
    const float* __restrict__ Af, const unsigned short* __restrict__ Ab, int nrows,
    const unsigned short* __restrict__ Bt, const float* __restrict__ bias,
    unsigned short* __restrict__ O1, unsigned short* __restrict__ O2b,
    float* __restrict__ O2f) {
    const int tid = threadIdx.x;
    const int w = tid >> 6, lane = tid & 63;
    const int l15 = lane & 15, lg = lane >> 4;
    const int wr = w / NWC, wc = w % NWC;
    const int row0 = blockIdx.x * (64 * NWR) + wr * 64;
    const int col0 = wc * 64;

    // B fragments: 4 col-tiles x 4 K-steps (L2-resident weights)
    short8 bfrag[4][4];
#pragma unroll
    for (int ct = 0; ct < 4; ++ct)
#pragma unroll
        for (int ks = 0; ks < 4; ++ks)
            bfrag[ct][ks] = *reinterpret_cast<const short8*>(
                Bt + (size_t)(col0 + ct * 16 + l15) * 128 + ks * 32 + lg * 8);

    f32x4 acc[4][4];
#pragma unroll
    for (int rt = 0; rt < 4; ++rt)
#pragma unroll
        for (int ct = 0; ct < 4; ++ct) acc[rt][ct] = (f32x4)0.f;

#pragma unroll
    for (int rt = 0; rt < 4; ++rt) {
        int row = row0 + rt * 16 + l15;
        int rc = row < nrows ? row : nrows - 1;  // clamp (OOB rows masked at store)
        short8 af[4];
        if constexpr (AF32) {
#pragma unroll
            for (int ks = 0; ks < 4; ++ks) {
                const float* p = Af + (size_t)rc * 128 + ks * 32 + lg * 8;
                float4 a = *reinterpret_cast<const float4*>(p);
                float4 b = *reinterpret_cast<const float4*>(p + 4);
                short8 v;
                v[0] = (short)f2bf(a.x); v[1] = (short)f2bf(a.y);
                v[2] = (short)f2bf(a.z); v[3] = (short)f2bf(a.w);
                v[4] = (short)f2bf(b.x); v[5] = (short)f2bf(b.y);
                v[6] = (short)f2bf(b.z); v[7] = (short)f2bf(b.w);
                af[ks] = v;
            }
        } else {
#pragma unroll
            for (int ks = 0; ks < 4; ++ks)
                af[ks] = *reinterpret_cast<const short8*>(
                    Ab + (size_t)rc * 128 + ks * 32 + lg * 8);
        }
#pragma unroll
        for (int ct = 0; ct < 4; ++ct)
#pragma unroll
            for (int ks = 0; ks < 4; ++ks)
                acc[rt][ct] = __builtin_amdgcn_mfma_f32_16x16x32_bf16(
                    af[ks], bfrag[ct][ks], acc[rt][ct], 0, 0, 0);
    }

    // epilogue: C/D layout col = lane&15, row = (lane>>4)*4 + reg
#pragma unroll
    for (int ct = 0; ct < 4; ++ct) {
        int gcol = col0 + ct * 16 + l15;
        bool isO2 = gcol >= MO;
        float bv = isO2 ? bias[gcol - MO] : 0.f;
#pragma unroll
        for (int rt = 0; rt < 4; ++rt) {
#pragma unroll
            for (int r = 0; r < 4; ++r) {
                int row = row0 + rt * 16 + lg * 4 + r;
                if (row < nrows) {
                    float v = acc[rt][ct][r];
                    if (!isO2) {
                        O1[(size_t)row * MO + gcol] = f2bf(v);
                    } else if constexpr (O2F32) {
                        O2f[(size_t)row * MO + (gcol - MO)] = v + bv;
                    } else {
                        O2b[(size_t)row * MO + (gcol - MO)] = f2bf(v + bv);
                    }
                }
            }
        }
    }
}

// ---------------- aggregation ----------------
// layer 1: one wave per node, 128 dims (u32 = 2 bf16 per lane).
// h = relu(hself + mean(t1[src])) -> bf16
__global__ __launch_bounds__(256) void k_agg1(
    const unsigned short* __restrict__ t1, const unsigned short* __restrict__ hs,
    unsigned short* __restrict__ hb,
    const int* __restrict__ row_off, const int* __restrict__ cnt,
    const float* __restrict__ inv_deg, const int* __restrict__ ssorted, int n) {
    int node = (blockIdx.x * 256 + threadIdx.x) >> 6;
    int lane = threadIdx.x & 63;
    if (node >= n) return;
    int beg = row_off[node], d = cnt[node];
    float ax = 0.f, ay = 0.f;
    for (int base = 0; base < d; base += 64) {
        int m = d - base; if (m > 64) m = 64;
        int sv = (lane < m) ? ssorted[beg + base + lane] : 0;
        for (int j = 0; j < m; ++j) {
            int s = __shfl(sv, j);
            unsigned int p = *reinterpret_cast<const unsigned int*>(
                t1 + (size_t)s * 128 + lane * 2);
            ax += bf_lo(p); ay += bf_hi(p);
        }
    }
    float inv = inv_deg[node];
    unsigned int q = *reinterpret_cast<const unsigned int*>(hs + (size_t)node * 128 + lane * 2);
    float hx = fmaxf(bf_lo(q) + ax * inv, 0.f);
    float hy = fmaxf(bf_hi(q) + ay * inv, 0.f);
    *reinterpret_cast<unsigned int*>(hb + (size_t)node * 128 + lane * 2) =
        (unsigned int)f2bf(hx) | ((unsigned int)f2bf(hy) << 16);
}

// layer 2: half-wave (32 lanes) per node, 64 dims. out += mean(t2[src]).
__global__ __launch_bounds__(256) void k_agg2(
    const unsigned short* __restrict__ t2, float* __restrict__ out,
    const int* __restrict__ row_off, const int* __restrict__ cnt,
    const float* __restrict__ inv_deg, const int* __restrict__ ssorted, int n) {
    int node = (blockIdx.x * 256 + threadIdx.x) >> 5;
    int l32 = threadIdx.x & 31;
    if (node >= n) return;
    int beg = row_off[node], d = cnt[node];
    float ax = 0.f, ay = 0.f;
    for (int base = 0; base < d; base += 32) {
        int m = d - base; if (m > 32) m = 32;
        int sv = (l32 < m) ? ssorted[beg + base + l32] : 0;
        for (int j = 0; j < m; ++j) {
            int s = __shfl(sv, j, 32);
            unsigned int p = *reinterpret_cast<const unsigned int*>(
                t2 + (size_t)s * 64 + l32 * 2);
            ax += bf_lo(p); ay += bf_hi(p);
        }
    }
    float inv = inv_deg[node];
    float2* po = reinterpret_cast<float2*>(out + (size_t)node * 64 + l32 * 2);
    float2 v = *po;
    v.x += ax * inv; v.y += ay * inv;
    *po = v;
}

// ---------------- launch ----------------

extern "C" void kernel_launch(void* const* d_in, const int* in_sizes, int n_in,
                              void* d_out, int out_size, void* d_ws, size_t ws_size,
                              hipStream_t stream) {
    const float* x        = (const float*)d_in[0];
    const int*   src      = (const int*)d_in[1];
    const int*   dst      = (const int*)d_in[2];
    const float* W_self1  = (const float*)d_in[3];
    const float* W_neigh1 = (const float*)d_in[4];
    const float* b1       = (const float*)d_in[5];
    const float* W_self2  = (const float*)d_in[6];
    const float* W_neigh2 = (const float*)d_in[7];
    const float* b2       = (const float*)d_in[8];
    float* out = (float*)d_out;

    const int N = in_sizes[0] / 128;
    const int E = in_sizes[1];

    char* ws = (char*)d_ws;
    size_t off = 0;
    auto carve = [&](size_t bytes) {
        char* p = ws + off;
        off = (off + bytes + 255) & ~(size_t)255;
        return p;
    };
    int*   cnt     = (int*)carve((size_t)N * 4);
    int*   bsum    = (int*)carve(4096);
    int*   row_off = (int*)carve((size_t)N * 4);
    int*   cursor  = (int*)carve((size_t)N * 4);
    float* inv_deg = (float*)carve((size_t)N * 4);
    int*   ssorted = (int*)carve((size_t)E * 4);
    unsigned short* Bt1 = (unsigned short*)carve(256 * 128 * 2);
    unsigned short* Bt2 = (unsigned short*)carve(128 * 128 * 2);
    unsigned short* t1  = (unsigned short*)carve((size_t)N * 128 * 2);  // reused as t2
    unsigned short* hs  = (unsigned short*)carve((size_t)N * 128 * 2);  // self part L1
    unsigned short* hb  = (unsigned short*)carve((size_t)N * 128 * 2);  // relu'd h (bf16)
    unsigned short* t2  = t1;  // alias: t1 dead after agg1

    const int nb = (N + 255) / 256;
    const int gE = (E + 255) / 256;

    // CSR build
    hipMemsetAsync(cnt, 0, (size_t)N * 4, stream);
    k_hist<<<gE, 256, 0, stream>>>(dst, cnt, E);
    k_scan1<<<nb, 256, 0, stream>>>(cnt, bsum, N);
    k_scan2<<<1, 512, 0, stream>>>(bsum, nb);
    k_scan3<<<nb, 256, 0, stream>>>(cnt, bsum, row_off, cursor, inv_deg, N);
    k_scatter<<<gE, 256, 0, stream>>>(src, dst, cursor, ssorted, E);

    // weights -> bf16 transposed
    k_prep<<<192, 256, 0, stream>>>(W_neigh1, W_self1, W_neigh2, W_self2, Bt1, Bt2);

    // layer 1: t1 = x@Wn1 (bf16), hs = x@Ws1 + b1 (bf16); fused f32->bf16 on A
    k_gemm<128, 1, 4, true, false><<<(N + 63) / 64, 256, 0, stream>>>(
        x, nullptr, N, Bt1, b1, t1, hs, nullptr);
    // h = relu(hs + mean_agg(t1)) -> hb (bf16)
    k_agg1<<<(N * 64 + 255) / 256, 256, 0, stream>>>(
        t1, hs, hb, row_off, cnt, inv_deg, ssorted, N);

    // layer 2: t2 = h@Wn2 (bf16), out = h@Ws2 + b2 (f32)
    k_gemm<64, 2, 2, false, true><<<(N + 127) / 128, 256, 0, stream>>>(
        nullptr, hb, N, Bt2, b2, t2, nullptr, out);
    // out += mean_agg(t2)
    k_agg2<<<(N * 32 + 255) / 256, 256, 0, stream>>>(
        t2, out, row_off, cnt, inv_deg, ssorted, N);
}

// Round 3
// 272.140 us; speedup vs baseline: 2.2350x; 1.7122x over previous
//
#include <hip/hip_runtime.h>
#include <hip/hip_bf16.h>

// GraphSAGE 2-layer, mean aggregator.
//   L1: h  = relu(x @ Wself1 + mean_agg(x) @ Wneigh1 + b1)
//   L2: out = h @ Wself2 + mean_agg(h) @ Wneigh2 + b2
// Transform-first aggregation. bf16 MFMA GEMMs (fp32 accum). CSR by dst built
// per launch with a two-level bucket sort (cache-line-friendly writes; the
// one-shot counting sort had 16x write amplification -> 123us scatter).

typedef __attribute__((ext_vector_type(8))) short short8;
typedef __attribute__((ext_vector_type(4))) float f32x4;

#define BKT_SHIFT 7                 // 128 nodes per bucket
#define SBUF_CAP 4096               // max staged edges per bucket (avg ~2046)

__device__ __forceinline__ unsigned short f2bf(float f) {
    unsigned int u = __builtin_bit_cast(unsigned int, f);
    u += 0x7fffu + ((u >> 16) & 1u);   // RNE
    return (unsigned short)(u >> 16);
}
__device__ __forceinline__ float bf_lo(unsigned int p) {
    return __builtin_bit_cast(float, p << 16);
}
__device__ __forceinline__ float bf_hi(unsigned int p) {
    return __builtin_bit_cast(float, p & 0xffff0000u);
}

// ---------------- CSR build: two-level bucket sort ----------------

// per-block LDS histogram over buckets, one global atomicAdd per (block,bucket)
__global__ __launch_bounds__(256) void k_bhist(
    const int* __restrict__ dst, int E, int chunk,
    int* __restrict__ bucket_cnt, int nb) {
    __shared__ int h[1024];
    for (int i = threadIdx.x; i < nb; i += 256) h[i] = 0;
    __syncthreads();
    int beg = blockIdx.x * chunk;
    int end = min(beg + chunk, E);
    for (int i = beg + threadIdx.x; i < end; i += 256)
        atomicAdd(&h[dst[i] >> BKT_SHIFT], 1);
    __syncthreads();
    for (int i = threadIdx.x; i < nb; i += 256)
        if (h[i]) atomicAdd(&bucket_cnt[i], h[i]);
}

// single block: exclusive scan of bucket counts -> base & cursor
__global__ __launch_bounds__(1024) void k_bscan(
    const int* __restrict__ bucket_cnt, int* __restrict__ base,
    int* __restrict__ cursor, int nb, int E) {
    __shared__ int s[1024];
    int t = threadIdx.x;
    int v = (t < nb) ? bucket_cnt[t] : 0;
    s[t] = v;
    __syncthreads();
    for (int o = 1; o < 1024; o <<= 1) {
        int x = (t >= o) ? s[t - o] : 0;
        __syncthreads();
        s[t] += x;
        __syncthreads();
    }
    if (t < nb) {
        int excl = s[t] - v;
        base[t] = excl;
        cursor[t] = excl;
    }
    if (t == 0) base[nb] = E;
}

// chunk-claiming scatter: block claims one contiguous run per bucket, writes
// packed (dstlow<<17 | src) entries chunk-contiguously (low write amp).
__global__ __launch_bounds__(256) void k_bscatter(
    const int* __restrict__ src, const int* __restrict__ dst, int E, int chunk,
    int* __restrict__ cursor, unsigned int* __restrict__ packed, int nb) {
    __shared__ int h[1024];
    __shared__ int cb[1024];
    for (int i = threadIdx.x; i < nb; i += 256) h[i] = 0;
    __syncthreads();
    int beg = blockIdx.x * chunk;
    int end = min(beg + chunk, E);
    for (int i = beg + threadIdx.x; i < end; i += 256)
        atomicAdd(&h[dst[i] >> BKT_SHIFT], 1);
    __syncthreads();
    for (int i = threadIdx.x; i < nb; i += 256) {
        cb[i] = h[i] ? atomicAdd(&cursor[i], h[i]) : 0;
    }
    __syncthreads();
    for (int i = threadIdx.x; i < nb; i += 256) h[i] = 0;  // reuse as local cursor
    __syncthreads();
    for (int i = beg + threadIdx.x; i < end; i += 256) {
        int d = dst[i];
        int b = d >> BKT_SHIFT;
        int loc = atomicAdd(&h[b], 1);
        packed[cb[b] + loc] = ((unsigned int)(d & 127) << 17) | (unsigned int)src[i];
    }
}

// per-bucket counting sort (block per bucket); emits row_off/cnt/inv_deg and
// fully-coalesced ssorted writes via LDS staging.
__global__ __launch_bounds__(256) void k_bsort(
    const unsigned int* __restrict__ packed, const int* __restrict__ base,
    int* __restrict__ ssorted, int* __restrict__ row_off, int* __restrict__ cnt,
    float* __restrict__ inv_deg, int n) {
    __shared__ int h128[128];
    __shared__ int ex[128];
    __shared__ int sbuf[SBUF_CAP];
    int t = threadIdx.x;
    int b = blockIdx.x;
    int beg = base[b], end = base[b + 1];
    int m = end - beg;
    if (t < 128) h128[t] = 0;
    __syncthreads();
    for (int i = t; i < m; i += 256)
        atomicAdd(&h128[packed[beg + i] >> 17], 1);
    __syncthreads();
    if (t < 128) ex[t] = h128[t];
    __syncthreads();
    for (int o = 1; o < 128; o <<= 1) {
        int v = (t < 128 && t >= o) ? ex[t - o] : 0;
        __syncthreads();
        if (t < 128) ex[t] += v;
        __syncthreads();
    }
    if (t < 128) {
        int deg = h128[t];
        ex[t] -= deg;  // exclusive
        int node = (b << BKT_SHIFT) + t;
        if (node < n) {
            row_off[node] = beg + ex[t];
            cnt[node] = deg;
            inv_deg[node] = 1.0f / fmaxf((float)deg, 1.0f);
        }
    }
    __syncthreads();
    if (t < 128) h128[t] = 0;  // reuse as cursor
    __syncthreads();
    if (m <= SBUF_CAP) {
        for (int i = t; i < m; i += 256) {
            unsigned int p = packed[beg + i];
            int dl = p >> 17;
            int loc = atomicAdd(&h128[dl], 1);
            sbuf[ex[dl] + loc] = (int)(p & 0x1FFFFu);
        }
        __syncthreads();
        for (int i = t; i < m; i += 256) ssorted[beg + i] = sbuf[i];
    } else {  // fallback (never for this size distribution)
        for (int i = t; i < m; i += 256) {
            unsigned int p = packed[beg + i];
            int dl = p >> 17;
            int loc = atomicAdd(&h128[dl], 1);
            ssorted[beg + ex[dl] + loc] = (int)(p & 0x1FFFFu);
        }
    }
}

// ---------------- weight prep: transpose + bf16 ----------------
__global__ void k_prep(const float* __restrict__ Wn1, const float* __restrict__ Ws1,
                       const float* __restrict__ Wn2, const float* __restrict__ Ws2,
                       unsigned short* __restrict__ Bt1, unsigned short* __restrict__ Bt2) {
    int i = blockIdx.x * 256 + threadIdx.x;
    if (i < 256 * 128) {
        int c = i >> 7, k = i & 127;
        float v = (c < 128) ? Wn1[k * 128 + c] : Ws1[k * 128 + (c - 128)];
        Bt1[i] = f2bf(v);
    } else {
        int j = i - 256 * 128;
        if (j < 128 * 128) {
            int c = j >> 7, k = j & 127;
            float v = (c < 64) ? Wn2[k * 64 + c] : Ws2[k * 64 + (c - 64)];
            Bt2[j] = f2bf(v);
        }
    }
}

// ---------------- bf16 MFMA dual-output GEMM ----------------
template <int MO, int NWR, int NWC, bool AF32, bool O2F32>
__global__ __launch_bounds__(256, 2) void k_gemm(
    const float* __restrict__ Af, const unsigned short* __restrict__ Ab, int nrows,
    const unsigned short* __restrict__ Bt, const float* __restrict__ bias,
    unsigned short* __restrict__ O1, unsigned short* __restrict__ O2b,
    float* __restrict__ O2f) {
    const int tid = threadIdx.x;
    const int w = tid >> 6, lane = tid & 63;
    const int l15 = lane & 15, lg = lane >> 4;
    const int wr = w / NWC, wc = w % NWC;
    const int row0 = blockIdx.x * (64 * NWR) + wr * 64;
    const int col0 = wc * 64;

    short8 bfrag[4][4];
#pragma unroll
    for (int ct = 0; ct < 4; ++ct)
#pragma unroll
        for (int ks = 0; ks < 4; ++ks)
            bfrag[ct][ks] = *reinterpret_cast<const short8*>(
                Bt + (size_t)(col0 + ct * 16 + l15) * 128 + ks * 32 + lg * 8);

    f32x4 acc[4][4];
#pragma unroll
    for (int rt = 0; rt < 4; ++rt)
#pragma unroll
        for (int ct = 0; ct < 4; ++ct) acc[rt][ct] = (f32x4)0.f;

#pragma unroll
    for (int rt = 0; rt < 4; ++rt) {
        int row = row0 + rt * 16 + l15;
        int rc = row < nrows ? row : nrows - 1;
        short8 af[4];
        if constexpr (AF32) {
#pragma unroll
            for (int ks = 0; ks < 4; ++ks) {
                const float* p = Af + (size_t)rc * 128 + ks * 32 + lg * 8;
                float4 a = *reinterpret_cast<const float4*>(p);
                float4 b = *reinterpret_cast<const float4*>(p + 4);
                short8 v;
                v[0] = (short)f2bf(a.x); v[1] = (short)f2bf(a.y);
                v[2] = (short)f2bf(a.z); v[3] = (short)f2bf(a.w);
                v[4] = (short)f2bf(b.x); v[5] = (short)f2bf(b.y);
                v[6] = (short)f2bf(b.z); v[7] = (short)f2bf(b.w);
                af[ks] = v;
            }
        } else {
#pragma unroll
            for (int ks = 0; ks < 4; ++ks)
                af[ks] = *reinterpret_cast<const short8*>(
                    Ab + (size_t)rc * 128 + ks * 32 + lg * 8);
        }
#pragma unroll
        for (int ct = 0; ct < 4; ++ct)
#pragma unroll
            for (int ks = 0; ks < 4; ++ks)
                acc[rt][ct] = __builtin_amdgcn_mfma_f32_16x16x32_bf16(
                    af[ks], bfrag[ct][ks], acc[rt][ct], 0, 0, 0);
    }

    // C/D layout: col = lane&15, row = (lane>>4)*4 + reg
#pragma unroll
    for (int ct = 0; ct < 4; ++ct) {
        int gcol = col0 + ct * 16 + l15;
        bool isO2 = gcol >= MO;
        float bv = isO2 ? bias[gcol - MO] : 0.f;
#pragma unroll
        for (int rt = 0; rt < 4; ++rt) {
#pragma unroll
            for (int r = 0; r < 4; ++r) {
                int row = row0 + rt * 16 + lg * 4 + r;
                if (row < nrows) {
                    float v = acc[rt][ct][r];
                    if (!isO2) {
                        O1[(size_t)row * MO + gcol] = f2bf(v);
                    } else if constexpr (O2F32) {
                        O2f[(size_t)row * MO + (gcol - MO)] = v + bv;
                    } else {
                        O2b[(size_t)row * MO + (gcol - MO)] = f2bf(v + bv);
                    }
                }
            }
        }
    }
}

// ---------------- aggregation ----------------
// layer 1: wave per node, 128 dims (u32 = 2 bf16 per lane), 4-way MLP unroll.
__global__ __launch_bounds__(256) void k_agg1(
    const unsigned short* __restrict__ t1, const unsigned short* __restrict__ hs,
    unsigned short* __restrict__ hb,
    const int* __restrict__ row_off, const int* __restrict__ cnt,
    const float* __restrict__ inv_deg, const int* __restrict__ ssorted, int n) {
    int node = (blockIdx.x * 256 + threadIdx.x) >> 6;
    int lane = threadIdx.x & 63;
    if (node >= n) return;
    int beg = row_off[node], d = cnt[node];
    float ax = 0.f, ay = 0.f;
    for (int base = 0; base < d; base += 64) {
        int m = d - base; if (m > 64) m = 64;
        int sv = (lane < m) ? ssorted[beg + base + lane] : 0;
        int j = 0;
        for (; j + 4 <= m; j += 4) {
            int s0 = __shfl(sv, j), s1 = __shfl(sv, j + 1);
            int s2 = __shfl(sv, j + 2), s3 = __shfl(sv, j + 3);
            unsigned int p0 = *reinterpret_cast<const unsigned int*>(t1 + (size_t)s0 * 128 + lane * 2);
            unsigned int p1 = *reinterpret_cast<const unsigned int*>(t1 + (size_t)s1 * 128 + lane * 2);
            unsigned int p2 = *reinterpret_cast<const unsigned int*>(t1 + (size_t)s2 * 128 + lane * 2);
            unsigned int p3 = *reinterpret_cast<const unsigned int*>(t1 + (size_t)s3 * 128 + lane * 2);
            ax += bf_lo(p0) + bf_lo(p1) + bf_lo(p2) + bf_lo(p3);
            ay += bf_hi(p0) + bf_hi(p1) + bf_hi(p2) + bf_hi(p3);
        }
        for (; j < m; ++j) {
            int s = __shfl(sv, j);
            unsigned int p = *reinterpret_cast<const unsigned int*>(t1 + (size_t)s * 128 + lane * 2);
            ax += bf_lo(p); ay += bf_hi(p);
        }
    }
    float inv = inv_deg[node];
    unsigned int q = *reinterpret_cast<const unsigned int*>(hs + (size_t)node * 128 + lane * 2);
    float hx = fmaxf(bf_lo(q) + ax * inv, 0.f);
    float hy = fmaxf(bf_hi(q) + ay * inv, 0.f);
    *reinterpret_cast<unsigned int*>(hb + (size_t)node * 128 + lane * 2) =
        (unsigned int)f2bf(hx) | ((unsigned int)f2bf(hy) << 16);
}

// layer 2: half-wave per node, 64 dims, 4-way MLP unroll. out += mean(t2[src]).
__global__ __launch_bounds__(256) void k_agg2(
    const unsigned short* __restrict__ t2, float* __restrict__ out,
    const int* __restrict__ row_off, const int* __restrict__ cnt,
    const float* __restrict__ inv_deg, const int* __restrict__ ssorted, int n) {
    int node = (blockIdx.x * 256 + threadIdx.x) >> 5;
    int l32 = threadIdx.x & 31;
    if (node >= n) return;
    int beg = row_off[node], d = cnt[node];
    float ax = 0.f, ay = 0.f;
    for (int base = 0; base < d; base += 32) {
        int m = d - base; if (m > 32) m = 32;
        int sv = (l32 < m) ? ssorted[beg + base + l32] : 0;
        int j = 0;
        for (; j + 4 <= m; j += 4) {
            int s0 = __shfl(sv, j, 32), s1 = __shfl(sv, j + 1, 32);
            int s2 = __shfl(sv, j + 2, 32), s3 = __shfl(sv, j + 3, 32);
            unsigned int p0 = *reinterpret_cast<const unsigned int*>(t2 + (size_t)s0 * 64 + l32 * 2);
            unsigned int p1 = *reinterpret_cast<const unsigned int*>(t2 + (size_t)s1 * 64 + l32 * 2);
            unsigned int p2 = *reinterpret_cast<const unsigned int*>(t2 + (size_t)s2 * 64 + l32 * 2);
            unsigned int p3 = *reinterpret_cast<const unsigned int*>(t2 + (size_t)s3 * 64 + l32 * 2);
            ax += bf_lo(p0) + bf_lo(p1) + bf_lo(p2) + bf_lo(p3);
            ay += bf_hi(p0) + bf_hi(p1) + bf_hi(p2) + bf_hi(p3);
        }
        for (; j < m; ++j) {
            int s = __shfl(sv, j, 32);
            unsigned int p = *reinterpret_cast<const unsigned int*>(t2 + (size_t)s * 64 + l32 * 2);
            ax += bf_lo(p); ay += bf_hi(p);
        }
    }
    float inv = inv_deg[node];
    float2* po = reinterpret_cast<float2*>(out + (size_t)node * 64 + l32 * 2);
    float2 v = *po;
    v.x += ax * inv; v.y += ay * inv;
    *po = v;
}

// ---------------- launch ----------------

extern "C" void kernel_launch(void* const* d_in, const int* in_sizes, int n_in,
                              void* d_out, int out_size, void* d_ws, size_t ws_size,
                              hipStream_t stream) {
    const float* x        = (const float*)d_in[0];
    const int*   src      = (const int*)d_in[1];
    const int*   dst      = (const int*)d_in[2];
    const float* W_self1  = (const float*)d_in[3];
    const float* W_neigh1 = (const float*)d_in[4];
    const float* b1       = (const float*)d_in[5];
    const float* W_self2  = (const float*)d_in[6];
    const float* W_neigh2 = (const float*)d_in[7];
    const float* b2       = (const float*)d_in[8];
    float* out = (float*)d_out;

    const int N = in_sizes[0] / 128;
    const int E = in_sizes[1];
    const int NB = (N + 127) >> BKT_SHIFT;     // 782 buckets

    char* ws = (char*)d_ws;
    size_t off = 0;
    auto carve = [&](size_t bytes) {
        char* p = ws + off;
        off = (off + bytes + 255) & ~(size_t)255;
        return p;
    };
    int*   bucket_cnt = (int*)carve((size_t)(NB + 1) * 4);
    int*   bbase      = (int*)carve((size_t)(NB + 1) * 4);
    int*   bcursor    = (int*)carve((size_t)NB * 4);
    int*   row_off    = (int*)carve((size_t)N * 4);
    int*   cnt        = (int*)carve((size_t)N * 4);
    float* inv_deg    = (float*)carve((size_t)N * 4);
    int*   ssorted    = (int*)carve((size_t)E * 4);
    unsigned short* Bt1 = (unsigned short*)carve(256 * 128 * 2);
    unsigned short* Bt2 = (unsigned short*)carve(128 * 128 * 2);
    unsigned short* t1  = (unsigned short*)carve((size_t)N * 128 * 2);  // reused as t2
    unsigned short* hs  = (unsigned short*)carve((size_t)N * 128 * 2);
    unsigned short* hb  = (unsigned short*)carve((size_t)N * 128 * 2);
    unsigned short* t2  = t1;                       // alias: t1 dead after agg1
    unsigned int* packed = (unsigned int*)hb;       // alias: dead before agg1 writes hb

    const int NBLK = 128;
    const int chunk = (E + NBLK - 1) / NBLK;

    // CSR build (two-level bucket sort)
    hipMemsetAsync(bucket_cnt, 0, (size_t)(NB + 1) * 4, stream);
    k_bhist<<<NBLK, 256, 0, stream>>>(dst, E, chunk, bucket_cnt, NB);
    k_bscan<<<1, 1024, 0, stream>>>(bucket_cnt, bbase, bcursor, NB, E);
    k_bscatter<<<NBLK, 256, 0, stream>>>(src, dst, E, chunk, bcursor, packed, NB);
    k_bsort<<<NB, 256, 0, stream>>>(packed, bbase, ssorted, row_off, cnt, inv_deg, N);

    // weights -> bf16 transposed
    k_prep<<<192, 256, 0, stream>>>(W_neigh1, W_self1, W_neigh2, W_self2, Bt1, Bt2);

    // layer 1: t1 = x@Wn1 (bf16), hs = x@Ws1 + b1 (bf16); fused f32->bf16 on A
    k_gemm<128, 1, 4, true, false><<<(N + 63) / 64, 256, 0, stream>>>(
        x, nullptr, N, Bt1, b1, t1, hs, nullptr);
    // h = relu(hs + mean_agg(t1)) -> hb (bf16)
    k_agg1<<<(N * 64 + 255) / 256, 256, 0, stream>>>(
        t1, hs, hb, row_off, cnt, inv_deg, ssorted, N);

    // layer 2: t2 = h@Wn2 (bf16), out = h@Ws2 + b2 (f32)
    k_gemm<64, 2, 2, false, true><<<(N + 127) / 128, 256, 0, stream>>>(
        nullptr, hb, N, Bt2, b2, t2, nullptr, out);
    // out += mean_agg(t2)
    k_agg2<<<(N * 32 + 255) / 256, 256, 0, stream>>>(
        t2, out, row_off, cnt, inv_deg, ssorted, N);
}

// Round 4
// 255.245 us; speedup vs baseline: 2.3830x; 1.0662x over previous
//
#include <hip/hip_runtime.h>
#include <hip/hip_bf16.h>

// GraphSAGE 2-layer, mean aggregator.
//   L1: h  = relu(x @ Wself1 + mean_agg(x) @ Wneigh1 + b1)
//   L2: out = h @ Wself2 + mean_agg(h) @ Wneigh2 + b2
// Transform-first aggregation. bf16 MFMA GEMMs (fp32 accum) with
// swapped-operand output layout + LDS-staged coalesced epilogue
// (R3 epilogue did scattered 2B stores -> 1.5x write amp, 1.4 TB/s).
// CSR by dst via two-level bucket sort.

typedef __attribute__((ext_vector_type(8))) short short8;
typedef __attribute__((ext_vector_type(4))) float f32x4;

#define BKT_SHIFT 7                 // 128 nodes per bucket
#define SBUF_CAP 4096               // max staged edges per bucket (avg ~2046)

__device__ __forceinline__ unsigned short f2bf(float f) {
    unsigned int u = __builtin_bit_cast(unsigned int, f);
    u += 0x7fffu + ((u >> 16) & 1u);   // RNE
    return (unsigned short)(u >> 16);
}
__device__ __forceinline__ float bf_lo(unsigned int p) {
    return __builtin_bit_cast(float, p << 16);
}
__device__ __forceinline__ float bf_hi(unsigned int p) {
    return __builtin_bit_cast(float, p & 0xffff0000u);
}

// ---------------- CSR build: two-level bucket sort ----------------

__global__ __launch_bounds__(256) void k_bhist(
    const int* __restrict__ dst, int E, int chunk,
    int* __restrict__ bucket_cnt, int nb) {
    __shared__ int h[1024];
    for (int i = threadIdx.x; i < nb; i += 256) h[i] = 0;
    __syncthreads();
    int beg = blockIdx.x * chunk;
    int end = min(beg + chunk, E);
    for (int i = beg + threadIdx.x; i < end; i += 256)
        atomicAdd(&h[dst[i] >> BKT_SHIFT], 1);
    __syncthreads();
    for (int i = threadIdx.x; i < nb; i += 256)
        if (h[i]) atomicAdd(&bucket_cnt[i], h[i]);
}

__global__ __launch_bounds__(1024) void k_bscan(
    const int* __restrict__ bucket_cnt, int* __restrict__ base,
    int* __restrict__ cursor, int nb, int E) {
    __shared__ int s[1024];
    int t = threadIdx.x;
    int v = (t < nb) ? bucket_cnt[t] : 0;
    s[t] = v;
    __syncthreads();
    for (int o = 1; o < 1024; o <<= 1) {
        int x = (t >= o) ? s[t - o] : 0;
        __syncthreads();
        s[t] += x;
        __syncthreads();
    }
    if (t < nb) {
        int excl = s[t] - v;
        base[t] = excl;
        cursor[t] = excl;
    }
    if (t == 0) base[nb] = E;
}

__global__ __launch_bounds__(256) void k_bscatter(
    const int* __restrict__ src, const int* __restrict__ dst, int E, int chunk,
    int* __restrict__ cursor, unsigned int* __restrict__ packed, int nb) {
    __shared__ int h[1024];
    __shared__ int cb[1024];
    for (int i = threadIdx.x; i < nb; i += 256) h[i] = 0;
    __syncthreads();
    int beg = blockIdx.x * chunk;
    int end = min(beg + chunk, E);
    for (int i = beg + threadIdx.x; i < end; i += 256)
        atomicAdd(&h[dst[i] >> BKT_SHIFT], 1);
    __syncthreads();
    for (int i = threadIdx.x; i < nb; i += 256) {
        cb[i] = h[i] ? atomicAdd(&cursor[i], h[i]) : 0;
    }
    __syncthreads();
    for (int i = threadIdx.x; i < nb; i += 256) h[i] = 0;  // reuse as local cursor
    __syncthreads();
    for (int i = beg + threadIdx.x; i < end; i += 256) {
        int d = dst[i];
        int b = d >> BKT_SHIFT;
        int loc = atomicAdd(&h[b], 1);
        packed[cb[b] + loc] = ((unsigned int)(d & 127) << 17) | (unsigned int)src[i];
    }
}

__global__ __launch_bounds__(256) void k_bsort(
    const unsigned int* __restrict__ packed, const int* __restrict__ base,
    int* __restrict__ ssorted, int* __restrict__ row_off, int* __restrict__ cnt,
    float* __restrict__ inv_deg, int n) {
    __shared__ int h128[128];
    __shared__ int ex[128];
    __shared__ int sbuf[SBUF_CAP];
    int t = threadIdx.x;
    int b = blockIdx.x;
    int beg = base[b], end = base[b + 1];
    int m = end - beg;
    if (t < 128) h128[t] = 0;
    __syncthreads();
    for (int i = t; i < m; i += 256)
        atomicAdd(&h128[packed[beg + i] >> 17], 1);
    __syncthreads();
    if (t < 128) ex[t] = h128[t];
    __syncthreads();
    for (int o = 1; o < 128; o <<= 1) {
        int v = (t < 128 && t >= o) ? ex[t - o] : 0;
        __syncthreads();
        if (t < 128) ex[t] += v;
        __syncthreads();
    }
    if (t < 128) {
        int deg = h128[t];
        ex[t] -= deg;  // exclusive
        int node = (b << BKT_SHIFT) + t;
        if (node < n) {
            row_off[node] = beg + ex[t];
            cnt[node] = deg;
            inv_deg[node] = 1.0f / fmaxf((float)deg, 1.0f);
        }
    }
    __syncthreads();
    if (t < 128) h128[t] = 0;  // reuse as cursor
    __syncthreads();
    if (m <= SBUF_CAP) {
        for (int i = t; i < m; i += 256) {
            unsigned int p = packed[beg + i];
            int dl = p >> 17;
            int loc = atomicAdd(&h128[dl], 1);
            sbuf[ex[dl] + loc] = (int)(p & 0x1FFFFu);
        }
        __syncthreads();
        for (int i = t; i < m; i += 256) ssorted[beg + i] = sbuf[i];
    } else {
        for (int i = t; i < m; i += 256) {
            unsigned int p = packed[beg + i];
            int dl = p >> 17;
            int loc = atomicAdd(&h128[dl], 1);
            ssorted[beg + ex[dl] + loc] = (int)(p & 0x1FFFFu);
        }
    }
}

// ---------------- weight prep: transpose + bf16 ----------------
__global__ void k_prep(const float* __restrict__ Wn1, const float* __restrict__ Ws1,
                       const float* __restrict__ Wn2, const float* __restrict__ Ws2,
                       unsigned short* __restrict__ Bt1, unsigned short* __restrict__ Bt2) {
    int i = blockIdx.x * 256 + threadIdx.x;
    if (i < 256 * 128) {
        int c = i >> 7, k = i & 127;
        float v = (c < 128) ? Wn1[k * 128 + c] : Ws1[k * 128 + (c - 128)];
        Bt1[i] = f2bf(v);
    } else {
        int j = i - 256 * 128;
        if (j < 128 * 128) {
            int c = j >> 7, k = j & 127;
            float v = (c < 64) ? Wn2[k * 64 + c] : Ws2[k * 64 + (c - 64)];
            Bt2[j] = f2bf(v);
        }
    }
}

// ---------------- bf16 MFMA dual-output GEMM (coalesced epilogue) ----------------
// A [nrows x 128]; Bt [TC x 128] bf16 K-contiguous (cols 0..MO-1 -> O1,
// MO..TC-1 -> O2 + bias). Swapped-operand MFMA: lane holds 4 consecutive
// output cols of one row -> packed LDS stage -> uint4 coalesced copy-out.
// !O2F32: single combined bf16 output Ocomb [nrows x TC].
//  O2F32: O1b = bf16 [nrows x MO], O2f = f32 [nrows x MO] (+bias).
template <int MO, int NWR, int NWC, bool AF32, bool O2F32>
__global__ __launch_bounds__(256, 3) void k_gemm(
    const float* __restrict__ Af, const unsigned short* __restrict__ Ab, int nrows,
    const unsigned short* __restrict__ Bt, const float* __restrict__ bias,
    unsigned short* __restrict__ O1, float* __restrict__ O2f) {
    constexpr int TC = 2 * MO;
    constexpr int BR = 64 * NWR;
    constexpr int PB = (O2F32 ? MO : TC) + 8;   // bf16 stage pitch (elems)
    constexpr int PF = MO + 4;                  // f32 stage pitch (words)

    __shared__ unsigned short sb[BR][PB];
    __shared__ float sf[O2F32 ? BR : 1][O2F32 ? PF : 1];

    const int tid = threadIdx.x;
    const int w = tid >> 6, lane = tid & 63;
    const int l15 = lane & 15, lg = lane >> 4;
    const int wr = w / NWC, wc = w % NWC;
    const int row0w = blockIdx.x * BR + wr * 64;
    const int col0 = wc * 64;

    f32x4 acc[4][4];
#pragma unroll
    for (int rt = 0; rt < 4; ++rt)
#pragma unroll
        for (int ct = 0; ct < 4; ++ct) acc[rt][ct] = (f32x4)0.f;

#pragma unroll
    for (int ks = 0; ks < 4; ++ks) {
        short8 bf[4];
#pragma unroll
        for (int ct = 0; ct < 4; ++ct)
            bf[ct] = *reinterpret_cast<const short8*>(
                Bt + (size_t)(col0 + ct * 16 + l15) * 128 + ks * 32 + lg * 8);
        short8 af[4];
#pragma unroll
        for (int rt = 0; rt < 4; ++rt) {
            int row = row0w + rt * 16 + l15;
            int rc = row < nrows ? row : nrows - 1;
            if constexpr (AF32) {
                const float* p = Af + (size_t)rc * 128 + ks * 32 + lg * 8;
                float4 a = *reinterpret_cast<const float4*>(p);
                float4 b = *reinterpret_cast<const float4*>(p + 4);
                short8 v;
                v[0] = (short)f2bf(a.x); v[1] = (short)f2bf(a.y);
                v[2] = (short)f2bf(a.z); v[3] = (short)f2bf(a.w);
                v[4] = (short)f2bf(b.x); v[5] = (short)f2bf(b.y);
                v[6] = (short)f2bf(b.z); v[7] = (short)f2bf(b.w);
                af[rt] = v;
            } else {
                af[rt] = *reinterpret_cast<const short8*>(
                    Ab + (size_t)rc * 128 + ks * 32 + lg * 8);
            }
        }
        // swapped operands: D = (A@B)^T layout -> lane: row = l15, cols = lg*4+r
#pragma unroll
        for (int rt = 0; rt < 4; ++rt)
#pragma unroll
            for (int ct = 0; ct < 4; ++ct)
                acc[rt][ct] = __builtin_amdgcn_mfma_f32_16x16x32_bf16(
                    bf[ct], af[rt], acc[rt][ct], 0, 0, 0);
    }

    // stage to LDS: lane holds rows (rt*16+l15), cols (ct*16+lg*4 .. +3)
#pragma unroll
    for (int rt = 0; rt < 4; ++rt) {
#pragma unroll
        for (int ct = 0; ct < 4; ++ct) {
            int rowL = wr * 64 + rt * 16 + l15;
            int colL = col0 + ct * 16 + lg * 4;
            f32x4 a = acc[rt][ct];
            if (colL >= MO) {
                float4 bv = *reinterpret_cast<const float4*>(bias + (colL - MO));
                a[0] += bv.x; a[1] += bv.y; a[2] += bv.z; a[3] += bv.w;
                if constexpr (O2F32) {
                    *reinterpret_cast<f32x4*>(&sf[rowL][colL - MO]) = a;
                    continue;
                }
            }
            unsigned int lo = (unsigned int)f2bf(a[0]) | ((unsigned int)f2bf(a[1]) << 16);
            unsigned int hi = (unsigned int)f2bf(a[2]) | ((unsigned int)f2bf(a[3]) << 16);
            *reinterpret_cast<uint2*>(&sb[rowL][colL]) = make_uint2(lo, hi);
        }
    }
    __syncthreads();

    // coalesced copy-out (uint4 per thread)
    const int row0 = blockIdx.x * BR;
    if constexpr (!O2F32) {
        constexpr int RCH = TC / 8;               // 16B chunks per row
#pragma unroll
        for (int it = 0; it < (BR * RCH) / 256; ++it) {
            int c = tid + 256 * it;
            int row = c / RCH, off = c % RCH;
            if (row0 + row < nrows) {
                uint4 v = *reinterpret_cast<const uint4*>(
                    reinterpret_cast<const char*>(&sb[row][0]) + off * 16);
                *reinterpret_cast<uint4*>(
                    reinterpret_cast<char*>(O1) + (size_t)(row0 + row) * (TC * 2) + off * 16) = v;
            }
        }
    } else {
        constexpr int RCH1 = MO / 8;              // bf16 out chunks per row
#pragma unroll
        for (int it = 0; it < (BR * RCH1) / 256; ++it) {
            int c = tid + 256 * it;
            int row = c / RCH1, off = c % RCH1;
            if (row0 + row < nrows) {
                uint4 v = *reinterpret_cast<const uint4*>(
                    reinterpret_cast<const char*>(&sb[row][0]) + off * 16);
                *reinterpret_cast<uint4*>(
                    reinterpret_cast<char*>(O1) + (size_t)(row0 + row) * (MO * 2) + off * 16) = v;
            }
        }
        constexpr int RCHF = MO / 4;              // f32 out chunks per row
#pragma unroll
        for (int it = 0; it < (BR * RCHF) / 256; ++it) {
            int c = tid + 256 * it;
            int row = c / RCHF, off = c % RCHF;
            if (row0 + row < nrows) {
                f32x4 v = *reinterpret_cast<const f32x4*>(&sf[row][off * 4]);
                *reinterpret_cast<f32x4*>(O2f + (size_t)(row0 + row) * MO + off * 4) = v;
            }
        }
    }
}

// ---------------- aggregation ----------------
// layer 1: wave per node. Tbuf[N][256]: cols 0-127 = t1 (neigh-transformed),
// 128-255 = hs (self+bias). h = relu(hs + mean(t1[src])) -> hb bf16.
__global__ __launch_bounds__(256) void k_agg1(
    const unsigned short* __restrict__ Tbuf, unsigned short* __restrict__ hb,
    const int* __restrict__ row_off, const int* __restrict__ cnt,
    const float* __restrict__ inv_deg, const int* __restrict__ ssorted, int n) {
    int node = (blockIdx.x * 256 + threadIdx.x) >> 6;
    int lane = threadIdx.x & 63;
    if (node >= n) return;
    int beg = row_off[node], d = cnt[node];
    float ax = 0.f, ay = 0.f;
    for (int base = 0; base < d; base += 64) {
        int m = d - base; if (m > 64) m = 64;
        int sv = (lane < m) ? ssorted[beg + base + lane] : 0;
        int j = 0;
        for (; j + 4 <= m; j += 4) {
            int s0 = __shfl(sv, j), s1 = __shfl(sv, j + 1);
            int s2 = __shfl(sv, j + 2), s3 = __shfl(sv, j + 3);
            unsigned int p0 = *reinterpret_cast<const unsigned int*>(Tbuf + (size_t)s0 * 256 + lane * 2);
            unsigned int p1 = *reinterpret_cast<const unsigned int*>(Tbuf + (size_t)s1 * 256 + lane * 2);
            unsigned int p2 = *reinterpret_cast<const unsigned int*>(Tbuf + (size_t)s2 * 256 + lane * 2);
            unsigned int p3 = *reinterpret_cast<const unsigned int*>(Tbuf + (size_t)s3 * 256 + lane * 2);
            ax += bf_lo(p0) + bf_lo(p1) + bf_lo(p2) + bf_lo(p3);
            ay += bf_hi(p0) + bf_hi(p1) + bf_hi(p2) + bf_hi(p3);
        }
        for (; j < m; ++j) {
            int s = __shfl(sv, j);
            unsigned int p = *reinterpret_cast<const unsigned int*>(Tbuf + (size_t)s * 256 + lane * 2);
            ax += bf_lo(p); ay += bf_hi(p);
        }
    }
    float inv = inv_deg[node];
    unsigned int q = *reinterpret_cast<const unsigned int*>(Tbuf + (size_t)node * 256 + 128 + lane * 2);
    float hx = fmaxf(bf_lo(q) + ax * inv, 0.f);
    float hy = fmaxf(bf_hi(q) + ay * inv, 0.f);
    *reinterpret_cast<unsigned int*>(hb + (size_t)node * 128 + lane * 2) =
        (unsigned int)f2bf(hx) | ((unsigned int)f2bf(hy) << 16);
}

// layer 2: half-wave per node, 64 dims. out += mean(t2[src]).
__global__ __launch_bounds__(256) void k_agg2(
    const unsigned short* __restrict__ t2, float* __restrict__ out,
    const int* __restrict__ row_off, const int* __restrict__ cnt,
    const float* __restrict__ inv_deg, const int* __restrict__ ssorted, int n) {
    int node = (blockIdx.x * 256 + threadIdx.x) >> 5;
    int l32 = threadIdx.x & 31;
    if (node >= n) return;
    int beg = row_off[node], d = cnt[node];
    float ax = 0.f, ay = 0.f;
    for (int base = 0; base < d; base += 32) {
        int m = d - base; if (m > 32) m = 32;
        int sv = (l32 < m) ? ssorted[beg + base + l32] : 0;
        int j = 0;
        for (; j + 4 <= m; j += 4) {
            int s0 = __shfl(sv, j, 32), s1 = __shfl(sv, j + 1, 32);
            int s2 = __shfl(sv, j + 2, 32), s3 = __shfl(sv, j + 3, 32);
            unsigned int p0 = *reinterpret_cast<const unsigned int*>(t2 + (size_t)s0 * 64 + l32 * 2);
            unsigned int p1 = *reinterpret_cast<const unsigned int*>(t2 + (size_t)s1 * 64 + l32 * 2);
            unsigned int p2 = *reinterpret_cast<const unsigned int*>(t2 + (size_t)s2 * 64 + l32 * 2);
            unsigned int p3 = *reinterpret_cast<const unsigned int*>(t2 + (size_t)s3 * 64 + l32 * 2);
            ax += bf_lo(p0) + bf_lo(p1) + bf_lo(p2) + bf_lo(p3);
            ay += bf_hi(p0) + bf_hi(p1) + bf_hi(p2) + bf_hi(p3);
        }
        for (; j < m; ++j) {
            int s = __shfl(sv, j, 32);
            unsigned int p = *reinterpret_cast<const unsigned int*>(t2 + (size_t)s * 64 + l32 * 2);
            ax += bf_lo(p); ay += bf_hi(p);
        }
    }
    float inv = inv_deg[node];
    float2* po = reinterpret_cast<float2*>(out + (size_t)node * 64 + l32 * 2);
    float2 v = *po;
    v.x += ax * inv; v.y += ay * inv;
    *po = v;
}

// ---------------- launch ----------------

extern "C" void kernel_launch(void* const* d_in, const int* in_sizes, int n_in,
                              void* d_out, int out_size, void* d_ws, size_t ws_size,
                              hipStream_t stream) {
    const float* x        = (const float*)d_in[0];
    const int*   src      = (const int*)d_in[1];
    const int*   dst      = (const int*)d_in[2];
    const float* W_self1  = (const float*)d_in[3];
    const float* W_neigh1 = (const float*)d_in[4];
    const float* b1       = (const float*)d_in[5];
    const float* W_self2  = (const float*)d_in[6];
    const float* W_neigh2 = (const float*)d_in[7];
    const float* b2       = (const float*)d_in[8];
    float* out = (float*)d_out;

    const int N = in_sizes[0] / 128;
    const int E = in_sizes[1];
    const int NB = (N + 127) >> BKT_SHIFT;     // 782 buckets

    char* ws = (char*)d_ws;
    size_t off = 0;
    auto carve = [&](size_t bytes) {
        char* p = ws + off;
        off = (off + bytes + 255) & ~(size_t)255;
        return p;
    };
    int*   bucket_cnt = (int*)carve((size_t)(NB + 1) * 4);
    int*   bbase      = (int*)carve((size_t)(NB + 1) * 4);
    int*   bcursor    = (int*)carve((size_t)NB * 4);
    int*   row_off    = (int*)carve((size_t)N * 4);
    int*   cnt        = (int*)carve((size_t)N * 4);
    float* inv_deg    = (float*)carve((size_t)N * 4);
    int*   ssorted    = (int*)carve((size_t)E * 4);
    unsigned short* Bt1  = (unsigned short*)carve(256 * 128 * 2);
    unsigned short* Bt2  = (unsigned short*)carve(128 * 128 * 2);
    unsigned short* Tbuf = (unsigned short*)carve((size_t)N * 256 * 2); // [t1|hs]
    unsigned short* hb   = (unsigned short*)carve((size_t)N * 128 * 2);
    unsigned short* t2   = Tbuf;                    // alias: Tbuf dead after agg1
    unsigned int* packed = (unsigned int*)hb;       // alias: dead before agg1 writes hb

    const int NBLK = 128;
    const int chunk = (E + NBLK - 1) / NBLK;

    // CSR build (two-level bucket sort)
    hipMemsetAsync(bucket_cnt, 0, (size_t)(NB + 1) * 4, stream);
    k_bhist<<<NBLK, 256, 0, stream>>>(dst, E, chunk, bucket_cnt, NB);
    k_bscan<<<1, 1024, 0, stream>>>(bucket_cnt, bbase, bcursor, NB, E);
    k_bscatter<<<NBLK, 256, 0, stream>>>(src, dst, E, chunk, bcursor, packed, NB);
    k_bsort<<<NB, 256, 0, stream>>>(packed, bbase, ssorted, row_off, cnt, inv_deg, N);

    // weights -> bf16 transposed
    k_prep<<<192, 256, 0, stream>>>(W_neigh1, W_self1, W_neigh2, W_self2, Bt1, Bt2);

    // layer 1: Tbuf = [x@Wn1 | x@Ws1 + b1] (bf16, combined row)
    k_gemm<128, 1, 4, true, false><<<(N + 63) / 64, 256, 0, stream>>>(
        x, nullptr, N, Bt1, b1, Tbuf, nullptr);
    // h = relu(hs + mean_agg(t1)) -> hb (bf16)
    k_agg1<<<(N * 64 + 255) / 256, 256, 0, stream>>>(
        Tbuf, hb, row_off, cnt, inv_deg, ssorted, N);

    // layer 2: t2 = h@Wn2 (bf16), out = h@Ws2 + b2 (f32)
    k_gemm<64, 2, 2, false, true><<<(N + 127) / 128, 256, 0, stream>>>(
        nullptr, hb, N, Bt2, b2, t2, out);
    // out += mean_agg(t2)
    k_agg2<<<(N * 32 + 255) / 256, 256, 0, stream>>>(
        t2, out, row_off, cnt, inv_deg, ssorted, N);
}

// Round 5
// 250.780 us; speedup vs baseline: 2.4254x; 1.0178x over previous
//
#include <hip/hip_runtime.h>
#include <hip/hip_bf16.h>

// GraphSAGE 2-layer, mean aggregator.
//   L1: h  = relu(x @ Wself1 + mean_agg(x) @ Wneigh1 + b1)
//   L2: out = h @ Wself2 + mean_agg(h) @ Wneigh2 + b2
// Transform-first aggregation. bf16 MFMA GEMMs (fp32 accum), swapped-operand
// layout + LDS-staged coalesced epilogue. CSR by dst via two-level bucket
// sort. R5: aggregation restructured for deep MLP (half-/quarter-wave per
// node, uint2 gathers, 8-deep unroll) - R4 showed latency-bound gathers
// (VALUBusy 38%, 42% HBM peak).

typedef __attribute__((ext_vector_type(8))) short short8;
typedef __attribute__((ext_vector_type(4))) float f32x4;

#define BKT_SHIFT 7                 // 128 nodes per bucket
#define SBUF_CAP 4096               // max staged edges per bucket (avg ~2046)

__device__ __forceinline__ unsigned short f2bf(float f) {
    unsigned int u = __builtin_bit_cast(unsigned int, f);
    u += 0x7fffu + ((u >> 16) & 1u);   // RNE
    return (unsigned short)(u >> 16);
}
__device__ __forceinline__ float bf_lo(unsigned int p) {
    return __builtin_bit_cast(float, p << 16);
}
__device__ __forceinline__ float bf_hi(unsigned int p) {
    return __builtin_bit_cast(float, p & 0xffff0000u);
}

// ---------------- CSR build: two-level bucket sort ----------------

__global__ __launch_bounds__(256) void k_bhist(
    const int* __restrict__ dst, int E, int chunk,
    int* __restrict__ bucket_cnt, int nb) {
    __shared__ int h[1024];
    for (int i = threadIdx.x; i < nb; i += 256) h[i] = 0;
    __syncthreads();
    int beg = blockIdx.x * chunk;
    int end = min(beg + chunk, E);
    for (int i = beg + threadIdx.x; i < end; i += 256)
        atomicAdd(&h[dst[i] >> BKT_SHIFT], 1);
    __syncthreads();
    for (int i = threadIdx.x; i < nb; i += 256)
        if (h[i]) atomicAdd(&bucket_cnt[i], h[i]);
}

__global__ __launch_bounds__(1024) void k_bscan(
    const int* __restrict__ bucket_cnt, int* __restrict__ base,
    int* __restrict__ cursor, int nb, int E) {
    __shared__ int s[1024];
    int t = threadIdx.x;
    int v = (t < nb) ? bucket_cnt[t] : 0;
    s[t] = v;
    __syncthreads();
    for (int o = 1; o < 1024; o <<= 1) {
        int x = (t >= o) ? s[t - o] : 0;
        __syncthreads();
        s[t] += x;
        __syncthreads();
    }
    if (t < nb) {
        int excl = s[t] - v;
        base[t] = excl;
        cursor[t] = excl;
    }
    if (t == 0) base[nb] = E;
}

__global__ __launch_bounds__(256) void k_bscatter(
    const int* __restrict__ src, const int* __restrict__ dst, int E, int chunk,
    int* __restrict__ cursor, unsigned int* __restrict__ packed, int nb) {
    __shared__ int h[1024];
    __shared__ int cb[1024];
    for (int i = threadIdx.x; i < nb; i += 256) h[i] = 0;
    __syncthreads();
    int beg = blockIdx.x * chunk;
    int end = min(beg + chunk, E);
    for (int i = beg + threadIdx.x; i < end; i += 256)
        atomicAdd(&h[dst[i] >> BKT_SHIFT], 1);
    __syncthreads();
    for (int i = threadIdx.x; i < nb; i += 256) {
        cb[i] = h[i] ? atomicAdd(&cursor[i], h[i]) : 0;
    }
    __syncthreads();
    for (int i = threadIdx.x; i < nb; i += 256) h[i] = 0;  // reuse as local cursor
    __syncthreads();
    for (int i = beg + threadIdx.x; i < end; i += 256) {
        int d = dst[i];
        int b = d >> BKT_SHIFT;
        int loc = atomicAdd(&h[b], 1);
        packed[cb[b] + loc] = ((unsigned int)(d & 127) << 17) | (unsigned int)src[i];
    }
}

__global__ __launch_bounds__(256) void k_bsort(
    const unsigned int* __restrict__ packed, const int* __restrict__ base,
    int* __restrict__ ssorted, int* __restrict__ row_off, int* __restrict__ cnt,
    float* __restrict__ inv_deg, int n) {
    __shared__ int h128[128];
    __shared__ int ex[128];
    __shared__ int sbuf[SBUF_CAP];
    int t = threadIdx.x;
    int b = blockIdx.x;
    int beg = base[b], end = base[b + 1];
    int m = end - beg;
    if (t < 128) h128[t] = 0;
    __syncthreads();
    for (int i = t; i < m; i += 256)
        atomicAdd(&h128[packed[beg + i] >> 17], 1);
    __syncthreads();
    if (t < 128) ex[t] = h128[t];
    __syncthreads();
    for (int o = 1; o < 128; o <<= 1) {
        int v = (t < 128 && t >= o) ? ex[t - o] : 0;
        __syncthreads();
        if (t < 128) ex[t] += v;
        __syncthreads();
    }
    if (t < 128) {
        int deg = h128[t];
        ex[t] -= deg;  // exclusive
        int node = (b << BKT_SHIFT) + t;
        if (node < n) {
            row_off[node] = beg + ex[t];
            cnt[node] = deg;
            inv_deg[node] = 1.0f / fmaxf((float)deg, 1.0f);
        }
    }
    __syncthreads();
    if (t < 128) h128[t] = 0;  // reuse as cursor
    __syncthreads();
    if (m <= SBUF_CAP) {
        for (int i = t; i < m; i += 256) {
            unsigned int p = packed[beg + i];
            int dl = p >> 17;
            int loc = atomicAdd(&h128[dl], 1);
            sbuf[ex[dl] + loc] = (int)(p & 0x1FFFFu);
        }
        __syncthreads();
        for (int i = t; i < m; i += 256) ssorted[beg + i] = sbuf[i];
    } else {
        for (int i = t; i < m; i += 256) {
            unsigned int p = packed[beg + i];
            int dl = p >> 17;
            int loc = atomicAdd(&h128[dl], 1);
            ssorted[beg + ex[dl] + loc] = (int)(p & 0x1FFFFu);
        }
    }
}

// ---------------- weight prep: transpose + bf16 ----------------
__global__ void k_prep(const float* __restrict__ Wn1, const float* __restrict__ Ws1,
                       const float* __restrict__ Wn2, const float* __restrict__ Ws2,
                       unsigned short* __restrict__ Bt1, unsigned short* __restrict__ Bt2) {
    int i = blockIdx.x * 256 + threadIdx.x;
    if (i < 256 * 128) {
        int c = i >> 7, k = i & 127;
        float v = (c < 128) ? Wn1[k * 128 + c] : Ws1[k * 128 + (c - 128)];
        Bt1[i] = f2bf(v);
    } else {
        int j = i - 256 * 128;
        if (j < 128 * 128) {
            int c = j >> 7, k = j & 127;
            float v = (c < 64) ? Wn2[k * 64 + c] : Ws2[k * 64 + (c - 64)];
            Bt2[j] = f2bf(v);
        }
    }
}

// ---------------- bf16 MFMA dual-output GEMM (coalesced epilogue) ----------------
template <int MO, int NWR, int NWC, bool AF32, bool O2F32>
__global__ __launch_bounds__(256, 3) void k_gemm(
    const float* __restrict__ Af, const unsigned short* __restrict__ Ab, int nrows,
    const unsigned short* __restrict__ Bt, const float* __restrict__ bias,
    unsigned short* __restrict__ O1, float* __restrict__ O2f) {
    constexpr int TC = 2 * MO;
    constexpr int BR = 64 * NWR;
    constexpr int PB = (O2F32 ? MO : TC) + 8;   // bf16 stage pitch (elems)
    constexpr int PF = MO + 4;                  // f32 stage pitch (words)

    __shared__ unsigned short sb[BR][PB];
    __shared__ float sf[O2F32 ? BR : 1][O2F32 ? PF : 1];

    const int tid = threadIdx.x;
    const int w = tid >> 6, lane = tid & 63;
    const int l15 = lane & 15, lg = lane >> 4;
    const int wr = w / NWC, wc = w % NWC;
    const int row0w = blockIdx.x * BR + wr * 64;
    const int col0 = wc * 64;

    f32x4 acc[4][4];
#pragma unroll
    for (int rt = 0; rt < 4; ++rt)
#pragma unroll
        for (int ct = 0; ct < 4; ++ct) acc[rt][ct] = (f32x4)0.f;

#pragma unroll
    for (int ks = 0; ks < 4; ++ks) {
        short8 bf[4];
#pragma unroll
        for (int ct = 0; ct < 4; ++ct)
            bf[ct] = *reinterpret_cast<const short8*>(
                Bt + (size_t)(col0 + ct * 16 + l15) * 128 + ks * 32 + lg * 8);
        short8 af[4];
#pragma unroll
        for (int rt = 0; rt < 4; ++rt) {
            int row = row0w + rt * 16 + l15;
            int rc = row < nrows ? row : nrows - 1;
            if constexpr (AF32) {
                const float* p = Af + (size_t)rc * 128 + ks * 32 + lg * 8;
                float4 a = *reinterpret_cast<const float4*>(p);
                float4 b = *reinterpret_cast<const float4*>(p + 4);
                short8 v;
                v[0] = (short)f2bf(a.x); v[1] = (short)f2bf(a.y);
                v[2] = (short)f2bf(a.z); v[3] = (short)f2bf(a.w);
                v[4] = (short)f2bf(b.x); v[5] = (short)f2bf(b.y);
                v[6] = (short)f2bf(b.z); v[7] = (short)f2bf(b.w);
                af[rt] = v;
            } else {
                af[rt] = *reinterpret_cast<const short8*>(
                    Ab + (size_t)rc * 128 + ks * 32 + lg * 8);
            }
        }
        // swapped operands: lane holds row = l15, cols = lg*4 + r
#pragma unroll
        for (int rt = 0; rt < 4; ++rt)
#pragma unroll
            for (int ct = 0; ct < 4; ++ct)
                acc[rt][ct] = __builtin_amdgcn_mfma_f32_16x16x32_bf16(
                    bf[ct], af[rt], acc[rt][ct], 0, 0, 0);
    }

#pragma unroll
    for (int rt = 0; rt < 4; ++rt) {
#pragma unroll
        for (int ct = 0; ct < 4; ++ct) {
            int rowL = wr * 64 + rt * 16 + l15;
            int colL = col0 + ct * 16 + lg * 4;
            f32x4 a = acc[rt][ct];
            if (colL >= MO) {
                float4 bv = *reinterpret_cast<const float4*>(bias + (colL - MO));
                a[0] += bv.x; a[1] += bv.y; a[2] += bv.z; a[3] += bv.w;
                if constexpr (O2F32) {
                    *reinterpret_cast<f32x4*>(&sf[rowL][colL - MO]) = a;
                    continue;
                }
            }
            unsigned int lo = (unsigned int)f2bf(a[0]) | ((unsigned int)f2bf(a[1]) << 16);
            unsigned int hi = (unsigned int)f2bf(a[2]) | ((unsigned int)f2bf(a[3]) << 16);
            *reinterpret_cast<uint2*>(&sb[rowL][colL]) = make_uint2(lo, hi);
        }
    }
    __syncthreads();

    const int row0 = blockIdx.x * BR;
    if constexpr (!O2F32) {
        constexpr int RCH = TC / 8;
#pragma unroll
        for (int it = 0; it < (BR * RCH) / 256; ++it) {
            int c = tid + 256 * it;
            int row = c / RCH, off = c % RCH;
            if (row0 + row < nrows) {
                uint4 v = *reinterpret_cast<const uint4*>(
                    reinterpret_cast<const char*>(&sb[row][0]) + off * 16);
                *reinterpret_cast<uint4*>(
                    reinterpret_cast<char*>(O1) + (size_t)(row0 + row) * (TC * 2) + off * 16) = v;
            }
        }
    } else {
        constexpr int RCH1 = MO / 8;
#pragma unroll
        for (int it = 0; it < (BR * RCH1) / 256; ++it) {
            int c = tid + 256 * it;
            int row = c / RCH1, off = c % RCH1;
            if (row0 + row < nrows) {
                uint4 v = *reinterpret_cast<const uint4*>(
                    reinterpret_cast<const char*>(&sb[row][0]) + off * 16);
                *reinterpret_cast<uint4*>(
                    reinterpret_cast<char*>(O1) + (size_t)(row0 + row) * (MO * 2) + off * 16) = v;
            }
        }
        constexpr int RCHF = MO / 4;
#pragma unroll
        for (int it = 0; it < (BR * RCHF) / 256; ++it) {
            int c = tid + 256 * it;
            int row = c / RCHF, off = c % RCHF;
            if (row0 + row < nrows) {
                f32x4 v = *reinterpret_cast<const f32x4*>(&sf[row][off * 4]);
                *reinterpret_cast<f32x4*>(O2f + (size_t)(row0 + row) * MO + off * 4) = v;
            }
        }
    }
}

// ---------------- aggregation ----------------
// layer 1: HALF-WAVE (32 lanes) per node, uint2 (4 bf16) per lane, 8-deep
// unrolled gather batches. Tbuf[N][256]: cols 0-127 = t1, 128-255 = hs.
__global__ __launch_bounds__(256) void k_agg1(
    const unsigned short* __restrict__ Tbuf, unsigned short* __restrict__ hb,
    const int* __restrict__ row_off, const int* __restrict__ cnt,
    const float* __restrict__ inv_deg, const int* __restrict__ ssorted, int n) {
    int node = (blockIdx.x * 256 + threadIdx.x) >> 5;
    int l = threadIdx.x & 31;
    if (node >= n) return;
    int beg = row_off[node], d = cnt[node];
    float a0 = 0.f, a1 = 0.f, a2 = 0.f, a3 = 0.f;
    for (int base = 0; base < d; base += 32) {
        int m = d - base; if (m > 32) m = 32;
        int sv = (l < m) ? ssorted[beg + base + l] : 0;
        int j = 0;
        for (; j + 8 <= m; j += 8) {
            uint2 p[8];
#pragma unroll
            for (int q = 0; q < 8; ++q) {
                int s = __shfl(sv, j + q, 32);
                p[q] = *reinterpret_cast<const uint2*>(Tbuf + (size_t)s * 256 + l * 4);
            }
#pragma unroll
            for (int q = 0; q < 8; ++q) {
                a0 += bf_lo(p[q].x); a1 += bf_hi(p[q].x);
                a2 += bf_lo(p[q].y); a3 += bf_hi(p[q].y);
            }
        }
        for (; j < m; ++j) {
            int s = __shfl(sv, j, 32);
            uint2 p = *reinterpret_cast<const uint2*>(Tbuf + (size_t)s * 256 + l * 4);
            a0 += bf_lo(p.x); a1 += bf_hi(p.x);
            a2 += bf_lo(p.y); a3 += bf_hi(p.y);
        }
    }
    float inv = inv_deg[node];
    uint2 q = *reinterpret_cast<const uint2*>(Tbuf + (size_t)node * 256 + 128 + l * 4);
    float h0 = fmaxf(bf_lo(q.x) + a0 * inv, 0.f);
    float h1 = fmaxf(bf_hi(q.x) + a1 * inv, 0.f);
    float h2 = fmaxf(bf_lo(q.y) + a2 * inv, 0.f);
    float h3 = fmaxf(bf_hi(q.y) + a3 * inv, 0.f);
    uint2 o;
    o.x = (unsigned int)f2bf(h0) | ((unsigned int)f2bf(h1) << 16);
    o.y = (unsigned int)f2bf(h2) | ((unsigned int)f2bf(h3) << 16);
    *reinterpret_cast<uint2*>(hb + (size_t)node * 128 + l * 4) = o;
}

// layer 2: QUARTER-WAVE (16 lanes) per node, uint2 per lane, 8-deep unroll.
// out += mean(t2[src]).
__global__ __launch_bounds__(256) void k_agg2(
    const unsigned short* __restrict__ t2, float* __restrict__ out,
    const int* __restrict__ row_off, const int* __restrict__ cnt,
    const float* __restrict__ inv_deg, const int* __restrict__ ssorted, int n) {
    int node = (blockIdx.x * 256 + threadIdx.x) >> 4;
    int l = threadIdx.x & 15;
    if (node >= n) return;
    int beg = row_off[node], d = cnt[node];
    float a0 = 0.f, a1 = 0.f, a2 = 0.f, a3 = 0.f;
    for (int base = 0; base < d; base += 16) {
        int m = d - base; if (m > 16) m = 16;
        int sv = (l < m) ? ssorted[beg + base + l] : 0;
        int j = 0;
        for (; j + 8 <= m; j += 8) {
            uint2 p[8];
#pragma unroll
            for (int q = 0; q < 8; ++q) {
                int s = __shfl(sv, j + q, 16);
                p[q] = *reinterpret_cast<const uint2*>(t2 + (size_t)s * 64 + l * 4);
            }
#pragma unroll
            for (int q = 0; q < 8; ++q) {
                a0 += bf_lo(p[q].x); a1 += bf_hi(p[q].x);
                a2 += bf_lo(p[q].y); a3 += bf_hi(p[q].y);
            }
        }
        for (; j < m; ++j) {
            int s = __shfl(sv, j, 16);
            uint2 p = *reinterpret_cast<const uint2*>(t2 + (size_t)s * 64 + l * 4);
            a0 += bf_lo(p.x); a1 += bf_hi(p.x);
            a2 += bf_lo(p.y); a3 += bf_hi(p.y);
        }
    }
    float inv = inv_deg[node];
    float4* po = reinterpret_cast<float4*>(out + (size_t)node * 64 + l * 4);
    float4 v = *po;
    v.x += a0 * inv; v.y += a1 * inv; v.z += a2 * inv; v.w += a3 * inv;
    *po = v;
}

// ---------------- launch ----------------

extern "C" void kernel_launch(void* const* d_in, const int* in_sizes, int n_in,
                              void* d_out, int out_size, void* d_ws, size_t ws_size,
                              hipStream_t stream) {
    const float* x        = (const float*)d_in[0];
    const int*   src      = (const int*)d_in[1];
    const int*   dst      = (const int*)d_in[2];
    const float* W_self1  = (const float*)d_in[3];
    const float* W_neigh1 = (const float*)d_in[4];
    const float* b1       = (const float*)d_in[5];
    const float* W_self2  = (const float*)d_in[6];
    const float* W_neigh2 = (const float*)d_in[7];
    const float* b2       = (const float*)d_in[8];
    float* out = (float*)d_out;

    const int N = in_sizes[0] / 128;
    const int E = in_sizes[1];
    const int NB = (N + 127) >> BKT_SHIFT;     // 782 buckets

    char* ws = (char*)d_ws;
    size_t off = 0;
    auto carve = [&](size_t bytes) {
        char* p = ws + off;
        off = (off + bytes + 255) & ~(size_t)255;
        return p;
    };
    int*   bucket_cnt = (int*)carve((size_t)(NB + 1) * 4);
    int*   bbase      = (int*)carve((size_t)(NB + 1) * 4);
    int*   bcursor    = (int*)carve((size_t)NB * 4);
    int*   row_off    = (int*)carve((size_t)N * 4);
    int*   cnt        = (int*)carve((size_t)N * 4);
    float* inv_deg    = (float*)carve((size_t)N * 4);
    int*   ssorted    = (int*)carve((size_t)E * 4);
    unsigned short* Bt1  = (unsigned short*)carve(256 * 128 * 2);
    unsigned short* Bt2  = (unsigned short*)carve(128 * 128 * 2);
    unsigned short* Tbuf = (unsigned short*)carve((size_t)N * 256 * 2); // [t1|hs]
    unsigned short* hb   = (unsigned short*)carve((size_t)N * 128 * 2);
    unsigned short* t2   = Tbuf;                    // alias: Tbuf dead after agg1
    unsigned int* packed = (unsigned int*)hb;       // alias: dead before agg1 writes hb

    const int NBLK = 128;
    const int chunk = (E + NBLK - 1) / NBLK;

    // CSR build (two-level bucket sort)
    hipMemsetAsync(bucket_cnt, 0, (size_t)(NB + 1) * 4, stream);
    k_bhist<<<NBLK, 256, 0, stream>>>(dst, E, chunk, bucket_cnt, NB);
    k_bscan<<<1, 1024, 0, stream>>>(bucket_cnt, bbase, bcursor, NB, E);
    k_bscatter<<<NBLK, 256, 0, stream>>>(src, dst, E, chunk, bcursor, packed, NB);
    k_bsort<<<NB, 256, 0, stream>>>(packed, bbase, ssorted, row_off, cnt, inv_deg, N);

    // weights -> bf16 transposed
    k_prep<<<192, 256, 0, stream>>>(W_neigh1, W_self1, W_neigh2, W_self2, Bt1, Bt2);

    // layer 1: Tbuf = [x@Wn1 | x@Ws1 + b1] (bf16, combined row)
    k_gemm<128, 1, 4, true, false><<<(N + 63) / 64, 256, 0, stream>>>(
        x, nullptr, N, Bt1, b1, Tbuf, nullptr);
    // h = relu(hs + mean_agg(t1)) -> hb (bf16)
    k_agg1<<<(N * 32 + 255) / 256, 256, 0, stream>>>(
        Tbuf, hb, row_off, cnt, inv_deg, ssorted, N);

    // layer 2: t2 = h@Wn2 (bf16), out = h@Ws2 + b2 (f32)
    k_gemm<64, 2, 2, false, true><<<(N + 127) / 128, 256, 0, stream>>>(
        nullptr, hb, N, Bt2, b2, t2, out);
    // out += mean_agg(t2)
    k_agg2<<<(N * 16 + 255) / 256, 256, 0, stream>>>(
        t2, out, row_off, cnt, inv_deg, ssorted, N);
}

// Round 6
// 223.055 us; speedup vs baseline: 2.7269x; 1.1243x over previous
//
#include <hip/hip_runtime.h>
#include <hip/hip_bf16.h>

// GraphSAGE 2-layer, mean aggregator.
//   L1: h  = relu(x @ Wself1 + mean_agg(x) @ Wneigh1 + b1)
//   L2: out = h @ Wself2 + mean_agg(h) @ Wneigh2 + b2
// Transform-first aggregation. bf16 MFMA GEMMs (fp32 accum), swapped-operand
// layout + LDS-staged coalesced epilogue. CSR by dst via radix-style
// 3-phase bucket sort with ZERO global atomics (R5 showed contended
// global cursor atomics stalled k_bscatter at 61us / 4.8% occupancy).

typedef __attribute__((ext_vector_type(8))) short short8;
typedef __attribute__((ext_vector_type(4))) float f32x4;

#define BKT_SHIFT 7                 // 128 nodes per bucket
#define SBUF_CAP 4096               // max staged edges per bucket (avg ~2046)
#define GHIST 512                   // hist/scatter blocks (PER=8 per lane in scan)

__device__ __forceinline__ unsigned short f2bf(float f) {
    unsigned int u = __builtin_bit_cast(unsigned int, f);
    u += 0x7fffu + ((u >> 16) & 1u);   // RNE
    return (unsigned short)(u >> 16);
}
__device__ __forceinline__ float bf_lo(unsigned int p) {
    return __builtin_bit_cast(float, p << 16);
}
__device__ __forceinline__ float bf_hi(unsigned int p) {
    return __builtin_bit_cast(float, p & 0xffff0000u);
}

// ---------------- CSR build: radix 3-phase, no global atomics ----------------

// phase 1: per-block LDS histogram -> Hist[blk][nb] (coalesced stores)
__global__ __launch_bounds__(256) void k_hist2(
    const int* __restrict__ dst, int E, int chunk,
    int* __restrict__ Hist, int nb) {
    __shared__ int h[1024];
    for (int i = threadIdx.x; i < nb; i += 256) h[i] = 0;
    __syncthreads();
    int beg = blockIdx.x * chunk;
    int end = min(beg + chunk, E);
    for (int i = beg + threadIdx.x; i < end; i += 256)
        atomicAdd(&h[dst[i] >> BKT_SHIFT], 1);
    __syncthreads();
    int* o = Hist + (size_t)blockIdx.x * nb;
    for (int i = threadIdx.x; i < nb; i += 256) o[i] = h[i];
}

// phase 2a: one wave per bucket — exclusive scan over GHIST block counts,
// in-place (Hist -> Off), emit bucket totals.
__global__ __launch_bounds__(256) void k_scanb(
    int* __restrict__ Hist, int* __restrict__ Tot, int nb) {
    int wave = (blockIdx.x * 256 + threadIdx.x) >> 6;
    int lane = threadIdx.x & 63;
    if (wave >= nb) return;
    const int b = wave;
    constexpr int PER = GHIST / 64;   // 8
    int v[PER];
    int s = 0;
    int blk0 = lane * PER;
#pragma unroll
    for (int j = 0; j < PER; ++j) {
        v[j] = Hist[(size_t)(blk0 + j) * nb + b];
        s += v[j];
    }
    int incl = s;
#pragma unroll
    for (int o = 1; o < 64; o <<= 1) {
        int t = __shfl_up(incl, o);
        if (lane >= o) incl += t;
    }
    int run = incl - s;   // exclusive
#pragma unroll
    for (int j = 0; j < PER; ++j) {
        int t = v[j];
        Hist[(size_t)(blk0 + j) * nb + b] = run;
        run += t;
    }
    if (lane == 63) Tot[b] = incl;
}

// phase 2b: single block — exclusive scan of bucket totals -> Base
__global__ __launch_bounds__(1024) void k_scant(
    const int* __restrict__ Tot, int* __restrict__ Base, int nb, int E) {
    __shared__ int s[1024];
    int t = threadIdx.x;
    int v = (t < nb) ? Tot[t] : 0;
    s[t] = v;
    __syncthreads();
    for (int o = 1; o < 1024; o <<= 1) {
        int x = (t >= o) ? s[t - o] : 0;
        __syncthreads();
        s[t] += x;
        __syncthreads();
    }
    if (t < nb) Base[t] = s[t] - v;  // exclusive
    if (t == 0) Base[nb] = E;
}

// phase 3: scatter with precomputed per-(block,bucket) cursors; LDS-only rank.
__global__ __launch_bounds__(256) void k_scatter2(
    const int* __restrict__ src, const int* __restrict__ dst, int E, int chunk,
    const int* __restrict__ Off, const int* __restrict__ Base,
    unsigned int* __restrict__ packed, int nb) {
    __shared__ int cb[1024];
    __shared__ int h[1024];
    const int blk = blockIdx.x;
    for (int i = threadIdx.x; i < nb; i += 256) {
        cb[i] = Base[i] + Off[(size_t)blk * nb + i];
        h[i] = 0;
    }
    __syncthreads();
    int beg = blk * chunk;
    int end = min(beg + chunk, E);
    for (int i = beg + threadIdx.x; i < end; i += 256) {
        int d = dst[i];
        int b = d >> BKT_SHIFT;
        int loc = atomicAdd(&h[b], 1);
        packed[cb[b] + loc] = ((unsigned int)(d & 127) << 17) | (unsigned int)src[i];
    }
}

// phase 4: per-bucket counting sort (block per bucket); emits row_off/cnt/
// inv_deg and fully-coalesced ssorted writes via LDS staging.
__global__ __launch_bounds__(256) void k_bsort(
    const unsigned int* __restrict__ packed, const int* __restrict__ base,
    int* __restrict__ ssorted, int* __restrict__ row_off, int* __restrict__ cnt,
    float* __restrict__ inv_deg, int n) {
    __shared__ int h128[128];
    __shared__ int ex[128];
    __shared__ int sbuf[SBUF_CAP];
    int t = threadIdx.x;
    int b = blockIdx.x;
    int beg = base[b], end = base[b + 1];
    int m = end - beg;
    if (t < 128) h128[t] = 0;
    __syncthreads();
    for (int i = t; i < m; i += 256)
        atomicAdd(&h128[packed[beg + i] >> 17], 1);
    __syncthreads();
    if (t < 128) ex[t] = h128[t];
    __syncthreads();
    for (int o = 1; o < 128; o <<= 1) {
        int v = (t < 128 && t >= o) ? ex[t - o] : 0;
        __syncthreads();
        if (t < 128) ex[t] += v;
        __syncthreads();
    }
    if (t < 128) {
        int deg = h128[t];
        ex[t] -= deg;  // exclusive
        int node = (b << BKT_SHIFT) + t;
        if (node < n) {
            row_off[node] = beg + ex[t];
            cnt[node] = deg;
            inv_deg[node] = 1.0f / fmaxf((float)deg, 1.0f);
        }
    }
    __syncthreads();
    if (t < 128) h128[t] = 0;  // reuse as cursor
    __syncthreads();
    if (m <= SBUF_CAP) {
        for (int i = t; i < m; i += 256) {
            unsigned int p = packed[beg + i];
            int dl = p >> 17;
            int loc = atomicAdd(&h128[dl], 1);
            sbuf[ex[dl] + loc] = (int)(p & 0x1FFFFu);
        }
        __syncthreads();
        for (int i = t; i < m; i += 256) ssorted[beg + i] = sbuf[i];
    } else {
        for (int i = t; i < m; i += 256) {
            unsigned int p = packed[beg + i];
            int dl = p >> 17;
            int loc = atomicAdd(&h128[dl], 1);
            ssorted[beg + ex[dl] + loc] = (int)(p & 0x1FFFFu);
        }
    }
}

// ---------------- weight prep: transpose + bf16 ----------------
__global__ void k_prep(const float* __restrict__ Wn1, const float* __restrict__ Ws1,
                       const float* __restrict__ Wn2, const float* __restrict__ Ws2,
                       unsigned short* __restrict__ Bt1, unsigned short* __restrict__ Bt2) {
    int i = blockIdx.x * 256 + threadIdx.x;
    if (i < 256 * 128) {
        int c = i >> 7, k = i & 127;
        float v = (c < 128) ? Wn1[k * 128 + c] : Ws1[k * 128 + (c - 128)];
        Bt1[i] = f2bf(v);
    } else {
        int j = i - 256 * 128;
        if (j < 128 * 128) {
            int c = j >> 7, k = j & 127;
            float v = (c < 64) ? Wn2[k * 64 + c] : Ws2[k * 64 + (c - 64)];
            Bt2[j] = f2bf(v);
        }
    }
}

// ---------------- bf16 MFMA dual-output GEMM (coalesced epilogue) ----------------
template <int MO, int NWR, int NWC, bool AF32, bool O2F32>
__global__ __launch_bounds__(256, 3) void k_gemm(
    const float* __restrict__ Af, const unsigned short* __restrict__ Ab, int nrows,
    const unsigned short* __restrict__ Bt, const float* __restrict__ bias,
    unsigned short* __restrict__ O1, float* __restrict__ O2f) {
    constexpr int TC = 2 * MO;
    constexpr int BR = 64 * NWR;
    constexpr int PB = (O2F32 ? MO : TC) + 8;   // bf16 stage pitch (elems)
    constexpr int PF = MO + 4;                  // f32 stage pitch (words)

    __shared__ unsigned short sb[BR][PB];
    __shared__ float sf[O2F32 ? BR : 1][O2F32 ? PF : 1];

    const int tid = threadIdx.x;
    const int w = tid >> 6, lane = tid & 63;
    const int l15 = lane & 15, lg = lane >> 4;
    const int wr = w / NWC, wc = w % NWC;
    const int row0w = blockIdx.x * BR + wr * 64;
    const int col0 = wc * 64;

    f32x4 acc[4][4];
#pragma unroll
    for (int rt = 0; rt < 4; ++rt)
#pragma unroll
        for (int ct = 0; ct < 4; ++ct) acc[rt][ct] = (f32x4)0.f;

#pragma unroll
    for (int ks = 0; ks < 4; ++ks) {
        short8 bf[4];
#pragma unroll
        for (int ct = 0; ct < 4; ++ct)
            bf[ct] = *reinterpret_cast<const short8*>(
                Bt + (size_t)(col0 + ct * 16 + l15) * 128 + ks * 32 + lg * 8);
        short8 af[4];
#pragma unroll
        for (int rt = 0; rt < 4; ++rt) {
            int row = row0w + rt * 16 + l15;
            int rc = row < nrows ? row : nrows - 1;
            if constexpr (AF32) {
                const float* p = Af + (size_t)rc * 128 + ks * 32 + lg * 8;
                float4 a = *reinterpret_cast<const float4*>(p);
                float4 b = *reinterpret_cast<const float4*>(p + 4);
                short8 v;
                v[0] = (short)f2bf(a.x); v[1] = (short)f2bf(a.y);
                v[2] = (short)f2bf(a.z); v[3] = (short)f2bf(a.w);
                v[4] = (short)f2bf(b.x); v[5] = (short)f2bf(b.y);
                v[6] = (short)f2bf(b.z); v[7] = (short)f2bf(b.w);
                af[rt] = v;
            } else {
                af[rt] = *reinterpret_cast<const short8*>(
                    Ab + (size_t)rc * 128 + ks * 32 + lg * 8);
            }
        }
        // swapped operands: lane holds row = l15, cols = lg*4 + r
#pragma unroll
        for (int rt = 0; rt < 4; ++rt)
#pragma unroll
            for (int ct = 0; ct < 4; ++ct)
                acc[rt][ct] = __builtin_amdgcn_mfma_f32_16x16x32_bf16(
                    bf[ct], af[rt], acc[rt][ct], 0, 0, 0);
    }

#pragma unroll
    for (int rt = 0; rt < 4; ++rt) {
#pragma unroll
        for (int ct = 0; ct < 4; ++ct) {
            int rowL = wr * 64 + rt * 16 + l15;
            int colL = col0 + ct * 16 + lg * 4;
            f32x4 a = acc[rt][ct];
            if (colL >= MO) {
                float4 bv = *reinterpret_cast<const float4*>(bias + (colL - MO));
                a[0] += bv.x; a[1] += bv.y; a[2] += bv.z; a[3] += bv.w;
                if constexpr (O2F32) {
                    *reinterpret_cast<f32x4*>(&sf[rowL][colL - MO]) = a;
                    continue;
                }
            }
            unsigned int lo = (unsigned int)f2bf(a[0]) | ((unsigned int)f2bf(a[1]) << 16);
            unsigned int hi = (unsigned int)f2bf(a[2]) | ((unsigned int)f2bf(a[3]) << 16);
            *reinterpret_cast<uint2*>(&sb[rowL][colL]) = make_uint2(lo, hi);
        }
    }
    __syncthreads();

    const int row0 = blockIdx.x * BR;
    if constexpr (!O2F32) {
        constexpr int RCH = TC / 8;
#pragma unroll
        for (int it = 0; it < (BR * RCH) / 256; ++it) {
            int c = tid + 256 * it;
            int row = c / RCH, off = c % RCH;
            if (row0 + row < nrows) {
                uint4 v = *reinterpret_cast<const uint4*>(
                    reinterpret_cast<const char*>(&sb[row][0]) + off * 16);
                *reinterpret_cast<uint4*>(
                    reinterpret_cast<char*>(O1) + (size_t)(row0 + row) * (TC * 2) + off * 16) = v;
            }
        }
    } else {
        constexpr int RCH1 = MO / 8;
#pragma unroll
        for (int it = 0; it < (BR * RCH1) / 256; ++it) {
            int c = tid + 256 * it;
            int row = c / RCH1, off = c % RCH1;
            if (row0 + row < nrows) {
                uint4 v = *reinterpret_cast<const uint4*>(
                    reinterpret_cast<const char*>(&sb[row][0]) + off * 16);
                *reinterpret_cast<uint4*>(
                    reinterpret_cast<char*>(O1) + (size_t)(row0 + row) * (MO * 2) + off * 16) = v;
            }
        }
        constexpr int RCHF = MO / 4;
#pragma unroll
        for (int it = 0; it < (BR * RCHF) / 256; ++it) {
            int c = tid + 256 * it;
            int row = c / RCHF, off = c % RCHF;
            if (row0 + row < nrows) {
                f32x4 v = *reinterpret_cast<const f32x4*>(&sf[row][off * 4]);
                *reinterpret_cast<f32x4*>(O2f + (size_t)(row0 + row) * MO + off * 4) = v;
            }
        }
    }
}

// ---------------- aggregation ----------------
// layer 1: half-wave (32 lanes) per node, uint2 (4 bf16) per lane, 8-deep
// unrolled gather batches. Tbuf[N][256]: cols 0-127 = t1, 128-255 = hs.
__global__ __launch_bounds__(256) void k_agg1(
    const unsigned short* __restrict__ Tbuf, unsigned short* __restrict__ hb,
    const int* __restrict__ row_off, const int* __restrict__ cnt,
    const float* __restrict__ inv_deg, const int* __restrict__ ssorted, int n) {
    int node = (blockIdx.x * 256 + threadIdx.x) >> 5;
    int l = threadIdx.x & 31;
    if (node >= n) return;
    int beg = row_off[node], d = cnt[node];
    float a0 = 0.f, a1 = 0.f, a2 = 0.f, a3 = 0.f;
    for (int base = 0; base < d; base += 32) {
        int m = d - base; if (m > 32) m = 32;
        int sv = (l < m) ? ssorted[beg + base + l] : 0;
        int j = 0;
        for (; j + 8 <= m; j += 8) {
            uint2 p[8];
#pragma unroll
            for (int q = 0; q < 8; ++q) {
                int s = __shfl(sv, j + q, 32);
                p[q] = *reinterpret_cast<const uint2*>(Tbuf + (size_t)s * 256 + l * 4);
            }
#pragma unroll
            for (int q = 0; q < 8; ++q) {
                a0 += bf_lo(p[q].x); a1 += bf_hi(p[q].x);
                a2 += bf_lo(p[q].y); a3 += bf_hi(p[q].y);
            }
        }
        for (; j < m; ++j) {
            int s = __shfl(sv, j, 32);
            uint2 p = *reinterpret_cast<const uint2*>(Tbuf + (size_t)s * 256 + l * 4);
            a0 += bf_lo(p.x); a1 += bf_hi(p.x);
            a2 += bf_lo(p.y); a3 += bf_hi(p.y);
        }
    }
    float inv = inv_deg[node];
    uint2 q = *reinterpret_cast<const uint2*>(Tbuf + (size_t)node * 256 + 128 + l * 4);
    float h0 = fmaxf(bf_lo(q.x) + a0 * inv, 0.f);
    float h1 = fmaxf(bf_hi(q.x) + a1 * inv, 0.f);
    float h2 = fmaxf(bf_lo(q.y) + a2 * inv, 0.f);
    float h3 = fmaxf(bf_hi(q.y) + a3 * inv, 0.f);
    uint2 o;
    o.x = (unsigned int)f2bf(h0) | ((unsigned int)f2bf(h1) << 16);
    o.y = (unsigned int)f2bf(h2) | ((unsigned int)f2bf(h3) << 16);
    *reinterpret_cast<uint2*>(hb + (size_t)node * 128 + l * 4) = o;
}

// layer 2: quarter-wave (16 lanes) per node, uint2 per lane, 8-deep unroll.
// out += mean(t2[src]).
__global__ __launch_bounds__(256) void k_agg2(
    const unsigned short* __restrict__ t2, float* __restrict__ out,
    const int* __restrict__ row_off, const int* __restrict__ cnt,
    const float* __restrict__ inv_deg, const int* __restrict__ ssorted, int n) {
    int node = (blockIdx.x * 256 + threadIdx.x) >> 4;
    int l = threadIdx.x & 15;
    if (node >= n) return;
    int beg = row_off[node], d = cnt[node];
    float a0 = 0.f, a1 = 0.f, a2 = 0.f, a3 = 0.f;
    for (int base = 0; base < d; base += 16) {
        int m = d - base; if (m > 16) m = 16;
        int sv = (l < m) ? ssorted[beg + base + l] : 0;
        int j = 0;
        for (; j + 8 <= m; j += 8) {
            uint2 p[8];
#pragma unroll
            for (int q = 0; q < 8; ++q) {
                int s = __shfl(sv, j + q, 16);
                p[q] = *reinterpret_cast<const uint2*>(t2 + (size_t)s * 64 + l * 4);
            }
#pragma unroll
            for (int q = 0; q < 8; ++q) {
                a0 += bf_lo(p[q].x); a1 += bf_hi(p[q].x);
                a2 += bf_lo(p[q].y); a3 += bf_hi(p[q].y);
            }
        }
        for (; j < m; ++j) {
            int s = __shfl(sv, j, 16);
            uint2 p = *reinterpret_cast<const uint2*>(t2 + (size_t)s * 64 + l * 4);
            a0 += bf_lo(p.x); a1 += bf_hi(p.x);
            a2 += bf_lo(p.y); a3 += bf_hi(p.y);
        }
    }
    float inv = inv_deg[node];
    float4* po = reinterpret_cast<float4*>(out + (size_t)node * 64 + l * 4);
    float4 v = *po;
    v.x += a0 * inv; v.y += a1 * inv; v.z += a2 * inv; v.w += a3 * inv;
    *po = v;
}

// ---------------- launch ----------------

extern "C" void kernel_launch(void* const* d_in, const int* in_sizes, int n_in,
                              void* d_out, int out_size, void* d_ws, size_t ws_size,
                              hipStream_t stream) {
    const float* x        = (const float*)d_in[0];
    const int*   src      = (const int*)d_in[1];
    const int*   dst      = (const int*)d_in[2];
    const float* W_self1  = (const float*)d_in[3];
    const float* W_neigh1 = (const float*)d_in[4];
    const float* b1       = (const float*)d_in[5];
    const float* W_self2  = (const float*)d_in[6];
    const float* W_neigh2 = (const float*)d_in[7];
    const float* b2       = (const float*)d_in[8];
    float* out = (float*)d_out;

    const int N = in_sizes[0] / 128;
    const int E = in_sizes[1];
    const int NB = (N + 127) >> BKT_SHIFT;     // 782 buckets

    char* ws = (char*)d_ws;
    size_t off = 0;
    auto carve = [&](size_t bytes) {
        char* p = ws + off;
        off = (off + bytes + 255) & ~(size_t)255;
        return p;
    };
    int*   Hist    = (int*)carve((size_t)GHIST * NB * 4);   // -> Off (in-place)
    int*   Tot     = (int*)carve((size_t)NB * 4);
    int*   Base    = (int*)carve((size_t)(NB + 1) * 4);
    int*   row_off = (int*)carve((size_t)N * 4);
    int*   cnt     = (int*)carve((size_t)N * 4);
    float* inv_deg = (float*)carve((size_t)N * 4);
    int*   ssorted = (int*)carve((size_t)E * 4);
    unsigned short* Bt1  = (unsigned short*)carve(256 * 128 * 2);
    unsigned short* Bt2  = (unsigned short*)carve(128 * 128 * 2);
    unsigned short* Tbuf = (unsigned short*)carve((size_t)N * 256 * 2); // [t1|hs]
    unsigned short* hb   = (unsigned short*)carve((size_t)N * 128 * 2);
    unsigned short* t2   = Tbuf;                    // alias: Tbuf dead after agg1
    unsigned int* packed = (unsigned int*)hb;       // alias: dead before agg1 writes hb

    const int chunk = (E + GHIST - 1) / GHIST;

    // CSR build (radix 3-phase, no global atomics)
    k_hist2<<<GHIST, 256, 0, stream>>>(dst, E, chunk, Hist, NB);
    k_scanb<<<(NB + 3) / 4, 256, 0, stream>>>(Hist, Tot, NB);
    k_scant<<<1, 1024, 0, stream>>>(Tot, Base, NB, E);
    k_scatter2<<<GHIST, 256, 0, stream>>>(src, dst, E, chunk, Hist, Base, packed, NB);
    k_bsort<<<NB, 256, 0, stream>>>(packed, Base, ssorted, row_off, cnt, inv_deg, N);

    // weights -> bf16 transposed
    k_prep<<<192, 256, 0, stream>>>(W_neigh1, W_self1, W_neigh2, W_self2, Bt1, Bt2);

    // layer 1: Tbuf = [x@Wn1 | x@Ws1 + b1] (bf16, combined row)
    k_gemm<128, 1, 4, true, false><<<(N + 63) / 64, 256, 0, stream>>>(
        x, nullptr, N, Bt1, b1, Tbuf, nullptr);
    // h = relu(hs + mean_agg(t1)) -> hb (bf16)
    k_agg1<<<(N * 32 + 255) / 256, 256, 0, stream>>>(
        Tbuf, hb, row_off, cnt, inv_deg, ssorted, N);

    // layer 2: t2 = h@Wn2 (bf16), out = h@Ws2 + b2 (f32)
    k_gemm<64, 2, 2, false, true><<<(N + 127) / 128, 256, 0, stream>>>(
        nullptr, hb, N, Bt2, b2, t2, out);
    // out += mean_agg(t2)
    k_agg2<<<(N * 16 + 255) / 256, 256, 0, stream>>>(
        t2, out, row_off, cnt, inv_deg, ssorted, N);
}

// Round 8
// 202.944 us; speedup vs baseline: 2.9971x; 1.0991x over previous
//
#include <hip/hip_runtime.h>
#include <hip/hip_bf16.h>

// GraphSAGE 2-layer, mean aggregator.
//   L1: h  = relu(x @ Wself1 + mean_agg(x) @ Wneigh1 + b1)
//   L2: out = h @ Wself2 + mean_agg(h) @ Wneigh2 + b2
// Transform-first aggregation. bf16 MFMA GEMMs (fp32 accum), LDS-staged
// coalesced epilogues. CSR by dst via radix 3-phase sort (no global atomics).
// R8: t1 (layer-1 neighbor payload) stored fp8 e4m3 -> gather row = 128B =
// one cache line (halves the L2-miss bytes that capped k_agg1 at 3.6 TB/s).
// (R7 compile fix: cvt_pk_f32_fp8 word-select must be an immediate ->
// template parameter.)

typedef __attribute__((ext_vector_type(8))) short short8;
typedef __attribute__((ext_vector_type(4))) float f32x4;
typedef __attribute__((ext_vector_type(2))) float f32x2;

#define BKT_SHIFT 7                 // 128 nodes per bucket
#define SBUF_CAP 4096               // max staged edges per bucket (avg ~2046)
#define GHIST 512                   // hist/scatter blocks

__device__ __forceinline__ unsigned short f2bf(float f) {
    unsigned int u = __builtin_bit_cast(unsigned int, f);
    u += 0x7fffu + ((u >> 16) & 1u);   // RNE
    return (unsigned short)(u >> 16);
}
__device__ __forceinline__ float bf_lo(unsigned int p) {
    return __builtin_bit_cast(float, p << 16);
}
__device__ __forceinline__ float bf_hi(unsigned int p) {
    return __builtin_bit_cast(float, p & 0xffff0000u);
}

// ---- fp8 e4m3 helpers (HW cvt on gfx950; bit-trick fallback) ----
template <bool WORD>
__device__ __forceinline__ f32x2 fp8pair_to_f32(unsigned int v) {
#if __has_builtin(__builtin_amdgcn_cvt_pk_f32_fp8)
    return __builtin_amdgcn_cvt_pk_f32_fp8(v, WORD);
#else
    unsigned int b = WORD ? (v >> 16) : v;
    f32x2 r;
#pragma unroll
    for (int i = 0; i < 2; ++i) {
        unsigned int byte = (b >> (8 * i)) & 0xffu;
        float f = __builtin_bit_cast(float, (byte & 0x7fu) << 20) * 0x1p+120f;
        r[i] = (byte & 0x80u) ? -f : f;
    }
    return r;
#endif
}
__device__ __forceinline__ unsigned int enc_fp8(float v) {
    float c = fminf(fmaxf(v, -448.f), 448.f);
    unsigned int s = (__builtin_bit_cast(unsigned int, c) >> 24) & 0x80u;
    unsigned int bits = __builtin_bit_cast(unsigned int, fabsf(c) * 0x1p-120f);
    bits += 0x7FFFFu + ((bits >> 20) & 1u);
    unsigned int mag = bits >> 20;
    if (mag > 0x7Eu) mag = 0x7Eu;
    return s | mag;
}
__device__ __forceinline__ unsigned int f32x4_to_fp8x4(float a0, float a1,
                                                       float a2, float a3) {
#if __has_builtin(__builtin_amdgcn_cvt_pk_fp8_f32)
    int p = __builtin_amdgcn_cvt_pk_fp8_f32(a0, a1, 0, false);
    p = __builtin_amdgcn_cvt_pk_fp8_f32(a2, a3, p, true);
    return (unsigned int)p;
#else
    return enc_fp8(a0) | (enc_fp8(a1) << 8) | (enc_fp8(a2) << 16) | (enc_fp8(a3) << 24);
#endif
}

// ---------------- CSR build: radix 3-phase, no global atomics ----------------

__global__ __launch_bounds__(256) void k_hist2(
    const int* __restrict__ dst, int E, int chunk,
    int* __restrict__ Hist, int nb) {
    __shared__ int h[1024];
    for (int i = threadIdx.x; i < nb; i += 256) h[i] = 0;
    __syncthreads();
    int beg = blockIdx.x * chunk;
    int end = min(beg + chunk, E);
    for (int i = beg + threadIdx.x; i < end; i += 256)
        atomicAdd(&h[dst[i] >> BKT_SHIFT], 1);
    __syncthreads();
    int* o = Hist + (size_t)blockIdx.x * nb;
    for (int i = threadIdx.x; i < nb; i += 256) o[i] = h[i];
}

__global__ __launch_bounds__(256) void k_scanb(
    int* __restrict__ Hist, int* __restrict__ Tot, int nb) {
    int wave = (blockIdx.x * 256 + threadIdx.x) >> 6;
    int lane = threadIdx.x & 63;
    if (wave >= nb) return;
    const int b = wave;
    constexpr int PER = GHIST / 64;   // 8
    int v[PER];
    int s = 0;
    int blk0 = lane * PER;
#pragma unroll
    for (int j = 0; j < PER; ++j) {
        v[j] = Hist[(size_t)(blk0 + j) * nb + b];
        s += v[j];
    }
    int incl = s;
#pragma unroll
    for (int o = 1; o < 64; o <<= 1) {
        int t = __shfl_up(incl, o);
        if (lane >= o) incl += t;
    }
    int run = incl - s;   // exclusive
#pragma unroll
    for (int j = 0; j < PER; ++j) {
        int t = v[j];
        Hist[(size_t)(blk0 + j) * nb + b] = run;
        run += t;
    }
    if (lane == 63) Tot[b] = incl;
}

__global__ __launch_bounds__(1024) void k_scant(
    const int* __restrict__ Tot, int* __restrict__ Base, int nb, int E) {
    __shared__ int s[1024];
    int t = threadIdx.x;
    int v = (t < nb) ? Tot[t] : 0;
    s[t] = v;
    __syncthreads();
    for (int o = 1; o < 1024; o <<= 1) {
        int x = (t >= o) ? s[t - o] : 0;
        __syncthreads();
        s[t] += x;
        __syncthreads();
    }
    if (t < nb) Base[t] = s[t] - v;  // exclusive
    if (t == 0) Base[nb] = E;
}

__global__ __launch_bounds__(256) void k_scatter2(
    const int* __restrict__ src, const int* __restrict__ dst, int E, int chunk,
    const int* __restrict__ Off, const int* __restrict__ Base,
    unsigned int* __restrict__ packed, int nb) {
    __shared__ int cb[1024];
    __shared__ int h[1024];
    const int blk = blockIdx.x;
    for (int i = threadIdx.x; i < nb; i += 256) {
        cb[i] = Base[i] + Off[(size_t)blk * nb + i];
        h[i] = 0;
    }
    __syncthreads();
    int beg = blk * chunk;
    int end = min(beg + chunk, E);
    for (int i = beg + threadIdx.x; i < end; i += 256) {
        int d = dst[i];
        int b = d >> BKT_SHIFT;
        int loc = atomicAdd(&h[b], 1);
        packed[cb[b] + loc] = ((unsigned int)(d & 127) << 17) | (unsigned int)src[i];
    }
}

__global__ __launch_bounds__(256) void k_bsort(
    const unsigned int* __restrict__ packed, const int* __restrict__ base,
    int* __restrict__ ssorted, int* __restrict__ row_off, int* __restrict__ cnt,
    float* __restrict__ inv_deg, int n) {
    __shared__ int h128[128];
    __shared__ int ex[128];
    __shared__ int sbuf[SBUF_CAP];
    int t = threadIdx.x;
    int b = blockIdx.x;
    int beg = base[b], end = base[b + 1];
    int m = end - beg;
    if (t < 128) h128[t] = 0;
    __syncthreads();
    for (int i = t; i < m; i += 256)
        atomicAdd(&h128[packed[beg + i] >> 17], 1);
    __syncthreads();
    if (t < 128) ex[t] = h128[t];
    __syncthreads();
    for (int o = 1; o < 128; o <<= 1) {
        int v = (t < 128 && t >= o) ? ex[t - o] : 0;
        __syncthreads();
        if (t < 128) ex[t] += v;
        __syncthreads();
    }
    if (t < 128) {
        int deg = h128[t];
        ex[t] -= deg;  // exclusive
        int node = (b << BKT_SHIFT) + t;
        if (node < n) {
            row_off[node] = beg + ex[t];
            cnt[node] = deg;
            inv_deg[node] = 1.0f / fmaxf((float)deg, 1.0f);
        }
    }
    __syncthreads();
    if (t < 128) h128[t] = 0;  // reuse as cursor
    __syncthreads();
    if (m <= SBUF_CAP) {
        for (int i = t; i < m; i += 256) {
            unsigned int p = packed[beg + i];
            int dl = p >> 17;
            int loc = atomicAdd(&h128[dl], 1);
            sbuf[ex[dl] + loc] = (int)(p & 0x1FFFFu);
        }
        __syncthreads();
        for (int i = t; i < m; i += 256) ssorted[beg + i] = sbuf[i];
    } else {
        for (int i = t; i < m; i += 256) {
            unsigned int p = packed[beg + i];
            int dl = p >> 17;
            int loc = atomicAdd(&h128[dl], 1);
            ssorted[beg + ex[dl] + loc] = (int)(p & 0x1FFFFu);
        }
    }
}

// ---------------- weight prep: transpose + bf16 ----------------
__global__ void k_prep(const float* __restrict__ Wn1, const float* __restrict__ Ws1,
                       const float* __restrict__ Wn2, const float* __restrict__ Ws2,
                       unsigned short* __restrict__ Bt1, unsigned short* __restrict__ Bt2) {
    int i = blockIdx.x * 256 + threadIdx.x;
    if (i < 256 * 128) {
        int c = i >> 7, k = i & 127;
        float v = (c < 128) ? Wn1[k * 128 + c] : Ws1[k * 128 + (c - 128)];
        Bt1[i] = f2bf(v);
    } else {
        int j = i - 256 * 128;
        if (j < 128 * 128) {
            int c = j >> 7, k = j & 127;
            float v = (c < 64) ? Wn2[k * 64 + c] : Ws2[k * 64 + (c - 64)];
            Bt2[j] = f2bf(v);
        }
    }
}

// ---------------- layer-1 GEMM: x(f32) @ [Wn1|Ws1] -> t1 fp8, hs bf16 ----------------
// Bt1 [256][128] bf16 K-contiguous. Block = 4 waves, BR=64 rows; wave wc owns
// cols [wc*64, wc*64+64). cols 0-127 -> t1 (fp8), 128-255 -> hs (+bias, bf16).
__global__ __launch_bounds__(256, 3) void k_gemm1(
    const float* __restrict__ Af, int nrows,
    const unsigned short* __restrict__ Bt, const float* __restrict__ bias,
    unsigned char* __restrict__ O8, unsigned short* __restrict__ Ob) {
    constexpr int BR = 64;
    __shared__ unsigned short sb[BR][136];                         // hs stage
    __shared__ __attribute__((aligned(16))) unsigned char s8[BR][144];  // t1 stage

    const int tid = threadIdx.x;
    const int w = tid >> 6, lane = tid & 63;
    const int l15 = lane & 15, lg = lane >> 4;
    const int col0 = w * 64;
    const int row0 = blockIdx.x * BR;

    f32x4 acc[4][4];
#pragma unroll
    for (int rt = 0; rt < 4; ++rt)
#pragma unroll
        for (int ct = 0; ct < 4; ++ct) acc[rt][ct] = (f32x4)0.f;

#pragma unroll
    for (int ks = 0; ks < 4; ++ks) {
        short8 bf[4];
#pragma unroll
        for (int ct = 0; ct < 4; ++ct)
            bf[ct] = *reinterpret_cast<const short8*>(
                Bt + (size_t)(col0 + ct * 16 + l15) * 128 + ks * 32 + lg * 8);
        short8 af[4];
#pragma unroll
        for (int rt = 0; rt < 4; ++rt) {
            int row = row0 + rt * 16 + l15;
            int rc = row < nrows ? row : nrows - 1;
            const float* p = Af + (size_t)rc * 128 + ks * 32 + lg * 8;
            float4 a = *reinterpret_cast<const float4*>(p);
            float4 b = *reinterpret_cast<const float4*>(p + 4);
            short8 v;
            v[0] = (short)f2bf(a.x); v[1] = (short)f2bf(a.y);
            v[2] = (short)f2bf(a.z); v[3] = (short)f2bf(a.w);
            v[4] = (short)f2bf(b.x); v[5] = (short)f2bf(b.y);
            v[6] = (short)f2bf(b.z); v[7] = (short)f2bf(b.w);
            af[rt] = v;
        }
#pragma unroll
        for (int rt = 0; rt < 4; ++rt)
#pragma unroll
            for (int ct = 0; ct < 4; ++ct)
                acc[rt][ct] = __builtin_amdgcn_mfma_f32_16x16x32_bf16(
                    bf[ct], af[rt], acc[rt][ct], 0, 0, 0);
    }

    // stage: lane holds row = rt*16+l15, cols = col0+ct*16+lg*4..+3
#pragma unroll
    for (int rt = 0; rt < 4; ++rt) {
#pragma unroll
        for (int ct = 0; ct < 4; ++ct) {
            int rowL = rt * 16 + l15;
            int colL = col0 + ct * 16 + lg * 4;
            f32x4 a = acc[rt][ct];
            if (colL < 128) {
                *reinterpret_cast<unsigned int*>(&s8[rowL][colL]) =
                    f32x4_to_fp8x4(a[0], a[1], a[2], a[3]);
            } else {
                int cc = colL - 128;
                float4 bv = *reinterpret_cast<const float4*>(bias + cc);
                unsigned int lo = (unsigned int)f2bf(a[0] + bv.x) |
                                  ((unsigned int)f2bf(a[1] + bv.y) << 16);
                unsigned int hi = (unsigned int)f2bf(a[2] + bv.z) |
                                  ((unsigned int)f2bf(a[3] + bv.w) << 16);
                *reinterpret_cast<uint2*>(&sb[rowL][cc]) = make_uint2(lo, hi);
            }
        }
    }
    __syncthreads();

    // coalesced copy-out: t1 fp8 (128B/row, 8 chunks), hs bf16 (256B/row, 16 chunks)
#pragma unroll
    for (int it = 0; it < 2; ++it) {
        int c = tid + 256 * it;
        int row = c >> 3, off = c & 7;
        if (row0 + row < nrows) {
            uint4 v = *reinterpret_cast<const uint4*>(&s8[row][off * 16]);
            *reinterpret_cast<uint4*>(O8 + (size_t)(row0 + row) * 128 + off * 16) = v;
        }
    }
#pragma unroll
    for (int it = 0; it < 4; ++it) {
        int c = tid + 256 * it;
        int row = c >> 4, off = c & 15;
        if (row0 + row < nrows) {
            uint4 v = *reinterpret_cast<const uint4*>(
                reinterpret_cast<const char*>(&sb[row][0]) + off * 16);
            *reinterpret_cast<uint4*>(
                reinterpret_cast<char*>(Ob) + (size_t)(row0 + row) * 256 + off * 16) = v;
        }
    }
}

// ---------------- layer-2 GEMM: h(bf16) @ [Wn2|Ws2] -> t2 bf16, out f32 ----------------
__global__ __launch_bounds__(256, 3) void k_gemm2(
    const unsigned short* __restrict__ Ab, int nrows,
    const unsigned short* __restrict__ Bt, const float* __restrict__ bias,
    unsigned short* __restrict__ O1, float* __restrict__ O2f) {
    constexpr int MO = 64, BR = 128;
    __shared__ unsigned short sb[BR][72];
    __shared__ float sf[BR][68];

    const int tid = threadIdx.x;
    const int w = tid >> 6, lane = tid & 63;
    const int l15 = lane & 15, lg = lane >> 4;
    const int wr = w >> 1, wc = w & 1;
    const int row0w = blockIdx.x * BR + wr * 64;
    const int col0 = wc * 64;

    f32x4 acc[4][4];
#pragma unroll
    for (int rt = 0; rt < 4; ++rt)
#pragma unroll
        for (int ct = 0; ct < 4; ++ct) acc[rt][ct] = (f32x4)0.f;

#pragma unroll
    for (int ks = 0; ks < 4; ++ks) {
        short8 bf[4];
#pragma unroll
        for (int ct = 0; ct < 4; ++ct)
            bf[ct] = *reinterpret_cast<const short8*>(
                Bt + (size_t)(col0 + ct * 16 + l15) * 128 + ks * 32 + lg * 8);
        short8 af[4];
#pragma unroll
        for (int rt = 0; rt < 4; ++rt) {
            int row = row0w + rt * 16 + l15;
            int rc = row < nrows ? row : nrows - 1;
            af[rt] = *reinterpret_cast<const short8*>(
                Ab + (size_t)rc * 128 + ks * 32 + lg * 8);
        }
#pragma unroll
        for (int rt = 0; rt < 4; ++rt)
#pragma unroll
            for (int ct = 0; ct < 4; ++ct)
                acc[rt][ct] = __builtin_amdgcn_mfma_f32_16x16x32_bf16(
                    bf[ct], af[rt], acc[rt][ct], 0, 0, 0);
    }

#pragma unroll
    for (int rt = 0; rt < 4; ++rt) {
#pragma unroll
        for (int ct = 0; ct < 4; ++ct) {
            int rowL = wr * 64 + rt * 16 + l15;
            int colL = col0 + ct * 16 + lg * 4;
            f32x4 a = acc[rt][ct];
            if (colL < MO) {
                unsigned int lo = (unsigned int)f2bf(a[0]) | ((unsigned int)f2bf(a[1]) << 16);
                unsigned int hi = (unsigned int)f2bf(a[2]) | ((unsigned int)f2bf(a[3]) << 16);
                *reinterpret_cast<uint2*>(&sb[rowL][colL]) = make_uint2(lo, hi);
            } else {
                int cc = colL - MO;
                float4 bv = *reinterpret_cast<const float4*>(bias + cc);
                a[0] += bv.x; a[1] += bv.y; a[2] += bv.z; a[3] += bv.w;
                *reinterpret_cast<f32x4*>(&sf[rowL][cc]) = a;
            }
        }
    }
    __syncthreads();

    const int row0 = blockIdx.x * BR;
#pragma unroll
    for (int it = 0; it < 4; ++it) {           // t2 bf16: 8 chunks/row
        int c = tid + 256 * it;
        int row = c >> 3, off = c & 7;
        if (row0 + row < nrows) {
            uint4 v = *reinterpret_cast<const uint4*>(
                reinterpret_cast<const char*>(&sb[row][0]) + off * 16);
            *reinterpret_cast<uint4*>(
                reinterpret_cast<char*>(O1) + (size_t)(row0 + row) * 128 + off * 16) = v;
        }
    }
#pragma unroll
    for (int it = 0; it < 8; ++it) {           // out f32: 16 chunks/row
        int c = tid + 256 * it;
        int row = c >> 4, off = c & 15;
        if (row0 + row < nrows) {
            f32x4 v = *reinterpret_cast<const f32x4*>(&sf[row][off * 4]);
            *reinterpret_cast<f32x4*>(O2f + (size_t)(row0 + row) * MO + off * 4) = v;
        }
    }
}

// ---------------- aggregation ----------------
// layer 1: half-wave per node; t1 fp8 [N][128] (1 line/gather), hs bf16 [N][128].
__global__ __launch_bounds__(256) void k_agg1(
    const unsigned char* __restrict__ t1f8, const unsigned short* __restrict__ hs,
    unsigned short* __restrict__ hb,
    const int* __restrict__ row_off, const int* __restrict__ cnt,
    const float* __restrict__ inv_deg, const int* __restrict__ ssorted, int n) {
    int node = (blockIdx.x * 256 + threadIdx.x) >> 5;
    int l = threadIdx.x & 31;
    if (node >= n) return;
    int beg = row_off[node], d = cnt[node];
    float a0 = 0.f, a1 = 0.f, a2 = 0.f, a3 = 0.f;
    for (int base = 0; base < d; base += 32) {
        int m = d - base; if (m > 32) m = 32;
        int sv = (l < m) ? ssorted[beg + base + l] : 0;
        int j = 0;
        for (; j + 8 <= m; j += 8) {
            unsigned int p[8];
#pragma unroll
            for (int q = 0; q < 8; ++q) {
                int s = __shfl(sv, j + q, 32);
                p[q] = *reinterpret_cast<const unsigned int*>(t1f8 + (size_t)s * 128 + l * 4);
            }
#pragma unroll
            for (int q = 0; q < 8; ++q) {
                f32x2 lo = fp8pair_to_f32<false>(p[q]);
                f32x2 hi = fp8pair_to_f32<true>(p[q]);
                a0 += lo[0]; a1 += lo[1]; a2 += hi[0]; a3 += hi[1];
            }
        }
        for (; j < m; ++j) {
            int s = __shfl(sv, j, 32);
            unsigned int p = *reinterpret_cast<const unsigned int*>(t1f8 + (size_t)s * 128 + l * 4);
            f32x2 lo = fp8pair_to_f32<false>(p);
            f32x2 hi = fp8pair_to_f32<true>(p);
            a0 += lo[0]; a1 += lo[1]; a2 += hi[0]; a3 += hi[1];
        }
    }
    float inv = inv_deg[node];
    uint2 q = *reinterpret_cast<const uint2*>(hs + (size_t)node * 128 + l * 4);
    float h0 = fmaxf(bf_lo(q.x) + a0 * inv, 0.f);
    float h1 = fmaxf(bf_hi(q.x) + a1 * inv, 0.f);
    float h2 = fmaxf(bf_lo(q.y) + a2 * inv, 0.f);
    float h3 = fmaxf(bf_hi(q.y) + a3 * inv, 0.f);
    uint2 o;
    o.x = (unsigned int)f2bf(h0) | ((unsigned int)f2bf(h1) << 16);
    o.y = (unsigned int)f2bf(h2) | ((unsigned int)f2bf(h3) << 16);
    *reinterpret_cast<uint2*>(hb + (size_t)node * 128 + l * 4) = o;
}

// layer 2: quarter-wave per node, t2 bf16 [N][64] (1 line/gather). out += mean.
__global__ __launch_bounds__(256) void k_agg2(
    const unsigned short* __restrict__ t2, float* __restrict__ out,
    const int* __restrict__ row_off, const int* __restrict__ cnt,
    const float* __restrict__ inv_deg, const int* __restrict__ ssorted, int n) {
    int node = (blockIdx.x * 256 + threadIdx.x) >> 4;
    int l = threadIdx.x & 15;
    if (node >= n) return;
    int beg = row_off[node], d = cnt[node];
    float a0 = 0.f, a1 = 0.f, a2 = 0.f, a3 = 0.f;
    for (int base = 0; base < d; base += 16) {
        int m = d - base; if (m > 16) m = 16;
        int sv = (l < m) ? ssorted[beg + base + l] : 0;
        int j = 0;
        for (; j + 8 <= m; j += 8) {
            uint2 p[8];
#pragma unroll
            for (int q = 0; q < 8; ++q) {
                int s = __shfl(sv, j + q, 16);
                p[q] = *reinterpret_cast<const uint2*>(t2 + (size_t)s * 64 + l * 4);
            }
#pragma unroll
            for (int q = 0; q < 8; ++q) {
                a0 += bf_lo(p[q].x); a1 += bf_hi(p[q].x);
                a2 += bf_lo(p[q].y); a3 += bf_hi(p[q].y);
            }
        }
        for (; j < m; ++j) {
            int s = __shfl(sv, j, 16);
            uint2 p = *reinterpret_cast<const uint2*>(t2 + (size_t)s * 64 + l * 4);
            a0 += bf_lo(p.x); a1 += bf_hi(p.x);
            a2 += bf_lo(p.y); a3 += bf_hi(p.y);
        }
    }
    float inv = inv_deg[node];
    float4* po = reinterpret_cast<float4*>(out + (size_t)node * 64 + l * 4);
    float4 v = *po;
    v.x += a0 * inv; v.y += a1 * inv; v.z += a2 * inv; v.w += a3 * inv;
    *po = v;
}

// ---------------- launch ----------------

extern "C" void kernel_launch(void* const* d_in, const int* in_sizes, int n_in,
                              void* d_out, int out_size, void* d_ws, size_t ws_size,
                              hipStream_t stream) {
    const float* x        = (const float*)d_in[0];
    const int*   src      = (const int*)d_in[1];
    const int*   dst      = (const int*)d_in[2];
    const float* W_self1  = (const float*)d_in[3];
    const float* W_neigh1 = (const float*)d_in[4];
    const float* b1       = (const float*)d_in[5];
    const float* W_self2  = (const float*)d_in[6];
    const float* W_neigh2 = (const float*)d_in[7];
    const float* b2       = (const float*)d_in[8];
    float* out = (float*)d_out;

    const int N = in_sizes[0] / 128;
    const int E = in_sizes[1];
    const int NB = (N + 127) >> BKT_SHIFT;     // 782 buckets

    char* ws = (char*)d_ws;
    size_t off = 0;
    auto carve = [&](size_t bytes) {
        char* p = ws + off;
        off = (off + bytes + 255) & ~(size_t)255;
        return p;
    };
    int*   Hist    = (int*)carve((size_t)GHIST * NB * 4);   // -> Off (in-place)
    int*   Tot     = (int*)carve((size_t)NB * 4);
    int*   Base    = (int*)carve((size_t)(NB + 1) * 4);
    int*   row_off = (int*)carve((size_t)N * 4);
    int*   cnt     = (int*)carve((size_t)N * 4);
    float* inv_deg = (float*)carve((size_t)N * 4);
    int*   ssorted = (int*)carve((size_t)E * 4);
    unsigned short* Bt1  = (unsigned short*)carve(256 * 128 * 2);
    unsigned short* Bt2  = (unsigned short*)carve(128 * 128 * 2);
    unsigned char*  t1f8 = (unsigned char*)carve((size_t)N * 128);      // fp8 t1
    unsigned short* hs   = (unsigned short*)carve((size_t)N * 128 * 2); // self L1
    unsigned short* hb   = (unsigned short*)carve((size_t)N * 128 * 2); // relu'd h
    unsigned short* t2   = hs;                      // alias: hs dead after agg1
    unsigned int* packed = (unsigned int*)hb;       // alias: dead before agg1 writes hb

    const int chunk = (E + GHIST - 1) / GHIST;

    // CSR build (radix 3-phase, no global atomics)
    k_hist2<<<GHIST, 256, 0, stream>>>(dst, E, chunk, Hist, NB);
    k_scanb<<<(NB + 3) / 4, 256, 0, stream>>>(Hist, Tot, NB);
    k_scant<<<1, 1024, 0, stream>>>(Tot, Base, NB, E);
    k_scatter2<<<GHIST, 256, 0, stream>>>(src, dst, E, chunk, Hist, Base, packed, NB);
    k_bsort<<<NB, 256, 0, stream>>>(packed, Base, ssorted, row_off, cnt, inv_deg, N);

    // weights -> bf16 transposed
    k_prep<<<192, 256, 0, stream>>>(W_neigh1, W_self1, W_neigh2, W_self2, Bt1, Bt2);

    // layer 1: t1f8 = fp8(x@Wn1), hs = bf16(x@Ws1 + b1)
    k_gemm1<<<(N + 63) / 64, 256, 0, stream>>>(x, N, Bt1, b1, t1f8, hs);
    // h = relu(hs + mean_agg(t1)) -> hb (bf16)
    k_agg1<<<(N * 32 + 255) / 256, 256, 0, stream>>>(
        t1f8, hs, hb, row_off, cnt, inv_deg, ssorted, N);

    // layer 2: t2 = bf16(h@Wn2), out = h@Ws2 + b2 (f32)
    k_gemm2<<<(N + 127) / 128, 256, 0, stream>>>(hb, N, Bt2, b2, t2, out);
    // out += mean_agg(t2)
    k_agg2<<<(N * 16 + 255) / 256, 256, 0, stream>>>(
        t2, out, row_off, cnt, inv_deg, ssorted, N);
}

// Round 9
// 183.753 us; speedup vs baseline: 3.3101x; 1.1044x over previous
//
#include <hip/hip_runtime.h>
#include <hip/hip_bf16.h>

// GraphSAGE 2-layer, mean aggregator.
//   L1: h  = relu(x @ Wself1 + mean_agg(x) @ Wneigh1 + b1)
//   L2: out = h @ Wself2 + mean_agg(h) @ Wneigh2 + b2
// Transform-first aggregation. bf16 MFMA GEMMs (fp32 accum), LDS-staged
// coalesced epilogues. CSR by dst via radix 3-phase sort (no global atomics).
// R9: (a) gemm1 A-tile staged through LDS with coalesced f32 loads (R8 showed
// per-lane scattered A-loads -> latency-bound 55us, MfmaUtil 4%);
// (b) t2 stored fp8 e4m3 -> layer-2 gather row = 64B = one cache line.

typedef __attribute__((ext_vector_type(8))) short short8;
typedef __attribute__((ext_vector_type(4))) float f32x4;
typedef __attribute__((ext_vector_type(2))) float f32x2;

#define BKT_SHIFT 7                 // 128 nodes per bucket
#define SBUF_CAP 4096               // max staged edges per bucket (avg ~2046)
#define GHIST 512                   // hist/scatter blocks

__device__ __forceinline__ unsigned short f2bf(float f) {
    unsigned int u = __builtin_bit_cast(unsigned int, f);
    u += 0x7fffu + ((u >> 16) & 1u);   // RNE
    return (unsigned short)(u >> 16);
}
__device__ __forceinline__ float bf_lo(unsigned int p) {
    return __builtin_bit_cast(float, p << 16);
}
__device__ __forceinline__ float bf_hi(unsigned int p) {
    return __builtin_bit_cast(float, p & 0xffff0000u);
}

// ---- fp8 e4m3 helpers (HW cvt on gfx950; bit-trick fallback) ----
template <bool WORD>
__device__ __forceinline__ f32x2 fp8pair_to_f32(unsigned int v) {
#if __has_builtin(__builtin_amdgcn_cvt_pk_f32_fp8)
    return __builtin_amdgcn_cvt_pk_f32_fp8(v, WORD);
#else
    unsigned int b = WORD ? (v >> 16) : v;
    f32x2 r;
#pragma unroll
    for (int i = 0; i < 2; ++i) {
        unsigned int byte = (b >> (8 * i)) & 0xffu;
        float f = __builtin_bit_cast(float, (byte & 0x7fu) << 20) * 0x1p+120f;
        r[i] = (byte & 0x80u) ? -f : f;
    }
    return r;
#endif
}
__device__ __forceinline__ unsigned int enc_fp8(float v) {
    float c = fminf(fmaxf(v, -448.f), 448.f);
    unsigned int s = (__builtin_bit_cast(unsigned int, c) >> 24) & 0x80u;
    unsigned int bits = __builtin_bit_cast(unsigned int, fabsf(c) * 0x1p-120f);
    bits += 0x7FFFFu + ((bits >> 20) & 1u);
    unsigned int mag = bits >> 20;
    if (mag > 0x7Eu) mag = 0x7Eu;
    return s | mag;
}
__device__ __forceinline__ unsigned int f32x4_to_fp8x4(float a0, float a1,
                                                       float a2, float a3) {
#if __has_builtin(__builtin_amdgcn_cvt_pk_fp8_f32)
    int p = __builtin_amdgcn_cvt_pk_fp8_f32(a0, a1, 0, false);
    p = __builtin_amdgcn_cvt_pk_fp8_f32(a2, a3, p, true);
    return (unsigned int)p;
#else
    return enc_fp8(a0) | (enc_fp8(a1) << 8) | (enc_fp8(a2) << 16) | (enc_fp8(a3) << 24);
#endif
}

// ---------------- CSR build: radix 3-phase, no global atomics ----------------

__global__ __launch_bounds__(256) void k_hist2(
    const int* __restrict__ dst, int E, int chunk,
    int* __restrict__ Hist, int nb) {
    __shared__ int h[1024];
    for (int i = threadIdx.x; i < nb; i += 256) h[i] = 0;
    __syncthreads();
    int beg = blockIdx.x * chunk;
    int end = min(beg + chunk, E);
    for (int i = beg + threadIdx.x; i < end; i += 256)
        atomicAdd(&h[dst[i] >> BKT_SHIFT], 1);
    __syncthreads();
    int* o = Hist + (size_t)blockIdx.x * nb;
    for (int i = threadIdx.x; i < nb; i += 256) o[i] = h[i];
}

__global__ __launch_bounds__(256) void k_scanb(
    int* __restrict__ Hist, int* __restrict__ Tot, int nb) {
    int wave = (blockIdx.x * 256 + threadIdx.x) >> 6;
    int lane = threadIdx.x & 63;
    if (wave >= nb) return;
    const int b = wave;
    constexpr int PER = GHIST / 64;   // 8
    int v[PER];
    int s = 0;
    int blk0 = lane * PER;
#pragma unroll
    for (int j = 0; j < PER; ++j) {
        v[j] = Hist[(size_t)(blk0 + j) * nb + b];
        s += v[j];
    }
    int incl = s;
#pragma unroll
    for (int o = 1; o < 64; o <<= 1) {
        int t = __shfl_up(incl, o);
        if (lane >= o) incl += t;
    }
    int run = incl - s;   // exclusive
#pragma unroll
    for (int j = 0; j < PER; ++j) {
        int t = v[j];
        Hist[(size_t)(blk0 + j) * nb + b] = run;
        run += t;
    }
    if (lane == 63) Tot[b] = incl;
}

__global__ __launch_bounds__(1024) void k_scant(
    const int* __restrict__ Tot, int* __restrict__ Base, int nb, int E) {
    __shared__ int s[1024];
    int t = threadIdx.x;
    int v = (t < nb) ? Tot[t] : 0;
    s[t] = v;
    __syncthreads();
    for (int o = 1; o < 1024; o <<= 1) {
        int x = (t >= o) ? s[t - o] : 0;
        __syncthreads();
        s[t] += x;
        __syncthreads();
    }
    if (t < nb) Base[t] = s[t] - v;  // exclusive
    if (t == 0) Base[nb] = E;
}

__global__ __launch_bounds__(256) void k_scatter2(
    const int* __restrict__ src, const int* __restrict__ dst, int E, int chunk,
    const int* __restrict__ Off, const int* __restrict__ Base,
    unsigned int* __restrict__ packed, int nb) {
    __shared__ int cb[1024];
    __shared__ int h[1024];
    const int blk = blockIdx.x;
    for (int i = threadIdx.x; i < nb; i += 256) {
        cb[i] = Base[i] + Off[(size_t)blk * nb + i];
        h[i] = 0;
    }
    __syncthreads();
    int beg = blk * chunk;
    int end = min(beg + chunk, E);
    for (int i = beg + threadIdx.x; i < end; i += 256) {
        int d = dst[i];
        int b = d >> BKT_SHIFT;
        int loc = atomicAdd(&h[b], 1);
        packed[cb[b] + loc] = ((unsigned int)(d & 127) << 17) | (unsigned int)src[i];
    }
}

__global__ __launch_bounds__(256) void k_bsort(
    const unsigned int* __restrict__ packed, const int* __restrict__ base,
    int* __restrict__ ssorted, int* __restrict__ row_off, int* __restrict__ cnt,
    float* __restrict__ inv_deg, int n) {
    __shared__ int h128[128];
    __shared__ int ex[128];
    __shared__ int sbuf[SBUF_CAP];
    int t = threadIdx.x;
    int b = blockIdx.x;
    int beg = base[b], end = base[b + 1];
    int m = end - beg;
    if (t < 128) h128[t] = 0;
    __syncthreads();
    for (int i = t; i < m; i += 256)
        atomicAdd(&h128[packed[beg + i] >> 17], 1);
    __syncthreads();
    if (t < 128) ex[t] = h128[t];
    __syncthreads();
    for (int o = 1; o < 128; o <<= 1) {
        int v = (t < 128 && t >= o) ? ex[t - o] : 0;
        __syncthreads();
        if (t < 128) ex[t] += v;
        __syncthreads();
    }
    if (t < 128) {
        int deg = h128[t];
        ex[t] -= deg;  // exclusive
        int node = (b << BKT_SHIFT) + t;
        if (node < n) {
            row_off[node] = beg + ex[t];
            cnt[node] = deg;
            inv_deg[node] = 1.0f / fmaxf((float)deg, 1.0f);
        }
    }
    __syncthreads();
    if (t < 128) h128[t] = 0;  // reuse as cursor
    __syncthreads();
    if (m <= SBUF_CAP) {
        for (int i = t; i < m; i += 256) {
            unsigned int p = packed[beg + i];
            int dl = p >> 17;
            int loc = atomicAdd(&h128[dl], 1);
            sbuf[ex[dl] + loc] = (int)(p & 0x1FFFFu);
        }
        __syncthreads();
        for (int i = t; i < m; i += 256) ssorted[beg + i] = sbuf[i];
    } else {
        for (int i = t; i < m; i += 256) {
            unsigned int p = packed[beg + i];
            int dl = p >> 17;
            int loc = atomicAdd(&h128[dl], 1);
            ssorted[beg + ex[dl] + loc] = (int)(p & 0x1FFFFu);
        }
    }
}

// ---------------- weight prep: transpose + bf16 ----------------
__global__ void k_prep(const float* __restrict__ Wn1, const float* __restrict__ Ws1,
                       const float* __restrict__ Wn2, const float* __restrict__ Ws2,
                       unsigned short* __restrict__ Bt1, unsigned short* __restrict__ Bt2) {
    int i = blockIdx.x * 256 + threadIdx.x;
    if (i < 256 * 128) {
        int c = i >> 7, k = i & 127;
        float v = (c < 128) ? Wn1[k * 128 + c] : Ws1[k * 128 + (c - 128)];
        Bt1[i] = f2bf(v);
    } else {
        int j = i - 256 * 128;
        if (j < 128 * 128) {
            int c = j >> 7, k = j & 127;
            float v = (c < 64) ? Wn2[k * 64 + c] : Ws2[k * 64 + (c - 64)];
            Bt2[j] = f2bf(v);
        }
    }
}

// ---------------- layer-1 GEMM: x(f32) @ [Wn1|Ws1] -> t1 fp8, hs bf16 ----------------
// A-tile (64x128 f32) staged via coalesced loads -> LDS bf16 [64][136].
// Block = 4 waves; wave w owns cols [w*64, w*64+64) of the 256 combined cols.
// cols 0-127 -> t1 (fp8), 128-255 -> hs (+bias, bf16).
__global__ __launch_bounds__(256, 3) void k_gemm1(
    const float* __restrict__ Af, int nrows,
    const unsigned short* __restrict__ Bt, const float* __restrict__ bias,
    unsigned char* __restrict__ O8, unsigned short* __restrict__ Ob) {
    constexpr int BR = 64;
    __shared__ unsigned short sA[BR][136];                              // bf16 A tile
    __shared__ unsigned short sb[BR][136];                              // hs stage
    __shared__ __attribute__((aligned(16))) unsigned char s8[BR][144];  // t1 stage

    const int tid = threadIdx.x;
    const int w = tid >> 6, lane = tid & 63;
    const int l15 = lane & 15, lg = lane >> 4;
    const int col0 = w * 64;
    const int row0 = blockIdx.x * BR;

    // coalesced A staging: 2048 float4; 32 lanes cover one 512B row
#pragma unroll
    for (int i = 0; i < 8; ++i) {
        int q = tid + 256 * i;
        int row = q >> 5, c4 = q & 31;
        float4 a = make_float4(0.f, 0.f, 0.f, 0.f);
        if (row0 + row < nrows)
            a = *reinterpret_cast<const float4*>(Af + (size_t)(row0 + row) * 128 + c4 * 4);
        uint2 pk;
        pk.x = (unsigned int)f2bf(a.x) | ((unsigned int)f2bf(a.y) << 16);
        pk.y = (unsigned int)f2bf(a.z) | ((unsigned int)f2bf(a.w) << 16);
        *reinterpret_cast<uint2*>(&sA[row][c4 * 4]) = pk;
    }
    __syncthreads();

    f32x4 acc[4][4];
#pragma unroll
    for (int rt = 0; rt < 4; ++rt)
#pragma unroll
        for (int ct = 0; ct < 4; ++ct) acc[rt][ct] = (f32x4)0.f;

#pragma unroll
    for (int ks = 0; ks < 4; ++ks) {
        short8 bf[4];
#pragma unroll
        for (int ct = 0; ct < 4; ++ct)
            bf[ct] = *reinterpret_cast<const short8*>(
                Bt + (size_t)(col0 + ct * 16 + l15) * 128 + ks * 32 + lg * 8);
        short8 af[4];
#pragma unroll
        for (int rt = 0; rt < 4; ++rt)
            af[rt] = *reinterpret_cast<const short8*>(&sA[rt * 16 + l15][ks * 32 + lg * 8]);
#pragma unroll
        for (int rt = 0; rt < 4; ++rt)
#pragma unroll
            for (int ct = 0; ct < 4; ++ct)
                acc[rt][ct] = __builtin_amdgcn_mfma_f32_16x16x32_bf16(
                    bf[ct], af[rt], acc[rt][ct], 0, 0, 0);
    }

    // stage: lane holds row = rt*16+l15, cols = col0+ct*16+lg*4..+3
#pragma unroll
    for (int rt = 0; rt < 4; ++rt) {
#pragma unroll
        for (int ct = 0; ct < 4; ++ct) {
            int rowL = rt * 16 + l15;
            int colL = col0 + ct * 16 + lg * 4;
            f32x4 a = acc[rt][ct];
            if (colL < 128) {
                *reinterpret_cast<unsigned int*>(&s8[rowL][colL]) =
                    f32x4_to_fp8x4(a[0], a[1], a[2], a[3]);
            } else {
                int cc = colL - 128;
                float4 bv = *reinterpret_cast<const float4*>(bias + cc);
                unsigned int lo = (unsigned int)f2bf(a[0] + bv.x) |
                                  ((unsigned int)f2bf(a[1] + bv.y) << 16);
                unsigned int hi = (unsigned int)f2bf(a[2] + bv.z) |
                                  ((unsigned int)f2bf(a[3] + bv.w) << 16);
                *reinterpret_cast<uint2*>(&sb[rowL][cc]) = make_uint2(lo, hi);
            }
        }
    }
    __syncthreads();

    // coalesced copy-out: t1 fp8 (128B/row), hs bf16 (256B/row)
#pragma unroll
    for (int it = 0; it < 2; ++it) {
        int c = tid + 256 * it;
        int row = c >> 3, off = c & 7;
        if (row0 + row < nrows) {
            uint4 v = *reinterpret_cast<const uint4*>(&s8[row][off * 16]);
            *reinterpret_cast<uint4*>(O8 + (size_t)(row0 + row) * 128 + off * 16) = v;
        }
    }
#pragma unroll
    for (int it = 0; it < 4; ++it) {
        int c = tid + 256 * it;
        int row = c >> 4, off = c & 15;
        if (row0 + row < nrows) {
            uint4 v = *reinterpret_cast<const uint4*>(
                reinterpret_cast<const char*>(&sb[row][0]) + off * 16);
            *reinterpret_cast<uint4*>(
                reinterpret_cast<char*>(Ob) + (size_t)(row0 + row) * 256 + off * 16) = v;
        }
    }
}

// ---------------- layer-2 GEMM: h(bf16) @ [Wn2|Ws2] -> t2 fp8, out f32 ----------------
__global__ __launch_bounds__(256, 3) void k_gemm2(
    const unsigned short* __restrict__ Ab, int nrows,
    const unsigned short* __restrict__ Bt, const float* __restrict__ bias,
    unsigned char* __restrict__ O8, float* __restrict__ O2f) {
    constexpr int MO = 64, BR = 128;
    __shared__ __attribute__((aligned(16))) unsigned char s8[BR][80];  // t2 fp8 stage
    __shared__ float sf[BR][68];

    const int tid = threadIdx.x;
    const int w = tid >> 6, lane = tid & 63;
    const int l15 = lane & 15, lg = lane >> 4;
    const int wr = w >> 1, wc = w & 1;
    const int row0w = blockIdx.x * BR + wr * 64;
    const int col0 = wc * 64;

    f32x4 acc[4][4];
#pragma unroll
    for (int rt = 0; rt < 4; ++rt)
#pragma unroll
        for (int ct = 0; ct < 4; ++ct) acc[rt][ct] = (f32x4)0.f;

#pragma unroll
    for (int ks = 0; ks < 4; ++ks) {
        short8 bf[4];
#pragma unroll
        for (int ct = 0; ct < 4; ++ct)
            bf[ct] = *reinterpret_cast<const short8*>(
                Bt + (size_t)(col0 + ct * 16 + l15) * 128 + ks * 32 + lg * 8);
        short8 af[4];
#pragma unroll
        for (int rt = 0; rt < 4; ++rt) {
            int row = row0w + rt * 16 + l15;
            int rc = row < nrows ? row : nrows - 1;
            af[rt] = *reinterpret_cast<const short8*>(
                Ab + (size_t)rc * 128 + ks * 32 + lg * 8);
        }
#pragma unroll
        for (int rt = 0; rt < 4; ++rt)
#pragma unroll
            for (int ct = 0; ct < 4; ++ct)
                acc[rt][ct] = __builtin_amdgcn_mfma_f32_16x16x32_bf16(
                    bf[ct], af[rt], acc[rt][ct], 0, 0, 0);
    }

#pragma unroll
    for (int rt = 0; rt < 4; ++rt) {
#pragma unroll
        for (int ct = 0; ct < 4; ++ct) {
            int rowL = wr * 64 + rt * 16 + l15;
            int colL = col0 + ct * 16 + lg * 4;
            f32x4 a = acc[rt][ct];
            if (colL < MO) {
                *reinterpret_cast<unsigned int*>(&s8[rowL][colL]) =
                    f32x4_to_fp8x4(a[0], a[1], a[2], a[3]);
            } else {
                int cc = colL - MO;
                float4 bv = *reinterpret_cast<const float4*>(bias + cc);
                a[0] += bv.x; a[1] += bv.y; a[2] += bv.z; a[3] += bv.w;
                *reinterpret_cast<f32x4*>(&sf[rowL][cc]) = a;
            }
        }
    }
    __syncthreads();

    const int row0 = blockIdx.x * BR;
#pragma unroll
    for (int it = 0; it < 2; ++it) {           // t2 fp8: 4 chunks(16B)/row
        int c = tid + 256 * it;
        int row = c >> 2, off = c & 3;
        if (row0 + row < nrows) {
            uint4 v = *reinterpret_cast<const uint4*>(&s8[row][off * 16]);
            *reinterpret_cast<uint4*>(O8 + (size_t)(row0 + row) * 64 + off * 16) = v;
        }
    }
#pragma unroll
    for (int it = 0; it < 8; ++it) {           // out f32: 16 chunks/row
        int c = tid + 256 * it;
        int row = c >> 4, off = c & 15;
        if (row0 + row < nrows) {
            f32x4 v = *reinterpret_cast<const f32x4*>(&sf[row][off * 4]);
            *reinterpret_cast<f32x4*>(O2f + (size_t)(row0 + row) * MO + off * 4) = v;
        }
    }
}

// ---------------- aggregation ----------------
// layer 1: half-wave per node; t1 fp8 [N][128] (1 line/gather), hs bf16 [N][128].
__global__ __launch_bounds__(256) void k_agg1(
    const unsigned char* __restrict__ t1f8, const unsigned short* __restrict__ hs,
    unsigned short* __restrict__ hb,
    const int* __restrict__ row_off, const int* __restrict__ cnt,
    const float* __restrict__ inv_deg, const int* __restrict__ ssorted, int n) {
    int node = (blockIdx.x * 256 + threadIdx.x) >> 5;
    int l = threadIdx.x & 31;
    if (node >= n) return;
    int beg = row_off[node], d = cnt[node];
    float a0 = 0.f, a1 = 0.f, a2 = 0.f, a3 = 0.f;
    for (int base = 0; base < d; base += 32) {
        int m = d - base; if (m > 32) m = 32;
        int sv = (l < m) ? ssorted[beg + base + l] : 0;
        int j = 0;
        for (; j + 8 <= m; j += 8) {
            unsigned int p[8];
#pragma unroll
            for (int q = 0; q < 8; ++q) {
                int s = __shfl(sv, j + q, 32);
                p[q] = *reinterpret_cast<const unsigned int*>(t1f8 + (size_t)s * 128 + l * 4);
            }
#pragma unroll
            for (int q = 0; q < 8; ++q) {
                f32x2 lo = fp8pair_to_f32<false>(p[q]);
                f32x2 hi = fp8pair_to_f32<true>(p[q]);
                a0 += lo[0]; a1 += lo[1]; a2 += hi[0]; a3 += hi[1];
            }
        }
        for (; j < m; ++j) {
            int s = __shfl(sv, j, 32);
            unsigned int p = *reinterpret_cast<const unsigned int*>(t1f8 + (size_t)s * 128 + l * 4);
            f32x2 lo = fp8pair_to_f32<false>(p);
            f32x2 hi = fp8pair_to_f32<true>(p);
            a0 += lo[0]; a1 += lo[1]; a2 += hi[0]; a3 += hi[1];
        }
    }
    float inv = inv_deg[node];
    uint2 q = *reinterpret_cast<const uint2*>(hs + (size_t)node * 128 + l * 4);
    float h0 = fmaxf(bf_lo(q.x) + a0 * inv, 0.f);
    float h1 = fmaxf(bf_hi(q.x) + a1 * inv, 0.f);
    float h2 = fmaxf(bf_lo(q.y) + a2 * inv, 0.f);
    float h3 = fmaxf(bf_hi(q.y) + a3 * inv, 0.f);
    uint2 o;
    o.x = (unsigned int)f2bf(h0) | ((unsigned int)f2bf(h1) << 16);
    o.y = (unsigned int)f2bf(h2) | ((unsigned int)f2bf(h3) << 16);
    *reinterpret_cast<uint2*>(hb + (size_t)node * 128 + l * 4) = o;
}

// layer 2: quarter-wave per node; t2 fp8 [N][64] (1 line/gather). out += mean.
__global__ __launch_bounds__(256) void k_agg2(
    const unsigned char* __restrict__ t2f8, float* __restrict__ out,
    const int* __restrict__ row_off, const int* __restrict__ cnt,
    const float* __restrict__ inv_deg, const int* __restrict__ ssorted, int n) {
    int node = (blockIdx.x * 256 + threadIdx.x) >> 4;
    int l = threadIdx.x & 15;
    if (node >= n) return;
    int beg = row_off[node], d = cnt[node];
    float a0 = 0.f, a1 = 0.f, a2 = 0.f, a3 = 0.f;
    for (int base = 0; base < d; base += 16) {
        int m = d - base; if (m > 16) m = 16;
        int sv = (l < m) ? ssorted[beg + base + l] : 0;
        int j = 0;
        for (; j + 8 <= m; j += 8) {
            unsigned int p[8];
#pragma unroll
            for (int q = 0; q < 8; ++q) {
                int s = __shfl(sv, j + q, 16);
                p[q] = *reinterpret_cast<const unsigned int*>(t2f8 + (size_t)s * 64 + l * 4);
            }
#pragma unroll
            for (int q = 0; q < 8; ++q) {
                f32x2 lo = fp8pair_to_f32<false>(p[q]);
                f32x2 hi = fp8pair_to_f32<true>(p[q]);
                a0 += lo[0]; a1 += lo[1]; a2 += hi[0]; a3 += hi[1];
            }
        }
        for (; j < m; ++j) {
            int s = __shfl(sv, j, 16);
            unsigned int p = *reinterpret_cast<const unsigned int*>(t2f8 + (size_t)s * 64 + l * 4);
            f32x2 lo = fp8pair_to_f32<false>(p);
            f32x2 hi = fp8pair_to_f32<true>(p);
            a0 += lo[0]; a1 += lo[1]; a2 += hi[0]; a3 += hi[1];
        }
    }
    float inv = inv_deg[node];
    float4* po = reinterpret_cast<float4*>(out + (size_t)node * 64 + l * 4);
    float4 v = *po;
    v.x += a0 * inv; v.y += a1 * inv; v.z += a2 * inv; v.w += a3 * inv;
    *po = v;
}

// ---------------- launch ----------------

extern "C" void kernel_launch(void* const* d_in, const int* in_sizes, int n_in,
                              void* d_out, int out_size, void* d_ws, size_t ws_size,
                              hipStream_t stream) {
    const float* x        = (const float*)d_in[0];
    const int*   src      = (const int*)d_in[1];
    const int*   dst      = (const int*)d_in[2];
    const float* W_self1  = (const float*)d_in[3];
    const float* W_neigh1 = (const float*)d_in[4];
    const float* b1       = (const float*)d_in[5];
    const float* W_self2  = (const float*)d_in[6];
    const float* W_neigh2 = (const float*)d_in[7];
    const float* b2       = (const float*)d_in[8];
    float* out = (float*)d_out;

    const int N = in_sizes[0] / 128;
    const int E = in_sizes[1];
    const int NB = (N + 127) >> BKT_SHIFT;     // 782 buckets

    char* ws = (char*)d_ws;
    size_t off = 0;
    auto carve = [&](size_t bytes) {
        char* p = ws + off;
        off = (off + bytes + 255) & ~(size_t)255;
        return p;
    };
    int*   Hist    = (int*)carve((size_t)GHIST * NB * 4);   // -> Off (in-place)
    int*   Tot     = (int*)carve((size_t)NB * 4);
    int*   Base    = (int*)carve((size_t)(NB + 1) * 4);
    int*   row_off = (int*)carve((size_t)N * 4);
    int*   cnt     = (int*)carve((size_t)N * 4);
    float* inv_deg = (float*)carve((size_t)N * 4);
    int*   ssorted = (int*)carve((size_t)E * 4);
    unsigned short* Bt1  = (unsigned short*)carve(256 * 128 * 2);
    unsigned short* Bt2  = (unsigned short*)carve(128 * 128 * 2);
    unsigned char*  t1f8 = (unsigned char*)carve((size_t)N * 128);      // fp8 t1
    unsigned short* hs   = (unsigned short*)carve((size_t)N * 128 * 2); // self L1
    unsigned short* hb   = (unsigned short*)carve((size_t)N * 128 * 2); // relu'd h
    unsigned char*  t2f8 = t1f8;                    // alias: t1f8 dead after agg1
    unsigned int* packed = (unsigned int*)hb;       // alias: dead before agg1 writes hb

    const int chunk = (E + GHIST - 1) / GHIST;

    // CSR build (radix 3-phase, no global atomics)
    k_hist2<<<GHIST, 256, 0, stream>>>(dst, E, chunk, Hist, NB);
    k_scanb<<<(NB + 3) / 4, 256, 0, stream>>>(Hist, Tot, NB);
    k_scant<<<1, 1024, 0, stream>>>(Tot, Base, NB, E);
    k_scatter2<<<GHIST, 256, 0, stream>>>(src, dst, E, chunk, Hist, Base, packed, NB);
    k_bsort<<<NB, 256, 0, stream>>>(packed, Base, ssorted, row_off, cnt, inv_deg, N);

    // weights -> bf16 transposed
    k_prep<<<192, 256, 0, stream>>>(W_neigh1, W_self1, W_neigh2, W_self2, Bt1, Bt2);

    // layer 1: t1f8 = fp8(x@Wn1), hs = bf16(x@Ws1 + b1)
    k_gemm1<<<(N + 63) / 64, 256, 0, stream>>>(x, N, Bt1, b1, t1f8, hs);
    // h = relu(hs + mean_agg(t1)) -> hb (bf16)
    k_agg1<<<(N * 32 + 255) / 256, 256, 0, stream>>>(
        t1f8, hs, hb, row_off, cnt, inv_deg, ssorted, N);

    // layer 2: t2f8 = fp8(h@Wn2), out = h@Ws2 + b2 (f32)
    k_gemm2<<<(N + 127) / 128, 256, 0, stream>>>(hb, N, Bt2, b2, t2f8, out);
    // out += mean_agg(t2)
    k_agg2<<<(N * 16 + 255) / 256, 256, 0, stream>>>(
        t2f8, out, row_off, cnt, inv_deg, ssorted, N);
}

// Round 10
// 178.020 us; speedup vs baseline: 3.4167x; 1.0322x over previous
//
#include <hip/hip_runtime.h>
#include <hip/hip_bf16.h>

// GraphSAGE 2-layer, mean aggregator.
//   L1: h  = relu(x @ Wself1 + mean_agg(x) @ Wneigh1 + b1)
//   L2: out = h @ Wself2 + mean_agg(h) @ Wneigh2 + b2
// Transform-first aggregation. bf16 MFMA GEMMs (fp32 accum). CSR by dst via
// radix 3-phase sort (no global atomics). t1/t2 stored fp8 e4m3 (1-line
// gathers). R10: gemm occupancy fix - gemm1 unions A-stage LDS with the
// epilogue stages (44->26.6 KB), gemm2 stores f32 out directly (line-complete
// per instruction; LDS 45->10.2 KB); both launch_bounds(256,4). R9 showed
// both GEMMs latency-bound at ~2 blocks/CU with MfmaUtil 5%.

typedef __attribute__((ext_vector_type(8))) short short8;
typedef __attribute__((ext_vector_type(4))) float f32x4;
typedef __attribute__((ext_vector_type(2))) float f32x2;

#define BKT_SHIFT 7                 // 128 nodes per bucket
#define SBUF_CAP 4096               // max staged edges per bucket (avg ~2046)
#define GHIST 512                   // hist/scatter blocks

__device__ __forceinline__ unsigned short f2bf(float f) {
    unsigned int u = __builtin_bit_cast(unsigned int, f);
    u += 0x7fffu + ((u >> 16) & 1u);   // RNE
    return (unsigned short)(u >> 16);
}
__device__ __forceinline__ float bf_lo(unsigned int p) {
    return __builtin_bit_cast(float, p << 16);
}
__device__ __forceinline__ float bf_hi(unsigned int p) {
    return __builtin_bit_cast(float, p & 0xffff0000u);
}

// ---- fp8 e4m3 helpers (HW cvt on gfx950; bit-trick fallback) ----
template <bool WORD>
__device__ __forceinline__ f32x2 fp8pair_to_f32(unsigned int v) {
#if __has_builtin(__builtin_amdgcn_cvt_pk_f32_fp8)
    return __builtin_amdgcn_cvt_pk_f32_fp8(v, WORD);
#else
    unsigned int b = WORD ? (v >> 16) : v;
    f32x2 r;
#pragma unroll
    for (int i = 0; i < 2; ++i) {
        unsigned int byte = (b >> (8 * i)) & 0xffu;
        float f = __builtin_bit_cast(float, (byte & 0x7fu) << 20) * 0x1p+120f;
        r[i] = (byte & 0x80u) ? -f : f;
    }
    return r;
#endif
}
__device__ __forceinline__ unsigned int enc_fp8(float v) {
    float c = fminf(fmaxf(v, -448.f), 448.f);
    unsigned int s = (__builtin_bit_cast(unsigned int, c) >> 24) & 0x80u;
    unsigned int bits = __builtin_bit_cast(unsigned int, fabsf(c) * 0x1p-120f);
    bits += 0x7FFFFu + ((bits >> 20) & 1u);
    unsigned int mag = bits >> 20;
    if (mag > 0x7Eu) mag = 0x7Eu;
    return s | mag;
}
__device__ __forceinline__ unsigned int f32x4_to_fp8x4(float a0, float a1,
                                                       float a2, float a3) {
#if __has_builtin(__builtin_amdgcn_cvt_pk_fp8_f32)
    int p = __builtin_amdgcn_cvt_pk_fp8_f32(a0, a1, 0, false);
    p = __builtin_amdgcn_cvt_pk_fp8_f32(a2, a3, p, true);
    return (unsigned int)p;
#else
    return enc_fp8(a0) | (enc_fp8(a1) << 8) | (enc_fp8(a2) << 16) | (enc_fp8(a3) << 24);
#endif
}

// ---------------- CSR build: radix 3-phase, no global atomics ----------------

__global__ __launch_bounds__(256) void k_hist2(
    const int* __restrict__ dst, int E, int chunk,
    int* __restrict__ Hist, int nb) {
    __shared__ int h[1024];
    for (int i = threadIdx.x; i < nb; i += 256) h[i] = 0;
    __syncthreads();
    int beg = blockIdx.x * chunk;
    int end = min(beg + chunk, E);
    for (int i = beg + threadIdx.x; i < end; i += 256)
        atomicAdd(&h[dst[i] >> BKT_SHIFT], 1);
    __syncthreads();
    int* o = Hist + (size_t)blockIdx.x * nb;
    for (int i = threadIdx.x; i < nb; i += 256) o[i] = h[i];
}

__global__ __launch_bounds__(256) void k_scanb(
    int* __restrict__ Hist, int* __restrict__ Tot, int nb) {
    int wave = (blockIdx.x * 256 + threadIdx.x) >> 6;
    int lane = threadIdx.x & 63;
    if (wave >= nb) return;
    const int b = wave;
    constexpr int PER = GHIST / 64;   // 8
    int v[PER];
    int s = 0;
    int blk0 = lane * PER;
#pragma unroll
    for (int j = 0; j < PER; ++j) {
        v[j] = Hist[(size_t)(blk0 + j) * nb + b];
        s += v[j];
    }
    int incl = s;
#pragma unroll
    for (int o = 1; o < 64; o <<= 1) {
        int t = __shfl_up(incl, o);
        if (lane >= o) incl += t;
    }
    int run = incl - s;   // exclusive
#pragma unroll
    for (int j = 0; j < PER; ++j) {
        int t = v[j];
        Hist[(size_t)(blk0 + j) * nb + b] = run;
        run += t;
    }
    if (lane == 63) Tot[b] = incl;
}

__global__ __launch_bounds__(1024) void k_scant(
    const int* __restrict__ Tot, int* __restrict__ Base, int nb, int E) {
    __shared__ int s[1024];
    int t = threadIdx.x;
    int v = (t < nb) ? Tot[t] : 0;
    s[t] = v;
    __syncthreads();
    for (int o = 1; o < 1024; o <<= 1) {
        int x = (t >= o) ? s[t - o] : 0;
        __syncthreads();
        s[t] += x;
        __syncthreads();
    }
    if (t < nb) Base[t] = s[t] - v;  // exclusive
    if (t == 0) Base[nb] = E;
}

__global__ __launch_bounds__(256) void k_scatter2(
    const int* __restrict__ src, const int* __restrict__ dst, int E, int chunk,
    const int* __restrict__ Off, const int* __restrict__ Base,
    unsigned int* __restrict__ packed, int nb) {
    __shared__ int cb[1024];
    __shared__ int h[1024];
    const int blk = blockIdx.x;
    for (int i = threadIdx.x; i < nb; i += 256) {
        cb[i] = Base[i] + Off[(size_t)blk * nb + i];
        h[i] = 0;
    }
    __syncthreads();
    int beg = blk * chunk;
    int end = min(beg + chunk, E);
    for (int i = beg + threadIdx.x; i < end; i += 256) {
        int d = dst[i];
        int b = d >> BKT_SHIFT;
        int loc = atomicAdd(&h[b], 1);
        packed[cb[b] + loc] = ((unsigned int)(d & 127) << 17) | (unsigned int)src[i];
    }
}

__global__ __launch_bounds__(256) void k_bsort(
    const unsigned int* __restrict__ packed, const int* __restrict__ base,
    int* __restrict__ ssorted, int* __restrict__ row_off, int* __restrict__ cnt,
    float* __restrict__ inv_deg, int n) {
    __shared__ int h128[128];
    __shared__ int ex[128];
    __shared__ int sbuf[SBUF_CAP];
    int t = threadIdx.x;
    int b = blockIdx.x;
    int beg = base[b], end = base[b + 1];
    int m = end - beg;
    if (t < 128) h128[t] = 0;
    __syncthreads();
    for (int i = t; i < m; i += 256)
        atomicAdd(&h128[packed[beg + i] >> 17], 1);
    __syncthreads();
    if (t < 128) ex[t] = h128[t];
    __syncthreads();
    for (int o = 1; o < 128; o <<= 1) {
        int v = (t < 128 && t >= o) ? ex[t - o] : 0;
        __syncthreads();
        if (t < 128) ex[t] += v;
        __syncthreads();
    }
    if (t < 128) {
        int deg = h128[t];
        ex[t] -= deg;  // exclusive
        int node = (b << BKT_SHIFT) + t;
        if (node < n) {
            row_off[node] = beg + ex[t];
            cnt[node] = deg;
            inv_deg[node] = 1.0f / fmaxf((float)deg, 1.0f);
        }
    }
    __syncthreads();
    if (t < 128) h128[t] = 0;  // reuse as cursor
    __syncthreads();
    if (m <= SBUF_CAP) {
        for (int i = t; i < m; i += 256) {
            unsigned int p = packed[beg + i];
            int dl = p >> 17;
            int loc = atomicAdd(&h128[dl], 1);
            sbuf[ex[dl] + loc] = (int)(p & 0x1FFFFu);
        }
        __syncthreads();
        for (int i = t; i < m; i += 256) ssorted[beg + i] = sbuf[i];
    } else {
        for (int i = t; i < m; i += 256) {
            unsigned int p = packed[beg + i];
            int dl = p >> 17;
            int loc = atomicAdd(&h128[dl], 1);
            ssorted[beg + ex[dl] + loc] = (int)(p & 0x1FFFFu);
        }
    }
}

// ---------------- weight prep: transpose + bf16 ----------------
__global__ void k_prep(const float* __restrict__ Wn1, const float* __restrict__ Ws1,
                       const float* __restrict__ Wn2, const float* __restrict__ Ws2,
                       unsigned short* __restrict__ Bt1, unsigned short* __restrict__ Bt2) {
    int i = blockIdx.x * 256 + threadIdx.x;
    if (i < 256 * 128) {
        int c = i >> 7, k = i & 127;
        float v = (c < 128) ? Wn1[k * 128 + c] : Ws1[k * 128 + (c - 128)];
        Bt1[i] = f2bf(v);
    } else {
        int j = i - 256 * 128;
        if (j < 128 * 128) {
            int c = j >> 7, k = j & 127;
            float v = (c < 64) ? Wn2[k * 64 + c] : Ws2[k * 64 + (c - 64)];
            Bt2[j] = f2bf(v);
        }
    }
}

// ---------------- layer-1 GEMM: x(f32) @ [Wn1|Ws1] -> t1 fp8, hs bf16 ----------------
// A-tile (64x128 f32) staged coalesced -> LDS bf16. LDS UNION: the A-tile
// region is reused for the epilogue stages after the MFMAs (extra barrier) ->
// 26.6 KB total, 6 blocks/CU by LDS.
__global__ __launch_bounds__(256, 4) void k_gemm1(
    const float* __restrict__ Af, int nrows,
    const unsigned short* __restrict__ Bt, const float* __restrict__ bias,
    unsigned char* __restrict__ O8, unsigned short* __restrict__ Ob) {
    constexpr int BR = 64;
    __shared__ __attribute__((aligned(16))) unsigned char smem[26624];
    auto sA = reinterpret_cast<unsigned short(*)[136]>(smem);          // phase 1: A bf16 (17408 B)
    auto sb = reinterpret_cast<unsigned short(*)[136]>(smem);          // phase 2: hs stage (17408 B)
    auto s8 = reinterpret_cast<unsigned char(*)[144]>(smem + 17408);   // phase 2: t1 fp8 stage (9216 B)

    const int tid = threadIdx.x;
    const int w = tid >> 6, lane = tid & 63;
    const int l15 = lane & 15, lg = lane >> 4;
    const int col0 = w * 64;
    const int row0 = blockIdx.x * BR;

    // coalesced A staging: 2048 float4; 32 lanes cover one 512B row
#pragma unroll
    for (int i = 0; i < 8; ++i) {
        int q = tid + 256 * i;
        int row = q >> 5, c4 = q & 31;
        float4 a = make_float4(0.f, 0.f, 0.f, 0.f);
        if (row0 + row < nrows)
            a = *reinterpret_cast<const float4*>(Af + (size_t)(row0 + row) * 128 + c4 * 4);
        uint2 pk;
        pk.x = (unsigned int)f2bf(a.x) | ((unsigned int)f2bf(a.y) << 16);
        pk.y = (unsigned int)f2bf(a.z) | ((unsigned int)f2bf(a.w) << 16);
        *reinterpret_cast<uint2*>(&sA[row][c4 * 4]) = pk;
    }
    __syncthreads();

    f32x4 acc[4][4];
#pragma unroll
    for (int rt = 0; rt < 4; ++rt)
#pragma unroll
        for (int ct = 0; ct < 4; ++ct) acc[rt][ct] = (f32x4)0.f;

#pragma unroll
    for (int ks = 0; ks < 4; ++ks) {
        short8 bf[4];
#pragma unroll
        for (int ct = 0; ct < 4; ++ct)
            bf[ct] = *reinterpret_cast<const short8*>(
                Bt + (size_t)(col0 + ct * 16 + l15) * 128 + ks * 32 + lg * 8);
        short8 af[4];
#pragma unroll
        for (int rt = 0; rt < 4; ++rt)
            af[rt] = *reinterpret_cast<const short8*>(&sA[rt * 16 + l15][ks * 32 + lg * 8]);
#pragma unroll
        for (int rt = 0; rt < 4; ++rt)
#pragma unroll
            for (int ct = 0; ct < 4; ++ct)
                acc[rt][ct] = __builtin_amdgcn_mfma_f32_16x16x32_bf16(
                    bf[ct], af[rt], acc[rt][ct], 0, 0, 0);
    }
    __syncthreads();   // sA dead; epilogue stages reuse the same LDS

    // stage: lane holds row = rt*16+l15, cols = col0+ct*16+lg*4..+3
#pragma unroll
    for (int rt = 0; rt < 4; ++rt) {
#pragma unroll
        for (int ct = 0; ct < 4; ++ct) {
            int rowL = rt * 16 + l15;
            int colL = col0 + ct * 16 + lg * 4;
            f32x4 a = acc[rt][ct];
            if (colL < 128) {
                *reinterpret_cast<unsigned int*>(&s8[rowL][colL]) =
                    f32x4_to_fp8x4(a[0], a[1], a[2], a[3]);
            } else {
                int cc = colL - 128;
                float4 bv = *reinterpret_cast<const float4*>(bias + cc);
                unsigned int lo = (unsigned int)f2bf(a[0] + bv.x) |
                                  ((unsigned int)f2bf(a[1] + bv.y) << 16);
                unsigned int hi = (unsigned int)f2bf(a[2] + bv.z) |
                                  ((unsigned int)f2bf(a[3] + bv.w) << 16);
                *reinterpret_cast<uint2*>(&sb[rowL][cc]) = make_uint2(lo, hi);
            }
        }
    }
    __syncthreads();

    // coalesced copy-out: t1 fp8 (128B/row), hs bf16 (256B/row)
#pragma unroll
    for (int it = 0; it < 2; ++it) {
        int c = tid + 256 * it;
        int row = c >> 3, off = c & 7;
        if (row0 + row < nrows) {
            uint4 v = *reinterpret_cast<const uint4*>(&s8[row][off * 16]);
            *reinterpret_cast<uint4*>(O8 + (size_t)(row0 + row) * 128 + off * 16) = v;
        }
    }
#pragma unroll
    for (int it = 0; it < 4; ++it) {
        int c = tid + 256 * it;
        int row = c >> 4, off = c & 15;
        if (row0 + row < nrows) {
            uint4 v = *reinterpret_cast<const uint4*>(
                reinterpret_cast<const char*>(&sb[row][0]) + off * 16);
            *reinterpret_cast<uint4*>(
                reinterpret_cast<char*>(Ob) + (size_t)(row0 + row) * 256 + off * 16) = v;
        }
    }
}

// ---------------- layer-2 GEMM: h(bf16) @ [Wn2|Ws2] -> t2 fp8, out f32 ----------------
// out f32 stored DIRECTLY from acc: per (rt,ct) the 4 lg-lanes cover 64
// contiguous bytes per row -> line-complete stores, no staging needed.
__global__ __launch_bounds__(256, 4) void k_gemm2(
    const unsigned short* __restrict__ Ab, int nrows,
    const unsigned short* __restrict__ Bt, const float* __restrict__ bias,
    unsigned char* __restrict__ O8, float* __restrict__ O2f) {
    constexpr int MO = 64, BR = 128;
    __shared__ __attribute__((aligned(16))) unsigned char s8[BR][80];  // t2 fp8 stage

    const int tid = threadIdx.x;
    const int w = tid >> 6, lane = tid & 63;
    const int l15 = lane & 15, lg = lane >> 4;
    const int wr = w >> 1, wc = w & 1;
    const int row0w = blockIdx.x * BR + wr * 64;
    const int col0 = wc * 64;

    f32x4 acc[4][4];
#pragma unroll
    for (int rt = 0; rt < 4; ++rt)
#pragma unroll
        for (int ct = 0; ct < 4; ++ct) acc[rt][ct] = (f32x4)0.f;

#pragma unroll
    for (int ks = 0; ks < 4; ++ks) {
        short8 bf[4];
#pragma unroll
        for (int ct = 0; ct < 4; ++ct)
            bf[ct] = *reinterpret_cast<const short8*>(
                Bt + (size_t)(col0 + ct * 16 + l15) * 128 + ks * 32 + lg * 8);
        short8 af[4];
#pragma unroll
        for (int rt = 0; rt < 4; ++rt) {
            int row = row0w + rt * 16 + l15;
            int rc = row < nrows ? row : nrows - 1;
            af[rt] = *reinterpret_cast<const short8*>(
                Ab + (size_t)rc * 128 + ks * 32 + lg * 8);
        }
#pragma unroll
        for (int rt = 0; rt < 4; ++rt)
#pragma unroll
            for (int ct = 0; ct < 4; ++ct)
                acc[rt][ct] = __builtin_amdgcn_mfma_f32_16x16x32_bf16(
                    bf[ct], af[rt], acc[rt][ct], 0, 0, 0);
    }

#pragma unroll
    for (int rt = 0; rt < 4; ++rt) {
#pragma unroll
        for (int ct = 0; ct < 4; ++ct) {
            int rowL = wr * 64 + rt * 16 + l15;
            int colL = col0 + ct * 16 + lg * 4;
            f32x4 a = acc[rt][ct];
            if (colL < MO) {
                *reinterpret_cast<unsigned int*>(&s8[rowL][colL]) =
                    f32x4_to_fp8x4(a[0], a[1], a[2], a[3]);
            } else {
                int cc = colL - MO;
                float4 bv = *reinterpret_cast<const float4*>(bias + cc);
                a[0] += bv.x; a[1] += bv.y; a[2] += bv.z; a[3] += bv.w;
                int grow = blockIdx.x * BR + rowL;
                if (grow < nrows)
                    *reinterpret_cast<f32x4*>(O2f + (size_t)grow * MO + cc) = a;
            }
        }
    }
    __syncthreads();

    const int row0 = blockIdx.x * BR;
#pragma unroll
    for (int it = 0; it < 2; ++it) {           // t2 fp8: 4 chunks(16B)/row
        int c = tid + 256 * it;
        int row = c >> 2, off = c & 3;
        if (row0 + row < nrows) {
            uint4 v = *reinterpret_cast<const uint4*>(&s8[row][off * 16]);
            *reinterpret_cast<uint4*>(O8 + (size_t)(row0 + row) * 64 + off * 16) = v;
        }
    }
}

// ---------------- aggregation ----------------
// layer 1: half-wave per node; t1 fp8 [N][128] (1 line/gather), hs bf16 [N][128].
__global__ __launch_bounds__(256) void k_agg1(
    const unsigned char* __restrict__ t1f8, const unsigned short* __restrict__ hs,
    unsigned short* __restrict__ hb,
    const int* __restrict__ row_off, const int* __restrict__ cnt,
    const float* __restrict__ inv_deg, const int* __restrict__ ssorted, int n) {
    int node = (blockIdx.x * 256 + threadIdx.x) >> 5;
    int l = threadIdx.x & 31;
    if (node >= n) return;
    int beg = row_off[node], d = cnt[node];
    float a0 = 0.f, a1 = 0.f, a2 = 0.f, a3 = 0.f;
    for (int base = 0; base < d; base += 32) {
        int m = d - base; if (m > 32) m = 32;
        int sv = (l < m) ? ssorted[beg + base + l] : 0;
        int j = 0;
        for (; j + 8 <= m; j += 8) {
            unsigned int p[8];
#pragma unroll
            for (int q = 0; q < 8; ++q) {
                int s = __shfl(sv, j + q, 32);
                p[q] = *reinterpret_cast<const unsigned int*>(t1f8 + (size_t)s * 128 + l * 4);
            }
#pragma unroll
            for (int q = 0; q < 8; ++q) {
                f32x2 lo = fp8pair_to_f32<false>(p[q]);
                f32x2 hi = fp8pair_to_f32<true>(p[q]);
                a0 += lo[0]; a1 += lo[1]; a2 += hi[0]; a3 += hi[1];
            }
        }
        for (; j < m; ++j) {
            int s = __shfl(sv, j, 32);
            unsigned int p = *reinterpret_cast<const unsigned int*>(t1f8 + (size_t)s * 128 + l * 4);
            f32x2 lo = fp8pair_to_f32<false>(p);
            f32x2 hi = fp8pair_to_f32<true>(p);
            a0 += lo[0]; a1 += lo[1]; a2 += hi[0]; a3 += hi[1];
        }
    }
    float inv = inv_deg[node];
    uint2 q = *reinterpret_cast<const uint2*>(hs + (size_t)node * 128 + l * 4);
    float h0 = fmaxf(bf_lo(q.x) + a0 * inv, 0.f);
    float h1 = fmaxf(bf_hi(q.x) + a1 * inv, 0.f);
    float h2 = fmaxf(bf_lo(q.y) + a2 * inv, 0.f);
    float h3 = fmaxf(bf_hi(q.y) + a3 * inv, 0.f);
    uint2 o;
    o.x = (unsigned int)f2bf(h0) | ((unsigned int)f2bf(h1) << 16);
    o.y = (unsigned int)f2bf(h2) | ((unsigned int)f2bf(h3) << 16);
    *reinterpret_cast<uint2*>(hb + (size_t)node * 128 + l * 4) = o;
}

// layer 2: quarter-wave per node; t2 fp8 [N][64] (1 line/gather). out += mean.
__global__ __launch_bounds__(256) void k_agg2(
    const unsigned char* __restrict__ t2f8, float* __restrict__ out,
    const int* __restrict__ row_off, const int* __restrict__ cnt,
    const float* __restrict__ inv_deg, const int* __restrict__ ssorted, int n) {
    int node = (blockIdx.x * 256 + threadIdx.x) >> 4;
    int l = threadIdx.x & 15;
    if (node >= n) return;
    int beg = row_off[node], d = cnt[node];
    float a0 = 0.f, a1 = 0.f, a2 = 0.f, a3 = 0.f;
    for (int base = 0; base < d; base += 16) {
        int m = d - base; if (m > 16) m = 16;
        int sv = (l < m) ? ssorted[beg + base + l] : 0;
        int j = 0;
        for (; j + 8 <= m; j += 8) {
            unsigned int p[8];
#pragma unroll
            for (int q = 0; q < 8; ++q) {
                int s = __shfl(sv, j + q, 16);
                p[q] = *reinterpret_cast<const unsigned int*>(t2f8 + (size_t)s * 64 + l * 4);
            }
#pragma unroll
            for (int q = 0; q < 8; ++q) {
                f32x2 lo = fp8pair_to_f32<false>(p[q]);
                f32x2 hi = fp8pair_to_f32<true>(p[q]);
                a0 += lo[0]; a1 += lo[1]; a2 += hi[0]; a3 += hi[1];
            }
        }
        for (; j < m; ++j) {
            int s = __shfl(sv, j, 16);
            unsigned int p = *reinterpret_cast<const unsigned int*>(t2f8 + (size_t)s * 64 + l * 4);
            f32x2 lo = fp8pair_to_f32<false>(p);
            f32x2 hi = fp8pair_to_f32<true>(p);
            a0 += lo[0]; a1 += lo[1]; a2 += hi[0]; a3 += hi[1];
        }
    }
    float inv = inv_deg[node];
    float4* po = reinterpret_cast<float4*>(out + (size_t)node * 64 + l * 4);
    float4 v = *po;
    v.x += a0 * inv; v.y += a1 * inv; v.z += a2 * inv; v.w += a3 * inv;
    *po = v;
}

// ---------------- launch ----------------

extern "C" void kernel_launch(void* const* d_in, const int* in_sizes, int n_in,
                              void* d_out, int out_size, void* d_ws, size_t ws_size,
                              hipStream_t stream) {
    const float* x        = (const float*)d_in[0];
    const int*   src      = (const int*)d_in[1];
    const int*   dst      = (const int*)d_in[2];
    const float* W_self1  = (const float*)d_in[3];
    const float* W_neigh1 = (const float*)d_in[4];
    const float* b1       = (const float*)d_in[5];
    const float* W_self2  = (const float*)d_in[6];
    const float* W_neigh2 = (const float*)d_in[7];
    const float* b2       = (const float*)d_in[8];
    float* out = (float*)d_out;

    const int N = in_sizes[0] / 128;
    const int E = in_sizes[1];
    const int NB = (N + 127) >> BKT_SHIFT;     // 782 buckets

    char* ws = (char*)d_ws;
    size_t off = 0;
    auto carve = [&](size_t bytes) {
        char* p = ws + off;
        off = (off + bytes + 255) & ~(size_t)255;
        return p;
    };
    int*   Hist    = (int*)carve((size_t)GHIST * NB * 4);   // -> Off (in-place)
    int*   Tot     = (int*)carve((size_t)NB * 4);
    int*   Base    = (int*)carve((size_t)(NB + 1) * 4);
    int*   row_off = (int*)carve((size_t)N * 4);
    int*   cnt     = (int*)carve((size_t)N * 4);
    float* inv_deg = (float*)carve((size_t)N * 4);
    int*   ssorted = (int*)carve((size_t)E * 4);
    unsigned short* Bt1  = (unsigned short*)carve(256 * 128 * 2);
    unsigned short* Bt2  = (unsigned short*)carve(128 * 128 * 2);
    unsigned char*  t1f8 = (unsigned char*)carve((size_t)N * 128);      // fp8 t1
    unsigned short* hs   = (unsigned short*)carve((size_t)N * 128 * 2); // self L1
    unsigned short* hb   = (unsigned short*)carve((size_t)N * 128 * 2); // relu'd h
    unsigned char*  t2f8 = t1f8;                    // alias: t1f8 dead after agg1
    unsigned int* packed = (unsigned int*)hb;       // alias: dead before agg1 writes hb

    const int chunk = (E + GHIST - 1) / GHIST;

    // CSR build (radix 3-phase, no global atomics)
    k_hist2<<<GHIST, 256, 0, stream>>>(dst, E, chunk, Hist, NB);
    k_scanb<<<(NB + 3) / 4, 256, 0, stream>>>(Hist, Tot, NB);
    k_scant<<<1, 1024, 0, stream>>>(Tot, Base, NB, E);
    k_scatter2<<<GHIST, 256, 0, stream>>>(src, dst, E, chunk, Hist, Base, packed, NB);
    k_bsort<<<NB, 256, 0, stream>>>(packed, Base, ssorted, row_off, cnt, inv_deg, N);

    // weights -> bf16 transposed
    k_prep<<<192, 256, 0, stream>>>(W_neigh1, W_self1, W_neigh2, W_self2, Bt1, Bt2);

    // layer 1: t1f8 = fp8(x@Wn1), hs = bf16(x@Ws1 + b1)
    k_gemm1<<<(N + 63) / 64, 256, 0, stream>>>(x, N, Bt1, b1, t1f8, hs);
    // h = relu(hs + mean_agg(t1)) -> hb (bf16)
    k_agg1<<<(N * 32 + 255) / 256, 256, 0, stream>>>(
        t1f8, hs, hb, row_off, cnt, inv_deg, ssorted, N);

    // layer 2: t2f8 = fp8(h@Wn2), out = h@Ws2 + b2 (f32)
    k_gemm2<<<(N + 127) / 128, 256, 0, stream>>>(hb, N, Bt2, b2, t2f8, out);
    // out += mean_agg(t2)
    k_agg2<<<(N * 16 + 255) / 256, 256, 0, stream>>>(
        t2f8, out, row_off, cnt, inv_deg, ssorted, N);
}

// Round 11
// 175.623 us; speedup vs baseline: 3.4634x; 1.0137x over previous
//
#include <hip/hip_runtime.h>
#include <hip/hip_bf16.h>

// GraphSAGE 2-layer, mean aggregator.
//   L1: h  = relu(x @ Wself1 + mean_agg(x) @ Wneigh1 + b1)
//   L2: out = h @ Wself2 + mean_agg(h) @ Wneigh2 + b2
// Transform-first aggregation. bf16 MFMA GEMMs (fp32 accum). CSR by dst via
// radix 3-phase sort (no global atomics). t1/t2 stored fp8 e4m3 (1-line
// gathers; agg at the ~3 TB/s random-gather service ceiling). R11: GHIST
// 512->256 (scatter write-amp down), k_prep fused into k_hist2 (one fewer
// launch), gemm1 hoists ks=0 B-fragments above the A-staging barrier.

typedef __attribute__((ext_vector_type(8))) short short8;
typedef __attribute__((ext_vector_type(4))) float f32x4;
typedef __attribute__((ext_vector_type(2))) float f32x2;

#define BKT_SHIFT 7                 // 128 nodes per bucket
#define SBUF_CAP 4096               // max staged edges per bucket (avg ~2046)
#define GHIST 256                   // hist/scatter blocks

__device__ __forceinline__ unsigned short f2bf(float f) {
    unsigned int u = __builtin_bit_cast(unsigned int, f);
    u += 0x7fffu + ((u >> 16) & 1u);   // RNE
    return (unsigned short)(u >> 16);
}
__device__ __forceinline__ float bf_lo(unsigned int p) {
    return __builtin_bit_cast(float, p << 16);
}
__device__ __forceinline__ float bf_hi(unsigned int p) {
    return __builtin_bit_cast(float, p & 0xffff0000u);
}

// ---- fp8 e4m3 helpers (HW cvt on gfx950; bit-trick fallback) ----
template <bool WORD>
__device__ __forceinline__ f32x2 fp8pair_to_f32(unsigned int v) {
#if __has_builtin(__builtin_amdgcn_cvt_pk_f32_fp8)
    return __builtin_amdgcn_cvt_pk_f32_fp8(v, WORD);
#else
    unsigned int b = WORD ? (v >> 16) : v;
    f32x2 r;
#pragma unroll
    for (int i = 0; i < 2; ++i) {
        unsigned int byte = (b >> (8 * i)) & 0xffu;
        float f = __builtin_bit_cast(float, (byte & 0x7fu) << 20) * 0x1p+120f;
        r[i] = (byte & 0x80u) ? -f : f;
    }
    return r;
#endif
}
__device__ __forceinline__ unsigned int enc_fp8(float v) {
    float c = fminf(fmaxf(v, -448.f), 448.f);
    unsigned int s = (__builtin_bit_cast(unsigned int, c) >> 24) & 0x80u;
    unsigned int bits = __builtin_bit_cast(unsigned int, fabsf(c) * 0x1p-120f);
    bits += 0x7FFFFu + ((bits >> 20) & 1u);
    unsigned int mag = bits >> 20;
    if (mag > 0x7Eu) mag = 0x7Eu;
    return s | mag;
}
__device__ __forceinline__ unsigned int f32x4_to_fp8x4(float a0, float a1,
                                                       float a2, float a3) {
#if __has_builtin(__builtin_amdgcn_cvt_pk_fp8_f32)
    int p = __builtin_amdgcn_cvt_pk_fp8_f32(a0, a1, 0, false);
    p = __builtin_amdgcn_cvt_pk_fp8_f32(a2, a3, p, true);
    return (unsigned int)p;
#else
    return enc_fp8(a0) | (enc_fp8(a1) << 8) | (enc_fp8(a2) << 16) | (enc_fp8(a3) << 24);
#endif
}

// ---------------- CSR build: radix 3-phase, no global atomics ----------------

// phase 1: per-block LDS histogram -> Hist[blk][nb]; also fuses the weight
// prep (bf16 transpose) as independent work: block b handles 192 elements.
__global__ __launch_bounds__(256) void k_hist2(
    const int* __restrict__ dst, int E, int chunk,
    int* __restrict__ Hist, int nb,
    const float* __restrict__ Wn1, const float* __restrict__ Ws1,
    const float* __restrict__ Wn2, const float* __restrict__ Ws2,
    unsigned short* __restrict__ Bt1, unsigned short* __restrict__ Bt2) {
    __shared__ int h[1024];
    // fused weight prep: 256 blocks x 192 elems = 49152 = 256*128 + 128*128
    {
        int g = blockIdx.x * 192 + threadIdx.x;
        if (threadIdx.x < 192) {
            if (g < 256 * 128) {
                int c = g >> 7, k = g & 127;
                float v = (c < 128) ? Wn1[k * 128 + c] : Ws1[k * 128 + (c - 128)];
                Bt1[g] = f2bf(v);
            } else if (g < 256 * 128 + 128 * 128) {
                int j = g - 256 * 128;
                int c = j >> 7, k = j & 127;
                float v = (c < 64) ? Wn2[k * 64 + c] : Ws2[k * 64 + (c - 64)];
                Bt2[j] = f2bf(v);
            }
        }
    }
    for (int i = threadIdx.x; i < nb; i += 256) h[i] = 0;
    __syncthreads();
    int beg = blockIdx.x * chunk;
    int end = min(beg + chunk, E);
    for (int i = beg + threadIdx.x; i < end; i += 256)
        atomicAdd(&h[dst[i] >> BKT_SHIFT], 1);
    __syncthreads();
    int* o = Hist + (size_t)blockIdx.x * nb;
    for (int i = threadIdx.x; i < nb; i += 256) o[i] = h[i];
}

__global__ __launch_bounds__(256) void k_scanb(
    int* __restrict__ Hist, int* __restrict__ Tot, int nb) {
    int wave = (blockIdx.x * 256 + threadIdx.x) >> 6;
    int lane = threadIdx.x & 63;
    if (wave >= nb) return;
    const int b = wave;
    constexpr int PER = GHIST / 64;   // 4
    int v[PER];
    int s = 0;
    int blk0 = lane * PER;
#pragma unroll
    for (int j = 0; j < PER; ++j) {
        v[j] = Hist[(size_t)(blk0 + j) * nb + b];
        s += v[j];
    }
    int incl = s;
#pragma unroll
    for (int o = 1; o < 64; o <<= 1) {
        int t = __shfl_up(incl, o);
        if (lane >= o) incl += t;
    }
    int run = incl - s;   // exclusive
#pragma unroll
    for (int j = 0; j < PER; ++j) {
        int t = v[j];
        Hist[(size_t)(blk0 + j) * nb + b] = run;
        run += t;
    }
    if (lane == 63) Tot[b] = incl;
}

__global__ __launch_bounds__(1024) void k_scant(
    const int* __restrict__ Tot, int* __restrict__ Base, int nb, int E) {
    __shared__ int s[1024];
    int t = threadIdx.x;
    int v = (t < nb) ? Tot[t] : 0;
    s[t] = v;
    __syncthreads();
    for (int o = 1; o < 1024; o <<= 1) {
        int x = (t >= o) ? s[t - o] : 0;
        __syncthreads();
        s[t] += x;
        __syncthreads();
    }
    if (t < nb) Base[t] = s[t] - v;  // exclusive
    if (t == 0) Base[nb] = E;
}

__global__ __launch_bounds__(256) void k_scatter2(
    const int* __restrict__ src, const int* __restrict__ dst, int E, int chunk,
    const int* __restrict__ Off, const int* __restrict__ Base,
    unsigned int* __restrict__ packed, int nb) {
    __shared__ int cb[1024];
    __shared__ int h[1024];
    const int blk = blockIdx.x;
    for (int i = threadIdx.x; i < nb; i += 256) {
        cb[i] = Base[i] + Off[(size_t)blk * nb + i];
        h[i] = 0;
    }
    __syncthreads();
    int beg = blk * chunk;
    int end = min(beg + chunk, E);
    for (int i = beg + threadIdx.x; i < end; i += 256) {
        int d = dst[i];
        int b = d >> BKT_SHIFT;
        int loc = atomicAdd(&h[b], 1);
        packed[cb[b] + loc] = ((unsigned int)(d & 127) << 17) | (unsigned int)src[i];
    }
}

__global__ __launch_bounds__(256) void k_bsort(
    const unsigned int* __restrict__ packed, const int* __restrict__ base,
    int* __restrict__ ssorted, int* __restrict__ row_off, int* __restrict__ cnt,
    float* __restrict__ inv_deg, int n) {
    __shared__ int h128[128];
    __shared__ int ex[128];
    __shared__ int sbuf[SBUF_CAP];
    int t = threadIdx.x;
    int b = blockIdx.x;
    int beg = base[b], end = base[b + 1];
    int m = end - beg;
    if (t < 128) h128[t] = 0;
    __syncthreads();
    for (int i = t; i < m; i += 256)
        atomicAdd(&h128[packed[beg + i] >> 17], 1);
    __syncthreads();
    if (t < 128) ex[t] = h128[t];
    __syncthreads();
    for (int o = 1; o < 128; o <<= 1) {
        int v = (t < 128 && t >= o) ? ex[t - o] : 0;
        __syncthreads();
        if (t < 128) ex[t] += v;
        __syncthreads();
    }
    if (t < 128) {
        int deg = h128[t];
        ex[t] -= deg;  // exclusive
        int node = (b << BKT_SHIFT) + t;
        if (node < n) {
            row_off[node] = beg + ex[t];
            cnt[node] = deg;
            inv_deg[node] = 1.0f / fmaxf((float)deg, 1.0f);
        }
    }
    __syncthreads();
    if (t < 128) h128[t] = 0;  // reuse as cursor
    __syncthreads();
    if (m <= SBUF_CAP) {
        for (int i = t; i < m; i += 256) {
            unsigned int p = packed[beg + i];
            int dl = p >> 17;
            int loc = atomicAdd(&h128[dl], 1);
            sbuf[ex[dl] + loc] = (int)(p & 0x1FFFFu);
        }
        __syncthreads();
        for (int i = t; i < m; i += 256) ssorted[beg + i] = sbuf[i];
    } else {
        for (int i = t; i < m; i += 256) {
            unsigned int p = packed[beg + i];
            int dl = p >> 17;
            int loc = atomicAdd(&h128[dl], 1);
            ssorted[beg + ex[dl] + loc] = (int)(p & 0x1FFFFu);
        }
    }
}

// ---------------- layer-1 GEMM: x(f32) @ [Wn1|Ws1] -> t1 fp8, hs bf16 ----------------
// A-tile staged coalesced -> LDS bf16 (union'd with epilogue stages).
// ks=0 B-fragments hoisted above the staging barrier to overlap weight loads.
__global__ __launch_bounds__(256, 4) void k_gemm1(
    const float* __restrict__ Af, int nrows,
    const unsigned short* __restrict__ Bt, const float* __restrict__ bias,
    unsigned char* __restrict__ O8, unsigned short* __restrict__ Ob) {
    constexpr int BR = 64;
    __shared__ __attribute__((aligned(16))) unsigned char smem[26624];
    auto sA = reinterpret_cast<unsigned short(*)[136]>(smem);          // phase 1: A bf16
    auto sb = reinterpret_cast<unsigned short(*)[136]>(smem);          // phase 2: hs stage
    auto s8 = reinterpret_cast<unsigned char(*)[144]>(smem + 17408);   // phase 2: t1 fp8 stage

    const int tid = threadIdx.x;
    const int w = tid >> 6, lane = tid & 63;
    const int l15 = lane & 15, lg = lane >> 4;
    const int col0 = w * 64;
    const int row0 = blockIdx.x * BR;

    // hoisted ks=0 B-fragments (overlap with A staging below)
    short8 bf0[4];
#pragma unroll
    for (int ct = 0; ct < 4; ++ct)
        bf0[ct] = *reinterpret_cast<const short8*>(
            Bt + (size_t)(col0 + ct * 16 + l15) * 128 + lg * 8);

    // coalesced A staging: 32 lanes cover one 512B row
#pragma unroll
    for (int i = 0; i < 8; ++i) {
        int q = tid + 256 * i;
        int row = q >> 5, c4 = q & 31;
        float4 a = make_float4(0.f, 0.f, 0.f, 0.f);
        if (row0 + row < nrows)
            a = *reinterpret_cast<const float4*>(Af + (size_t)(row0 + row) * 128 + c4 * 4);
        uint2 pk;
        pk.x = (unsigned int)f2bf(a.x) | ((unsigned int)f2bf(a.y) << 16);
        pk.y = (unsigned int)f2bf(a.z) | ((unsigned int)f2bf(a.w) << 16);
        *reinterpret_cast<uint2*>(&sA[row][c4 * 4]) = pk;
    }
    __syncthreads();

    f32x4 acc[4][4];
#pragma unroll
    for (int rt = 0; rt < 4; ++rt)
#pragma unroll
        for (int ct = 0; ct < 4; ++ct) acc[rt][ct] = (f32x4)0.f;

#pragma unroll
    for (int ks = 0; ks < 4; ++ks) {
        short8 bf[4];
#pragma unroll
        for (int ct = 0; ct < 4; ++ct) {
            if (ks == 0) bf[ct] = bf0[ct];
            else
                bf[ct] = *reinterpret_cast<const short8*>(
                    Bt + (size_t)(col0 + ct * 16 + l15) * 128 + ks * 32 + lg * 8);
        }
        short8 af[4];
#pragma unroll
        for (int rt = 0; rt < 4; ++rt)
            af[rt] = *reinterpret_cast<const short8*>(&sA[rt * 16 + l15][ks * 32 + lg * 8]);
#pragma unroll
        for (int rt = 0; rt < 4; ++rt)
#pragma unroll
            for (int ct = 0; ct < 4; ++ct)
                acc[rt][ct] = __builtin_amdgcn_mfma_f32_16x16x32_bf16(
                    bf[ct], af[rt], acc[rt][ct], 0, 0, 0);
    }
    __syncthreads();   // sA dead; epilogue stages reuse the same LDS

    // stage: lane holds row = rt*16+l15, cols = col0+ct*16+lg*4..+3
#pragma unroll
    for (int rt = 0; rt < 4; ++rt) {
#pragma unroll
        for (int ct = 0; ct < 4; ++ct) {
            int rowL = rt * 16 + l15;
            int colL = col0 + ct * 16 + lg * 4;
            f32x4 a = acc[rt][ct];
            if (colL < 128) {
                *reinterpret_cast<unsigned int*>(&s8[rowL][colL]) =
                    f32x4_to_fp8x4(a[0], a[1], a[2], a[3]);
            } else {
                int cc = colL - 128;
                float4 bv = *reinterpret_cast<const float4*>(bias + cc);
                unsigned int lo = (unsigned int)f2bf(a[0] + bv.x) |
                                  ((unsigned int)f2bf(a[1] + bv.y) << 16);
                unsigned int hi = (unsigned int)f2bf(a[2] + bv.z) |
                                  ((unsigned int)f2bf(a[3] + bv.w) << 16);
                *reinterpret_cast<uint2*>(&sb[rowL][cc]) = make_uint2(lo, hi);
            }
        }
    }
    __syncthreads();

    // coalesced copy-out: t1 fp8 (128B/row), hs bf16 (256B/row)
#pragma unroll
    for (int it = 0; it < 2; ++it) {
        int c = tid + 256 * it;
        int row = c >> 3, off = c & 7;
        if (row0 + row < nrows) {
            uint4 v = *reinterpret_cast<const uint4*>(&s8[row][off * 16]);
            *reinterpret_cast<uint4*>(O8 + (size_t)(row0 + row) * 128 + off * 16) = v;
        }
    }
#pragma unroll
    for (int it = 0; it < 4; ++it) {
        int c = tid + 256 * it;
        int row = c >> 4, off = c & 15;
        if (row0 + row < nrows) {
            uint4 v = *reinterpret_cast<const uint4*>(
                reinterpret_cast<const char*>(&sb[row][0]) + off * 16);
            *reinterpret_cast<uint4*>(
                reinterpret_cast<char*>(Ob) + (size_t)(row0 + row) * 256 + off * 16) = v;
        }
    }
}

// ---------------- layer-2 GEMM: h(bf16) @ [Wn2|Ws2] -> t2 fp8, out f32 ----------------
__global__ __launch_bounds__(256, 4) void k_gemm2(
    const unsigned short* __restrict__ Ab, int nrows,
    const unsigned short* __restrict__ Bt, const float* __restrict__ bias,
    unsigned char* __restrict__ O8, float* __restrict__ O2f) {
    constexpr int MO = 64, BR = 128;
    __shared__ __attribute__((aligned(16))) unsigned char s8[BR][80];  // t2 fp8 stage

    const int tid = threadIdx.x;
    const int w = tid >> 6, lane = tid & 63;
    const int l15 = lane & 15, lg = lane >> 4;
    const int wr = w >> 1, wc = w & 1;
    const int row0w = blockIdx.x * BR + wr * 64;
    const int col0 = wc * 64;

    f32x4 acc[4][4];
#pragma unroll
    for (int rt = 0; rt < 4; ++rt)
#pragma unroll
        for (int ct = 0; ct < 4; ++ct) acc[rt][ct] = (f32x4)0.f;

#pragma unroll
    for (int ks = 0; ks < 4; ++ks) {
        short8 bf[4];
#pragma unroll
        for (int ct = 0; ct < 4; ++ct)
            bf[ct] = *reinterpret_cast<const short8*>(
                Bt + (size_t)(col0 + ct * 16 + l15) * 128 + ks * 32 + lg * 8);
        short8 af[4];
#pragma unroll
        for (int rt = 0; rt < 4; ++rt) {
            int row = row0w + rt * 16 + l15;
            int rc = row < nrows ? row : nrows - 1;
            af[rt] = *reinterpret_cast<const short8*>(
                Ab + (size_t)rc * 128 + ks * 32 + lg * 8);
        }
#pragma unroll
        for (int rt = 0; rt < 4; ++rt)
#pragma unroll
            for (int ct = 0; ct < 4; ++ct)
                acc[rt][ct] = __builtin_amdgcn_mfma_f32_16x16x32_bf16(
                    bf[ct], af[rt], acc[rt][ct], 0, 0, 0);
    }

#pragma unroll
    for (int rt = 0; rt < 4; ++rt) {
#pragma unroll
        for (int ct = 0; ct < 4; ++ct) {
            int rowL = wr * 64 + rt * 16 + l15;
            int colL = col0 + ct * 16 + lg * 4;
            f32x4 a = acc[rt][ct];
            if (colL < MO) {
                *reinterpret_cast<unsigned int*>(&s8[rowL][colL]) =
                    f32x4_to_fp8x4(a[0], a[1], a[2], a[3]);
            } else {
                int cc = colL - MO;
                float4 bv = *reinterpret_cast<const float4*>(bias + cc);
                a[0] += bv.x; a[1] += bv.y; a[2] += bv.z; a[3] += bv.w;
                int grow = blockIdx.x * BR + rowL;
                if (grow < nrows)
                    *reinterpret_cast<f32x4*>(O2f + (size_t)grow * MO + cc) = a;
            }
        }
    }
    __syncthreads();

    const int row0 = blockIdx.x * BR;
#pragma unroll
    for (int it = 0; it < 2; ++it) {           // t2 fp8: 4 chunks(16B)/row
        int c = tid + 256 * it;
        int row = c >> 2, off = c & 3;
        if (row0 + row < nrows) {
            uint4 v = *reinterpret_cast<const uint4*>(&s8[row][off * 16]);
            *reinterpret_cast<uint4*>(O8 + (size_t)(row0 + row) * 64 + off * 16) = v;
        }
    }
}

// ---------------- aggregation ----------------
// layer 1: half-wave per node; t1 fp8 [N][128] (2 lines/gather), hs bf16.
__global__ __launch_bounds__(256) void k_agg1(
    const unsigned char* __restrict__ t1f8, const unsigned short* __restrict__ hs,
    unsigned short* __restrict__ hb,
    const int* __restrict__ row_off, const int* __restrict__ cnt,
    const float* __restrict__ inv_deg, const int* __restrict__ ssorted, int n) {
    int node = (blockIdx.x * 256 + threadIdx.x) >> 5;
    int l = threadIdx.x & 31;
    if (node >= n) return;
    int beg = row_off[node], d = cnt[node];
    float a0 = 0.f, a1 = 0.f, a2 = 0.f, a3 = 0.f;
    for (int base = 0; base < d; base += 32) {
        int m = d - base; if (m > 32) m = 32;
        int sv = (l < m) ? ssorted[beg + base + l] : 0;
        int j = 0;
        for (; j + 8 <= m; j += 8) {
            unsigned int p[8];
#pragma unroll
            for (int q = 0; q < 8; ++q) {
                int s = __shfl(sv, j + q, 32);
                p[q] = *reinterpret_cast<const unsigned int*>(t1f8 + (size_t)s * 128 + l * 4);
            }
#pragma unroll
            for (int q = 0; q < 8; ++q) {
                f32x2 lo = fp8pair_to_f32<false>(p[q]);
                f32x2 hi = fp8pair_to_f32<true>(p[q]);
                a0 += lo[0]; a1 += lo[1]; a2 += hi[0]; a3 += hi[1];
            }
        }
        for (; j < m; ++j) {
            int s = __shfl(sv, j, 32);
            unsigned int p = *reinterpret_cast<const unsigned int*>(t1f8 + (size_t)s * 128 + l * 4);
            f32x2 lo = fp8pair_to_f32<false>(p);
            f32x2 hi = fp8pair_to_f32<true>(p);
            a0 += lo[0]; a1 += lo[1]; a2 += hi[0]; a3 += hi[1];
        }
    }
    float inv = inv_deg[node];
    uint2 q = *reinterpret_cast<const uint2*>(hs + (size_t)node * 128 + l * 4);
    float h0 = fmaxf(bf_lo(q.x) + a0 * inv, 0.f);
    float h1 = fmaxf(bf_hi(q.x) + a1 * inv, 0.f);
    float h2 = fmaxf(bf_lo(q.y) + a2 * inv, 0.f);
    float h3 = fmaxf(bf_hi(q.y) + a3 * inv, 0.f);
    uint2 o;
    o.x = (unsigned int)f2bf(h0) | ((unsigned int)f2bf(h1) << 16);
    o.y = (unsigned int)f2bf(h2) | ((unsigned int)f2bf(h3) << 16);
    *reinterpret_cast<uint2*>(hb + (size_t)node * 128 + l * 4) = o;
}

// layer 2: quarter-wave per node; t2 fp8 [N][64] (1 line/gather). out += mean.
__global__ __launch_bounds__(256) void k_agg2(
    const unsigned char* __restrict__ t2f8, float* __restrict__ out,
    const int* __restrict__ row_off, const int* __restrict__ cnt,
    const float* __restrict__ inv_deg, const int* __restrict__ ssorted, int n) {
    int node = (blockIdx.x * 256 + threadIdx.x) >> 4;
    int l = threadIdx.x & 15;
    if (node >= n) return;
    int beg = row_off[node], d = cnt[node];
    float a0 = 0.f, a1 = 0.f, a2 = 0.f, a3 = 0.f;
    for (int base = 0; base < d; base += 16) {
        int m = d - base; if (m > 16) m = 16;
        int sv = (l < m) ? ssorted[beg + base + l] : 0;
        int j = 0;
        for (; j + 8 <= m; j += 8) {
            unsigned int p[8];
#pragma unroll
            for (int q = 0; q < 8; ++q) {
                int s = __shfl(sv, j + q, 16);
                p[q] = *reinterpret_cast<const unsigned int*>(t2f8 + (size_t)s * 64 + l * 4);
            }
#pragma unroll
            for (int q = 0; q < 8; ++q) {
                f32x2 lo = fp8pair_to_f32<false>(p[q]);
                f32x2 hi = fp8pair_to_f32<true>(p[q]);
                a0 += lo[0]; a1 += lo[1]; a2 += hi[0]; a3 += hi[1];
            }
        }
        for (; j < m; ++j) {
            int s = __shfl(sv, j, 16);
            unsigned int p = *reinterpret_cast<const unsigned int*>(t2f8 + (size_t)s * 64 + l * 4);
            f32x2 lo = fp8pair_to_f32<false>(p);
            f32x2 hi = fp8pair_to_f32<true>(p);
            a0 += lo[0]; a1 += lo[1]; a2 += hi[0]; a3 += hi[1];
        }
    }
    float inv = inv_deg[node];
    float4* po = reinterpret_cast<float4*>(out + (size_t)node * 64 + l * 4);
    float4 v = *po;
    v.x += a0 * inv; v.y += a1 * inv; v.z += a2 * inv; v.w += a3 * inv;
    *po = v;
}

// ---------------- launch ----------------

extern "C" void kernel_launch(void* const* d_in, const int* in_sizes, int n_in,
                              void* d_out, int out_size, void* d_ws, size_t ws_size,
                              hipStream_t stream) {
    const float* x        = (const float*)d_in[0];
    const int*   src      = (const int*)d_in[1];
    const int*   dst      = (const int*)d_in[2];
    const float* W_self1  = (const float*)d_in[3];
    const float* W_neigh1 = (const float*)d_in[4];
    const float* b1       = (const float*)d_in[5];
    const float* W_self2  = (const float*)d_in[6];
    const float* W_neigh2 = (const float*)d_in[7];
    const float* b2       = (const float*)d_in[8];
    float* out = (float*)d_out;

    const int N = in_sizes[0] / 128;
    const int E = in_sizes[1];
    const int NB = (N + 127) >> BKT_SHIFT;     // 782 buckets

    char* ws = (char*)d_ws;
    size_t off = 0;
    auto carve = [&](size_t bytes) {
        char* p = ws + off;
        off = (off + bytes + 255) & ~(size_t)255;
        return p;
    };
    int*   Hist    = (int*)carve((size_t)GHIST * NB * 4);   // -> Off (in-place)
    int*   Tot     = (int*)carve((size_t)NB * 4);
    int*   Base    = (int*)carve((size_t)(NB + 1) * 4);
    int*   row_off = (int*)carve((size_t)N * 4);
    int*   cnt     = (int*)carve((size_t)N * 4);
    float* inv_deg = (float*)carve((size_t)N * 4);
    int*   ssorted = (int*)carve((size_t)E * 4);
    unsigned short* Bt1  = (unsigned short*)carve(256 * 128 * 2);
    unsigned short* Bt2  = (unsigned short*)carve(128 * 128 * 2);
    unsigned char*  t1f8 = (unsigned char*)carve((size_t)N * 128);      // fp8 t1
    unsigned short* hs   = (unsigned short*)carve((size_t)N * 128 * 2); // self L1
    unsigned short* hb   = (unsigned short*)carve((size_t)N * 128 * 2); // relu'd h
    unsigned char*  t2f8 = t1f8;                    // alias: t1f8 dead after agg1
    unsigned int* packed = (unsigned int*)hb;       // alias: dead before agg1 writes hb

    const int chunk = (E + GHIST - 1) / GHIST;

    // CSR build (radix 3-phase, no global atomics); hist fuses weight prep
    k_hist2<<<GHIST, 256, 0, stream>>>(dst, E, chunk, Hist, NB,
                                       W_neigh1, W_self1, W_neigh2, W_self2, Bt1, Bt2);
    k_scanb<<<(NB + 3) / 4, 256, 0, stream>>>(Hist, Tot, NB);
    k_scant<<<1, 1024, 0, stream>>>(Tot, Base, NB, E);
    k_scatter2<<<GHIST, 256, 0, stream>>>(src, dst, E, chunk, Hist, Base, packed, NB);
    k_bsort<<<NB, 256, 0, stream>>>(packed, Base, ssorted, row_off, cnt, inv_deg, N);

    // layer 1: t1f8 = fp8(x@Wn1), hs = bf16(x@Ws1 + b1)
    k_gemm1<<<(N + 63) / 64, 256, 0, stream>>>(x, N, Bt1, b1, t1f8, hs);
    // h = relu(hs + mean_agg(t1)) -> hb (bf16)
    k_agg1<<<(N * 32 + 255) / 256, 256, 0, stream>>>(
        t1f8, hs, hb, row_off, cnt, inv_deg, ssorted, N);

    // layer 2: t2f8 = fp8(h@Wn2), out = h@Ws2 + b2 (f32)
    k_gemm2<<<(N + 127) / 128, 256, 0, stream>>>(hb, N, Bt2, b2, t2f8, out);
    // out += mean_agg(t2)
    k_agg2<<<(N * 16 + 255) / 256, 256, 0, stream>>>(
        t2f8, out, row_off, cnt, inv_deg, ssorted, N);
}